// Round 3
// baseline (854.321 us; speedup 1.0000x reference)
//
#include <hip/hip_runtime.h>

#define LSEQ 2048
#define BB 8
#define NTOK (LSEQ*BB)        // 16384 tokens, n = l*B + b
#define DMODEL 256
#define DINNER 512

__device__ __forceinline__ float siluf(float x){ return x / (1.f + __expf(-x)); }

// ---------------- 128x128 tiled fp32 GEMM: C = A(MxK) @ W(KxN) [+bias][+resid]
// 256 threads, 8x8 microtile; rows {ty*4..+3, 64+ty*4..+3}, cols likewise.
__global__ __launch_bounds__(256) void gemm128(
    const float* __restrict__ A, const float* __restrict__ W,
    const float* __restrict__ bias, const float* resid,
    float* C, int M, int N, int K)
{
  __shared__ __align__(16) float As[16][132];
  __shared__ __align__(16) float Bs[16][132];
  const int tid = threadIdx.x;
  const int tx = tid & 15, ty = tid >> 4;
  const int bm = blockIdx.x * 128, bn = blockIdx.y * 128;
  float acc[8][8];
  #pragma unroll
  for (int i = 0; i < 8; ++i)
    #pragma unroll
    for (int j = 0; j < 8; ++j) acc[i][j] = 0.f;

  for (int k0 = 0; k0 < K; k0 += 16) {
    #pragma unroll
    for (int e0 = 0; e0 < 2; ++e0) {
      int e = tid + e0*256;
      int m = e >> 2, kq = e & 3;
      float4 v = *(const float4*)&A[(size_t)(bm+m)*K + k0 + kq*4];
      As[kq*4+0][m] = v.x; As[kq*4+1][m] = v.y;
      As[kq*4+2][m] = v.z; As[kq*4+3][m] = v.w;
    }
    #pragma unroll
    for (int e0 = 0; e0 < 2; ++e0) {
      int e = tid + e0*256;
      int kk = e >> 5, nq = e & 31;
      float4 v = *(const float4*)&W[(size_t)(k0+kk)*N + bn + nq*4];
      *(float4*)&Bs[kk][nq*4] = v;
    }
    __syncthreads();
    #pragma unroll
    for (int kk = 0; kk < 16; ++kk) {
      float av[8], bv[8];
      float4 a0 = *(const float4*)&As[kk][ty*4];
      float4 a1 = *(const float4*)&As[kk][64 + ty*4];
      float4 b0 = *(const float4*)&Bs[kk][tx*4];
      float4 b1 = *(const float4*)&Bs[kk][64 + tx*4];
      av[0]=a0.x; av[1]=a0.y; av[2]=a0.z; av[3]=a0.w;
      av[4]=a1.x; av[5]=a1.y; av[6]=a1.z; av[7]=a1.w;
      bv[0]=b0.x; bv[1]=b0.y; bv[2]=b0.z; bv[3]=b0.w;
      bv[4]=b1.x; bv[5]=b1.y; bv[6]=b1.z; bv[7]=b1.w;
      #pragma unroll
      for (int i = 0; i < 8; ++i)
        #pragma unroll
        for (int j = 0; j < 8; ++j)
          acc[i][j] = fmaf(av[i], bv[j], acc[i][j]);
    }
    __syncthreads();
  }
  #pragma unroll
  for (int i = 0; i < 8; ++i) {
    int m = bm + ((i < 4) ? (ty*4 + i) : (64 + ty*4 + (i-4)));
    #pragma unroll
    for (int jh = 0; jh < 2; ++jh) {
      int n0 = bn + jh*64 + tx*4;
      float4 v; float* pv = (float*)&v;
      #pragma unroll
      for (int j = 0; j < 4; ++j) {
        float t = acc[i][jh*4+j];
        if (bias) t += bias[n0+j];
        pv[j] = t;
      }
      if (resid) {
        float4 r = *(const float4*)&resid[(size_t)m*N + n0];
        v.x += r.x; v.y += r.y; v.z += r.z; v.w += r.w;
      }
      *(float4*)&C[(size_t)m*N + n0] = v;
    }
  }
}

// ---------------- RMSNorm: one wave per token (4 tokens / 256-thread block)
__global__ __launch_bounds__(256) void rmsnorm_k(const float* __restrict__ X,
    const float* __restrict__ w, float* __restrict__ XN)
{
  int n = blockIdx.x*4 + (threadIdx.x >> 6);
  int lane = threadIdx.x & 63;
  const float4 x = *(const float4*)&X[(size_t)n*DMODEL + lane*4];
  float ss = x.x*x.x + x.y*x.y + x.z*x.z + x.w*x.w;
  #pragma unroll
  for (int m = 1; m < 64; m <<= 1) ss += __shfl_xor(ss, m);
  float r = rsqrtf(ss * (1.f/DMODEL) + 1e-5f);
  float4 o;
  o.x = x.x * r * w[lane*4+0];
  o.y = x.y * r * w[lane*4+1];
  o.z = x.z * r * w[lane*4+2];
  o.w = x.w * r * w[lane*4+3];
  *(float4*)&XN[(size_t)n*DMODEL + lane*4] = o;
}

// ---------------- causal depthwise conv (K=4) + SiLU; xp = first 512 cols of XZ
__global__ __launch_bounds__(256) void conv_silu_k(const float* __restrict__ XZ,
    const float* __restrict__ cw, const float* __restrict__ cb, float* __restrict__ XP)
{
  int g = blockIdx.x*256 + threadIdx.x;   // NTOK * 128 c4-groups
  int c4 = (g & 127) << 2;
  int n = g >> 7;
  int l = n >> 3;
  float w[4][4];
  #pragma unroll
  for (int i = 0; i < 4; ++i)
    #pragma unroll
    for (int k = 0; k < 4; ++k) w[i][k] = cw[(c4+i)*4 + k];
  float acc[4];
  #pragma unroll
  for (int i = 0; i < 4; ++i) acc[i] = cb[c4+i];
  #pragma unroll
  for (int k = 0; k < 4; ++k) {
    int lp = l - 3 + k;
    if (lp >= 0) {
      const float4 xv = *(const float4*)&XZ[(size_t)(n - BB*(3-k))*1024 + c4];
      acc[0] = fmaf(w[0][k], xv.x, acc[0]);
      acc[1] = fmaf(w[1][k], xv.y, acc[1]);
      acc[2] = fmaf(w[2][k], xv.z, acc[2]);
      acc[3] = fmaf(w[3][k], xv.w, acc[3]);
    }
  }
  float4 o;
  o.x = siluf(acc[0]); o.y = siluf(acc[1]); o.z = siluf(acc[2]); o.w = siluf(acc[3]);
  *(float4*)&XP[(size_t)n*DINNER + c4] = o;
}

// ---------------- fused x_dbl = xp@W_x ; dt = softplus(x_dbl[:,:16]@W_dt + b_dt); emit B,C
// 64 tokens per 256-thread block. SH reused: XPs (64x132) during GEMM, XDs (64x52) after.
__global__ __launch_bounds__(256) void xdbl_dt_k(const float* __restrict__ XP,
    const float* __restrict__ Wx, const float* __restrict__ Wdt, const float* __restrict__ bdt,
    float* __restrict__ DT, float* __restrict__ BM, float* __restrict__ CM)
{
  __shared__ __align__(16) float SH[64*132];
  __shared__ __align__(16) float Ws[128*49];
  const int tid = threadIdx.x;
  const int tb = blockIdx.x * 64;
  const int t2 = tid >> 2, jq = tid & 3;
  float acc[12];
  #pragma unroll
  for (int i = 0; i < 12; ++i) acc[i] = 0.f;
  for (int kc = 0; kc < 4; ++kc) {
    for (int e = tid; e < 64*32; e += 256) {
      int m = e >> 5, kq = e & 31;
      float4 v = *(const float4*)&XP[(size_t)(tb+m)*DINNER + kc*128 + kq*4];
      SH[m*132 + kq*4+0] = v.x; SH[m*132 + kq*4+1] = v.y;
      SH[m*132 + kq*4+2] = v.z; SH[m*132 + kq*4+3] = v.w;
    }
    for (int e = tid; e < 128*12; e += 256) {
      int kk = e / 12, nq = e % 12;
      float4 v = *(const float4*)&Wx[(size_t)(kc*128+kk)*48 + nq*4];
      Ws[kk*49 + nq*4+0] = v.x; Ws[kk*49 + nq*4+1] = v.y;
      Ws[kk*49 + nq*4+2] = v.z; Ws[kk*49 + nq*4+3] = v.w;
    }
    __syncthreads();
    for (int kk = 0; kk < 128; ++kk) {
      float xv = SH[t2*132 + kk];
      #pragma unroll
      for (int i = 0; i < 12; ++i)
        acc[i] = fmaf(xv, Ws[kk*49 + jq + 4*i], acc[i]);
    }
    __syncthreads();
  }
  // SH now reused as XDs[64][52]
  #pragma unroll
  for (int i = 0; i < 12; ++i) SH[t2*52 + jq + 4*i] = acc[i];
  __syncthreads();
  for (int e = tid; e < 64*16; e += 256) {
    int t = e >> 4, s2 = e & 15;
    BM[(size_t)(tb+t)*16 + s2] = SH[t*52 + 16+s2];
    CM[(size_t)(tb+t)*16 + s2] = SH[t*52 + 32+s2];
  }
  #pragma unroll
  for (int cc = 0; cc < 2; ++cc) {
    int c = cc*256 + tid;
    float wreg[16];
    #pragma unroll
    for (int r = 0; r < 16; ++r) wreg[r] = Wdt[r*DINNER + c];
    float bd = bdt[c];
    for (int t = 0; t < 64; ++t) {
      float sum = bd;
      #pragma unroll
      for (int r = 0; r < 16; ++r) sum = fmaf(SH[t*52 + r], wreg[r], sum);
      DT[(size_t)(tb+t)*DINNER + c] = (sum > 20.f) ? sum : log1pf(__expf(sum));
    }
  }
}

// ---------------- selective scan: lane = (channel_local, state); LDS-staged 128-step chunks
#define SCT 128
__global__ __launch_bounds__(256) void scan_k(const float* __restrict__ DT,
    const float* __restrict__ XP, const float* __restrict__ BM, const float* __restrict__ CM,
    const float* __restrict__ XZ, const float* __restrict__ Alog, const float* __restrict__ Dp,
    float* __restrict__ YG)
{
  __shared__ __align__(16) float DTs[16][SCT+4];
  __shared__ __align__(16) float XPs[16][SCT+4];
  __shared__ __align__(16) float Bls[16][SCT+4];
  __shared__ __align__(16) float Cls[16][SCT+4];
  __shared__ __align__(16) float Ys [16][SCT+4];
  const int tid = threadIdx.x;
  const int cblk = blockIdx.x, b = blockIdx.y;
  const int cl = tid >> 4, s = tid & 15;
  const int c = cblk*16 + cl;
  const float Acs = -__expf(Alog[c*16 + s]);
  float h = 0.f;
  for (int t0 = 0; t0 < LSEQ; t0 += SCT) {
    for (int e = tid; e < 16*SCT; e += 256) {
      int t = e >> 4, cc = e & 15;
      size_t n = (size_t)(t0 + t)*BB + b;
      DTs[cc][t] = DT[n*DINNER + cblk*16 + cc];
      XPs[cc][t] = XP[n*DINNER + cblk*16 + cc];
      Bls[cc][t] = BM[n*16 + cc];
      Cls[cc][t] = CM[n*16 + cc];
    }
    __syncthreads();
    for (int tt = 0; tt < SCT; tt += 4) {
      float4 d4 = *(const float4*)&DTs[cl][tt];
      float4 x4 = *(const float4*)&XPs[cl][tt];
      float4 b4 = *(const float4*)&Bls[s][tt];
      float4 c4 = *(const float4*)&Cls[s][tt];
      #pragma unroll
      for (int j = 0; j < 4; ++j) {
        float dtv = ((const float*)&d4)[j];
        float xv  = ((const float*)&x4)[j];
        float bvv = ((const float*)&b4)[j];
        float cvv = ((const float*)&c4)[j];
        float dA = __expf(dtv * Acs);
        h = fmaf(dA, h, dtv * xv * bvv);
        float y = h * cvv;
        y += __shfl_xor(y, 1);
        y += __shfl_xor(y, 2);
        y += __shfl_xor(y, 4);
        y += __shfl_xor(y, 8);
        if (s == 0) Ys[cl][tt+j] = y;
      }
    }
    __syncthreads();
    for (int e = tid; e < 16*SCT; e += 256) {
      int t = e >> 4, cc = e & 15;
      size_t n = (size_t)(t0 + t)*BB + b;
      int cg = cblk*16 + cc;
      float z = XZ[n*1024 + DINNER + cg];
      float y = Ys[cc][t] + XPs[cc][t] * Dp[cg];
      YG[n*DINNER + cg] = y * siluf(z);
    }
    __syncthreads();
  }
}

// ---------------- action head + Normal log-prob, 8 tokens/block (32 lanes per token)
__global__ __launch_bounds__(256) void head_logp_k(const float* __restrict__ X2,
    const float* __restrict__ Wh, const float* __restrict__ bh, const float* __restrict__ lstd,
    const float* __restrict__ a, float* __restrict__ out)
{
  int n = blockIdx.x*8 + (threadIdx.x >> 5);
  int j = threadIdx.x & 31;
  float accv = bh[j];
  const float* xr = &X2[(size_t)n*DMODEL];
  for (int k = 0; k < DMODEL; k += 4) {
    float4 xv = *(const float4*)&xr[k];
    accv = fmaf(xv.x, Wh[(k+0)*32 + j], accv);
    accv = fmaf(xv.y, Wh[(k+1)*32 + j], accv);
    accv = fmaf(xv.z, Wh[(k+2)*32 + j], accv);
    accv = fmaf(xv.w, Wh[(k+3)*32 + j], accv);
  }
  float ls = lstd[j];
  float z = (a[(size_t)n*32 + j] - accv) * __expf(-ls);
  float t = -0.5f*z*z - ls - 0.91893853320467274f;   // 0.5*log(2*pi)
  t += __shfl_xor(t, 1);
  t += __shfl_xor(t, 2);
  t += __shfl_xor(t, 4);
  t += __shfl_xor(t, 8);
  t += __shfl_xor(t, 16);
  if (j == 0) out[n] = t;
}

extern "C" void kernel_launch(void* const* d_in, const int* in_sizes, int n_in,
                              void* d_out, int out_size, void* d_ws, size_t ws_size,
                              hipStream_t stream)
{
  const float* s    = (const float*)d_in[0];
  const float* a    = (const float*)d_in[1];
  const float* Wemb = (const float*)d_in[2];
  const float* bemb = (const float*)d_in[3];
  const float* nw   = (const float*)d_in[4];
  const float* Win  = (const float*)d_in[5];
  const float* cw   = (const float*)d_in[6];
  const float* cb   = (const float*)d_in[7];
  const float* Wx   = (const float*)d_in[8];
  const float* Wdt  = (const float*)d_in[9];
  const float* bdt  = (const float*)d_in[10];
  const float* Alog = (const float*)d_in[11];
  const float* Dp   = (const float*)d_in[12];
  const float* Wout = (const float*)d_in[13];
  const float* Wh   = (const float*)d_in[14];
  const float* bh   = (const float*)d_in[15];
  const float* lstd = (const float*)d_in[16];

  float* X  = (float*)d_ws;                    // resid / final hidden (in-place)
  float* XN = X  + (size_t)NTOK*DMODEL;
  float* XZ = XN + (size_t)NTOK*DMODEL;        // [xp | z], 1024 wide
  float* XP = XZ + (size_t)NTOK*1024;
  float* DT = XP + (size_t)NTOK*DINNER;
  float* BM = DT + (size_t)NTOK*DINNER;
  float* CM = BM + (size_t)NTOK*16;
  float* YG = CM + (size_t)NTOK*16;
  float* out = (float*)d_out;

  gemm128    <<<dim3(128,2), 256, 0, stream>>>(s,  Wemb, bemb,   nullptr, X,  NTOK, DMODEL, 128);
  rmsnorm_k  <<<4096,        256, 0, stream>>>(X, nw, XN);
  gemm128    <<<dim3(128,8), 256, 0, stream>>>(XN, Win,  nullptr, nullptr, XZ, NTOK, 1024, DMODEL);
  conv_silu_k<<<8192,        256, 0, stream>>>(XZ, cw, cb, XP);
  xdbl_dt_k  <<<256,         256, 0, stream>>>(XP, Wx, Wdt, bdt, DT, BM, CM);
  scan_k     <<<dim3(32,8),  256, 0, stream>>>(DT, XP, BM, CM, XZ, Alog, Dp, YG);
  gemm128    <<<dim3(128,2), 256, 0, stream>>>(YG, Wout, nullptr, X,       X,  NTOK, DMODEL, DINNER);
  head_logp_k<<<2048,        256, 0, stream>>>(X, Wh, bh, lstd, a, out);
}

// Round 4
// 556.273 us; speedup vs baseline: 1.5358x; 1.5358x over previous
//
#include <hip/hip_runtime.h>

#define LSEQ 2048
#define BB 8
#define NTOK (LSEQ*BB)        // 16384 tokens, n = l*B + b
#define DMODEL 256
#define DINNER 512

__device__ __forceinline__ float siluf(float x){ return x / (1.f + __expf(-x)); }

// ---------------- 128x128 tiled fp32 GEMM: C = A(MxK) @ W(KxN) [+bias][+resid]
__global__ __launch_bounds__(256) void gemm128(
    const float* __restrict__ A, const float* __restrict__ W,
    const float* __restrict__ bias, const float* resid,
    float* C, int M, int N, int K)
{
  __shared__ __align__(16) float As[16][132];
  __shared__ __align__(16) float Bs[16][132];
  const int tid = threadIdx.x;
  const int tx = tid & 15, ty = tid >> 4;
  const int bm = blockIdx.x * 128, bn = blockIdx.y * 128;
  float acc[8][8];
  #pragma unroll
  for (int i = 0; i < 8; ++i)
    #pragma unroll
    for (int j = 0; j < 8; ++j) acc[i][j] = 0.f;

  for (int k0 = 0; k0 < K; k0 += 16) {
    #pragma unroll
    for (int e0 = 0; e0 < 2; ++e0) {
      int e = tid + e0*256;
      int m = e >> 2, kq = e & 3;
      float4 v = *(const float4*)&A[(size_t)(bm+m)*K + k0 + kq*4];
      As[kq*4+0][m] = v.x; As[kq*4+1][m] = v.y;
      As[kq*4+2][m] = v.z; As[kq*4+3][m] = v.w;
    }
    #pragma unroll
    for (int e0 = 0; e0 < 2; ++e0) {
      int e = tid + e0*256;
      int kk = e >> 5, nq = e & 31;
      float4 v = *(const float4*)&W[(size_t)(k0+kk)*N + bn + nq*4];
      *(float4*)&Bs[kk][nq*4] = v;
    }
    __syncthreads();
    #pragma unroll
    for (int kk = 0; kk < 16; ++kk) {
      float av[8], bv[8];
      float4 a0 = *(const float4*)&As[kk][ty*4];
      float4 a1 = *(const float4*)&As[kk][64 + ty*4];
      float4 b0 = *(const float4*)&Bs[kk][tx*4];
      float4 b1 = *(const float4*)&Bs[kk][64 + tx*4];
      av[0]=a0.x; av[1]=a0.y; av[2]=a0.z; av[3]=a0.w;
      av[4]=a1.x; av[5]=a1.y; av[6]=a1.z; av[7]=a1.w;
      bv[0]=b0.x; bv[1]=b0.y; bv[2]=b0.z; bv[3]=b0.w;
      bv[4]=b1.x; bv[5]=b1.y; bv[6]=b1.z; bv[7]=b1.w;
      #pragma unroll
      for (int i = 0; i < 8; ++i)
        #pragma unroll
        for (int j = 0; j < 8; ++j)
          acc[i][j] = fmaf(av[i], bv[j], acc[i][j]);
    }
    __syncthreads();
  }
  #pragma unroll
  for (int i = 0; i < 8; ++i) {
    int m = bm + ((i < 4) ? (ty*4 + i) : (64 + ty*4 + (i-4)));
    #pragma unroll
    for (int jh = 0; jh < 2; ++jh) {
      int n0 = bn + jh*64 + tx*4;
      float4 v; float* pv = (float*)&v;
      #pragma unroll
      for (int j = 0; j < 4; ++j) {
        float t = acc[i][jh*4+j];
        if (bias) t += bias[n0+j];
        pv[j] = t;
      }
      if (resid) {
        float4 r = *(const float4*)&resid[(size_t)m*N + n0];
        v.x += r.x; v.y += r.y; v.z += r.z; v.w += r.w;
      }
      *(float4*)&C[(size_t)m*N + n0] = v;
    }
  }
}

// ---------------- RMSNorm: one wave per token (4 tokens / 256-thread block)
__global__ __launch_bounds__(256) void rmsnorm_k(const float* __restrict__ X,
    const float* __restrict__ w, float* __restrict__ XN)
{
  int n = blockIdx.x*4 + (threadIdx.x >> 6);
  int lane = threadIdx.x & 63;
  const float4 x = *(const float4*)&X[(size_t)n*DMODEL + lane*4];
  float ss = x.x*x.x + x.y*x.y + x.z*x.z + x.w*x.w;
  #pragma unroll
  for (int m = 1; m < 64; m <<= 1) ss += __shfl_xor(ss, m);
  float r = rsqrtf(ss * (1.f/DMODEL) + 1e-5f);
  float4 o;
  o.x = x.x * r * w[lane*4+0];
  o.y = x.y * r * w[lane*4+1];
  o.z = x.z * r * w[lane*4+2];
  o.w = x.w * r * w[lane*4+3];
  *(float4*)&XN[(size_t)n*DMODEL + lane*4] = o;
}

// ---------------- causal depthwise conv (K=4) + SiLU; xp = first 512 cols of XZ
__global__ __launch_bounds__(256) void conv_silu_k(const float* __restrict__ XZ,
    const float* __restrict__ cw, const float* __restrict__ cb, float* __restrict__ XP)
{
  int g = blockIdx.x*256 + threadIdx.x;   // NTOK * 128 c4-groups
  int c4 = (g & 127) << 2;
  int n = g >> 7;
  int l = n >> 3;
  float w[4][4];
  #pragma unroll
  for (int i = 0; i < 4; ++i)
    #pragma unroll
    for (int k = 0; k < 4; ++k) w[i][k] = cw[(c4+i)*4 + k];
  float acc[4];
  #pragma unroll
  for (int i = 0; i < 4; ++i) acc[i] = cb[c4+i];
  #pragma unroll
  for (int k = 0; k < 4; ++k) {
    int lp = l - 3 + k;
    if (lp >= 0) {
      const float4 xv = *(const float4*)&XZ[(size_t)(n - BB*(3-k))*1024 + c4];
      acc[0] = fmaf(w[0][k], xv.x, acc[0]);
      acc[1] = fmaf(w[1][k], xv.y, acc[1]);
      acc[2] = fmaf(w[2][k], xv.z, acc[2]);
      acc[3] = fmaf(w[3][k], xv.w, acc[3]);
    }
  }
  float4 o;
  o.x = siluf(acc[0]); o.y = siluf(acc[1]); o.z = siluf(acc[2]); o.w = siluf(acc[3]);
  *(float4*)&XP[(size_t)n*DINNER + c4] = o;
}

// ---------------- fused x_dbl = xp@W_x ; dt = softplus(x_dbl[:,:16]@W_dt + b_dt); emit B,C
__global__ __launch_bounds__(256) void xdbl_dt_k(const float* __restrict__ XP,
    const float* __restrict__ Wx, const float* __restrict__ Wdt, const float* __restrict__ bdt,
    float* __restrict__ DT, float* __restrict__ BM, float* __restrict__ CM)
{
  __shared__ __align__(16) float SH[64*132];
  __shared__ __align__(16) float Ws[128*49];
  const int tid = threadIdx.x;
  const int tb = blockIdx.x * 64;
  const int t2 = tid >> 2, jq = tid & 3;
  float acc[12];
  #pragma unroll
  for (int i = 0; i < 12; ++i) acc[i] = 0.f;
  for (int kc = 0; kc < 4; ++kc) {
    for (int e = tid; e < 64*32; e += 256) {
      int m = e >> 5, kq = e & 31;
      float4 v = *(const float4*)&XP[(size_t)(tb+m)*DINNER + kc*128 + kq*4];
      SH[m*132 + kq*4+0] = v.x; SH[m*132 + kq*4+1] = v.y;
      SH[m*132 + kq*4+2] = v.z; SH[m*132 + kq*4+3] = v.w;
    }
    for (int e = tid; e < 128*12; e += 256) {
      int kk = e / 12, nq = e % 12;
      float4 v = *(const float4*)&Wx[(size_t)(kc*128+kk)*48 + nq*4];
      Ws[kk*49 + nq*4+0] = v.x; Ws[kk*49 + nq*4+1] = v.y;
      Ws[kk*49 + nq*4+2] = v.z; Ws[kk*49 + nq*4+3] = v.w;
    }
    __syncthreads();
    for (int kk = 0; kk < 128; ++kk) {
      float xv = SH[t2*132 + kk];
      #pragma unroll
      for (int i = 0; i < 12; ++i)
        acc[i] = fmaf(xv, Ws[kk*49 + jq + 4*i], acc[i]);
    }
    __syncthreads();
  }
  #pragma unroll
  for (int i = 0; i < 12; ++i) SH[t2*52 + jq + 4*i] = acc[i];
  __syncthreads();
  for (int e = tid; e < 64*16; e += 256) {
    int t = e >> 4, s2 = e & 15;
    BM[(size_t)(tb+t)*16 + s2] = SH[t*52 + 16+s2];
    CM[(size_t)(tb+t)*16 + s2] = SH[t*52 + 32+s2];
  }
  #pragma unroll
  for (int cc = 0; cc < 2; ++cc) {
    int c = cc*256 + tid;
    float wreg[16];
    #pragma unroll
    for (int r = 0; r < 16; ++r) wreg[r] = Wdt[r*DINNER + c];
    float bd = bdt[c];
    for (int t = 0; t < 64; ++t) {
      float sum = bd;
      #pragma unroll
      for (int r = 0; r < 16; ++r) sum = fmaf(SH[t*52 + r], wreg[r], sum);
      DT[(size_t)(tb+t)*DINNER + c] = (sum > 20.f) ? sum : log1pf(__expf(sum));
    }
  }
}

// ---------------- selective scan, no cross-lane ops in the step loop.
// Block = (cblk, b); lane = (cl = channel, s = state). Per step each lane
// fire-and-forget ds_writes its partial h*C into P[t][s][cl]; a post-chunk
// phase reduces over s and fuses +xp*D, *silu(z), global write.
// Strides: stage rows 36 words (<=2-way), P: t-pitch 280 (280%32=24 -> 2-way
// on reduce reads), s-pitch 17 (<=3-way on step writes).
#define SCT 32
#define STR 36
#define PSTR 280
__global__ __launch_bounds__(256) void scan_k(const float* __restrict__ DT,
    const float* __restrict__ XP, const float* __restrict__ BM, const float* __restrict__ CM,
    const float* __restrict__ XZ, const float* __restrict__ Alog, const float* __restrict__ Dp,
    float* __restrict__ YG)
{
  __shared__ __align__(16) float ST[5*16*STR];
  __shared__ __align__(16) float P[SCT*PSTR];
  float* DTs = ST;                // [cc][t] -> cc*STR + t
  float* XPs = ST + 16*STR;
  float* Bls = ST + 32*STR;
  float* Cls = ST + 48*STR;
  float* Zs  = ST + 64*STR;
  const int tid = threadIdx.x;
  const int cblk = blockIdx.x, b = blockIdx.y;
  const int cl = tid >> 4, s = tid & 15;
  const int c = cblk*16 + cl;
  const float Acs = -__expf(Alog[c*16 + s]);
  // reduce-phase fixed mapping: cc_r = tid&15, t_r in {tid>>4, tid>>4 + 16}
  const int cc_r = tid & 15;
  const float Dv = Dp[cblk*16 + cc_r];
  float h = 0.f;
  float* pw = &P[s*17 + cl];
  for (int t0 = 0; t0 < LSEQ; t0 += SCT) {
    // ---- stage (incl. z prefetch)
    #pragma unroll
    for (int e0 = 0; e0 < 2; ++e0) {
      int e = tid + e0*256;
      int t = e >> 4, cc = e & 15;
      size_t n = (size_t)(t0 + t)*BB + b;
      DTs[cc*STR + t] = DT[n*DINNER + cblk*16 + cc];
      XPs[cc*STR + t] = XP[n*DINNER + cblk*16 + cc];
      Bls[cc*STR + t] = BM[n*16 + cc];
      Cls[cc*STR + t] = CM[n*16 + cc];
      Zs [cc*STR + t] = XZ[n*1024 + DINNER + cblk*16 + cc];
    }
    __syncthreads();
    // ---- step loop: recurrence + partial store (no cross-lane, no waits)
    for (int tt = 0; tt < SCT; tt += 4) {
      float4 d4 = *(const float4*)&DTs[cl*STR + tt];
      float4 x4 = *(const float4*)&XPs[cl*STR + tt];
      float4 b4 = *(const float4*)&Bls[s*STR + tt];
      float4 c4 = *(const float4*)&Cls[s*STR + tt];
      #pragma unroll
      for (int j = 0; j < 4; ++j) {
        float dtv = ((const float*)&d4)[j];
        float xv  = ((const float*)&x4)[j];
        float bvv = ((const float*)&b4)[j];
        float cvv = ((const float*)&c4)[j];
        float dA = __expf(dtv * Acs);
        h = fmaf(dA, h, dtv * xv * bvv);
        pw[(tt+j)*PSTR] = h * cvv;
      }
    }
    __syncthreads();
    // ---- reduce over s + gate + coalesced global write
    #pragma unroll
    for (int e0 = 0; e0 < 2; ++e0) {
      int t = (tid >> 4) + e0*16;
      const float* pr = &P[t*PSTR + cc_r];
      float p0 = pr[0*17],  p1 = pr[1*17],  p2 = pr[2*17],  p3 = pr[3*17];
      float p4 = pr[4*17],  p5 = pr[5*17],  p6 = pr[6*17],  p7 = pr[7*17];
      float p8 = pr[8*17],  p9 = pr[9*17],  pa = pr[10*17], pb = pr[11*17];
      float pc = pr[12*17], pd = pr[13*17], pe = pr[14*17], pf = pr[15*17];
      float sum = ((p0+p1)+(p2+p3)) + ((p4+p5)+(p6+p7))
                + ((p8+p9)+(pa+pb)) + ((pc+pd)+(pe+pf));
      float xp = XPs[cc_r*STR + t];
      float z  = Zs [cc_r*STR + t];
      size_t n = (size_t)(t0 + t)*BB + b;
      YG[n*DINNER + cblk*16 + cc_r] = (sum + xp*Dv) * siluf(z);
    }
    __syncthreads();
  }
}

// ---------------- action head + Normal log-prob, 8 tokens/block (32 lanes per token)
__global__ __launch_bounds__(256) void head_logp_k(const float* __restrict__ X2,
    const float* __restrict__ Wh, const float* __restrict__ bh, const float* __restrict__ lstd,
    const float* __restrict__ a, float* __restrict__ out)
{
  int n = blockIdx.x*8 + (threadIdx.x >> 5);
  int j = threadIdx.x & 31;
  float accv = bh[j];
  const float* xr = &X2[(size_t)n*DMODEL];
  for (int k = 0; k < DMODEL; k += 4) {
    float4 xv = *(const float4*)&xr[k];
    accv = fmaf(xv.x, Wh[(k+0)*32 + j], accv);
    accv = fmaf(xv.y, Wh[(k+1)*32 + j], accv);
    accv = fmaf(xv.z, Wh[(k+2)*32 + j], accv);
    accv = fmaf(xv.w, Wh[(k+3)*32 + j], accv);
  }
  float ls = lstd[j];
  float z = (a[(size_t)n*32 + j] - accv) * __expf(-ls);
  float t = -0.5f*z*z - ls - 0.91893853320467274f;   // 0.5*log(2*pi)
  t += __shfl_xor(t, 1);
  t += __shfl_xor(t, 2);
  t += __shfl_xor(t, 4);
  t += __shfl_xor(t, 8);
  t += __shfl_xor(t, 16);
  if (j == 0) out[n] = t;
}

extern "C" void kernel_launch(void* const* d_in, const int* in_sizes, int n_in,
                              void* d_out, int out_size, void* d_ws, size_t ws_size,
                              hipStream_t stream)
{
  const float* s    = (const float*)d_in[0];
  const float* a    = (const float*)d_in[1];
  const float* Wemb = (const float*)d_in[2];
  const float* bemb = (const float*)d_in[3];
  const float* nw   = (const float*)d_in[4];
  const float* Win  = (const float*)d_in[5];
  const float* cw   = (const float*)d_in[6];
  const float* cb   = (const float*)d_in[7];
  const float* Wx   = (const float*)d_in[8];
  const float* Wdt  = (const float*)d_in[9];
  const float* bdt  = (const float*)d_in[10];
  const float* Alog = (const float*)d_in[11];
  const float* Dp   = (const float*)d_in[12];
  const float* Wout = (const float*)d_in[13];
  const float* Wh   = (const float*)d_in[14];
  const float* bh   = (const float*)d_in[15];
  const float* lstd = (const float*)d_in[16];

  float* X  = (float*)d_ws;                    // resid / final hidden (in-place)
  float* XN = X  + (size_t)NTOK*DMODEL;
  float* XZ = XN + (size_t)NTOK*DMODEL;        // [xp | z], 1024 wide
  float* XP = XZ + (size_t)NTOK*1024;
  float* DT = XP + (size_t)NTOK*DINNER;
  float* BM = DT + (size_t)NTOK*DINNER;
  float* CM = BM + (size_t)NTOK*16;
  float* YG = CM + (size_t)NTOK*16;
  float* out = (float*)d_out;

  gemm128    <<<dim3(128,2), 256, 0, stream>>>(s,  Wemb, bemb,   nullptr, X,  NTOK, DMODEL, 128);
  rmsnorm_k  <<<4096,        256, 0, stream>>>(X, nw, XN);
  gemm128    <<<dim3(128,8), 256, 0, stream>>>(XN, Win,  nullptr, nullptr, XZ, NTOK, 1024, DMODEL);
  conv_silu_k<<<8192,        256, 0, stream>>>(XZ, cw, cb, XP);
  xdbl_dt_k  <<<256,         256, 0, stream>>>(XP, Wx, Wdt, bdt, DT, BM, CM);
  scan_k     <<<dim3(32,8),  256, 0, stream>>>(DT, XP, BM, CM, XZ, Alog, Dp, YG);
  gemm128    <<<dim3(128,2), 256, 0, stream>>>(YG, Wout, nullptr, X,       X,  NTOK, DMODEL, DINNER);
  head_logp_k<<<2048,        256, 0, stream>>>(X, Wh, bh, lstd, a, out);
}

// Round 5
// 509.776 us; speedup vs baseline: 1.6759x; 1.0912x over previous
//
#include <hip/hip_runtime.h>

#define LSEQ 2048
#define BB 8
#define NTOK (LSEQ*BB)        // 16384 tokens, n = l*B + b
#define DMODEL 256
#define DINNER 512
#define NSEG 64
#define SEGLEN 32             // LSEQ / NSEG

__device__ __forceinline__ float siluf(float x){ return x / (1.f + __expf(-x)); }

// ---------------- 128x128 tiled fp32 GEMM: C = A(MxK) @ W(KxN) [+bias][+resid]
__global__ __launch_bounds__(256) void gemm128(
    const float* __restrict__ A, const float* __restrict__ W,
    const float* __restrict__ bias, const float* resid,
    float* C, int M, int N, int K)
{
  __shared__ __align__(16) float As[16][132];
  __shared__ __align__(16) float Bs[16][132];
  const int tid = threadIdx.x;
  const int tx = tid & 15, ty = tid >> 4;
  const int bm = blockIdx.x * 128, bn = blockIdx.y * 128;
  float acc[8][8];
  #pragma unroll
  for (int i = 0; i < 8; ++i)
    #pragma unroll
    for (int j = 0; j < 8; ++j) acc[i][j] = 0.f;

  for (int k0 = 0; k0 < K; k0 += 16) {
    #pragma unroll
    for (int e0 = 0; e0 < 2; ++e0) {
      int e = tid + e0*256;
      int m = e >> 2, kq = e & 3;
      float4 v = *(const float4*)&A[(size_t)(bm+m)*K + k0 + kq*4];
      As[kq*4+0][m] = v.x; As[kq*4+1][m] = v.y;
      As[kq*4+2][m] = v.z; As[kq*4+3][m] = v.w;
    }
    #pragma unroll
    for (int e0 = 0; e0 < 2; ++e0) {
      int e = tid + e0*256;
      int kk = e >> 5, nq = e & 31;
      float4 v = *(const float4*)&W[(size_t)(k0+kk)*N + bn + nq*4];
      *(float4*)&Bs[kk][nq*4] = v;
    }
    __syncthreads();
    #pragma unroll
    for (int kk = 0; kk < 16; ++kk) {
      float av[8], bv[8];
      float4 a0 = *(const float4*)&As[kk][ty*4];
      float4 a1 = *(const float4*)&As[kk][64 + ty*4];
      float4 b0 = *(const float4*)&Bs[kk][tx*4];
      float4 b1 = *(const float4*)&Bs[kk][64 + tx*4];
      av[0]=a0.x; av[1]=a0.y; av[2]=a0.z; av[3]=a0.w;
      av[4]=a1.x; av[5]=a1.y; av[6]=a1.z; av[7]=a1.w;
      bv[0]=b0.x; bv[1]=b0.y; bv[2]=b0.z; bv[3]=b0.w;
      bv[4]=b1.x; bv[5]=b1.y; bv[6]=b1.z; bv[7]=b1.w;
      #pragma unroll
      for (int i = 0; i < 8; ++i)
        #pragma unroll
        for (int j = 0; j < 8; ++j)
          acc[i][j] = fmaf(av[i], bv[j], acc[i][j]);
    }
    __syncthreads();
  }
  #pragma unroll
  for (int i = 0; i < 8; ++i) {
    int m = bm + ((i < 4) ? (ty*4 + i) : (64 + ty*4 + (i-4)));
    #pragma unroll
    for (int jh = 0; jh < 2; ++jh) {
      int n0 = bn + jh*64 + tx*4;
      float4 v; float* pv = (float*)&v;
      #pragma unroll
      for (int j = 0; j < 4; ++j) {
        float t = acc[i][jh*4+j];
        if (bias) t += bias[n0+j];
        pv[j] = t;
      }
      if (resid) {
        float4 r = *(const float4*)&resid[(size_t)m*N + n0];
        v.x += r.x; v.y += r.y; v.z += r.z; v.w += r.w;
      }
      *(float4*)&C[(size_t)m*N + n0] = v;
    }
  }
}

// ---------------- RMSNorm: one wave per token (4 tokens / 256-thread block)
__global__ __launch_bounds__(256) void rmsnorm_k(const float* __restrict__ X,
    const float* __restrict__ w, float* __restrict__ XN)
{
  int n = blockIdx.x*4 + (threadIdx.x >> 6);
  int lane = threadIdx.x & 63;
  const float4 x = *(const float4*)&X[(size_t)n*DMODEL + lane*4];
  float ss = x.x*x.x + x.y*x.y + x.z*x.z + x.w*x.w;
  #pragma unroll
  for (int m = 1; m < 64; m <<= 1) ss += __shfl_xor(ss, m);
  float r = rsqrtf(ss * (1.f/DMODEL) + 1e-5f);
  float4 o;
  o.x = x.x * r * w[lane*4+0];
  o.y = x.y * r * w[lane*4+1];
  o.z = x.z * r * w[lane*4+2];
  o.w = x.w * r * w[lane*4+3];
  *(float4*)&XN[(size_t)n*DMODEL + lane*4] = o;
}

// ---------------- causal depthwise conv (K=4) + SiLU; xp = first 512 cols of XZ
__global__ __launch_bounds__(256) void conv_silu_k(const float* __restrict__ XZ,
    const float* __restrict__ cw, const float* __restrict__ cb, float* __restrict__ XP)
{
  int g = blockIdx.x*256 + threadIdx.x;   // NTOK * 128 c4-groups
  int c4 = (g & 127) << 2;
  int n = g >> 7;
  int l = n >> 3;
  float w[4][4];
  #pragma unroll
  for (int i = 0; i < 4; ++i)
    #pragma unroll
    for (int k = 0; k < 4; ++k) w[i][k] = cw[(c4+i)*4 + k];
  float acc[4];
  #pragma unroll
  for (int i = 0; i < 4; ++i) acc[i] = cb[c4+i];
  #pragma unroll
  for (int k = 0; k < 4; ++k) {
    int lp = l - 3 + k;
    if (lp >= 0) {
      const float4 xv = *(const float4*)&XZ[(size_t)(n - BB*(3-k))*1024 + c4];
      acc[0] = fmaf(w[0][k], xv.x, acc[0]);
      acc[1] = fmaf(w[1][k], xv.y, acc[1]);
      acc[2] = fmaf(w[2][k], xv.z, acc[2]);
      acc[3] = fmaf(w[3][k], xv.w, acc[3]);
    }
  }
  float4 o;
  o.x = siluf(acc[0]); o.y = siluf(acc[1]); o.z = siluf(acc[2]); o.w = siluf(acc[3]);
  *(float4*)&XP[(size_t)n*DINNER + c4] = o;
}

// ---------------- fused x_dbl = xp@W_x ; dt = softplus(x_dbl[:,:16]@W_dt + b_dt); emit B,C
__global__ __launch_bounds__(256) void xdbl_dt_k(const float* __restrict__ XP,
    const float* __restrict__ Wx, const float* __restrict__ Wdt, const float* __restrict__ bdt,
    float* __restrict__ DT, float* __restrict__ BM, float* __restrict__ CM)
{
  __shared__ __align__(16) float SH[64*132];
  __shared__ __align__(16) float Ws[128*49];
  const int tid = threadIdx.x;
  const int tb = blockIdx.x * 64;
  const int t2 = tid >> 2, jq = tid & 3;
  float acc[12];
  #pragma unroll
  for (int i = 0; i < 12; ++i) acc[i] = 0.f;
  for (int kc = 0; kc < 4; ++kc) {
    for (int e = tid; e < 64*32; e += 256) {
      int m = e >> 5, kq = e & 31;
      float4 v = *(const float4*)&XP[(size_t)(tb+m)*DINNER + kc*128 + kq*4];
      SH[m*132 + kq*4+0] = v.x; SH[m*132 + kq*4+1] = v.y;
      SH[m*132 + kq*4+2] = v.z; SH[m*132 + kq*4+3] = v.w;
    }
    for (int e = tid; e < 128*12; e += 256) {
      int kk = e / 12, nq = e % 12;
      float4 v = *(const float4*)&Wx[(size_t)(kc*128+kk)*48 + nq*4];
      Ws[kk*49 + nq*4+0] = v.x; Ws[kk*49 + nq*4+1] = v.y;
      Ws[kk*49 + nq*4+2] = v.z; Ws[kk*49 + nq*4+3] = v.w;
    }
    __syncthreads();
    for (int kk = 0; kk < 128; ++kk) {
      float xv = SH[t2*132 + kk];
      #pragma unroll
      for (int i = 0; i < 12; ++i)
        acc[i] = fmaf(xv, Ws[kk*49 + jq + 4*i], acc[i]);
    }
    __syncthreads();
  }
  #pragma unroll
  for (int i = 0; i < 12; ++i) SH[t2*52 + jq + 4*i] = acc[i];
  __syncthreads();
  for (int e = tid; e < 64*16; e += 256) {
    int t = e >> 4, s2 = e & 15;
    BM[(size_t)(tb+t)*16 + s2] = SH[t*52 + 16+s2];
    CM[(size_t)(tb+t)*16 + s2] = SH[t*52 + 32+s2];
  }
  #pragma unroll
  for (int cc = 0; cc < 2; ++cc) {
    int c = cc*256 + tid;
    float wreg[16];
    #pragma unroll
    for (int r = 0; r < 16; ++r) wreg[r] = Wdt[r*DINNER + c];
    float bd = bdt[c];
    for (int t = 0; t < 64; ++t) {
      float sum = bd;
      #pragma unroll
      for (int r = 0; r < 16; ++r) sum = fmaf(SH[t*52 + r], wreg[r], sum);
      DT[(size_t)(tb+t)*DINNER + c] = (sum > 20.f) ? sum : log1pf(__expf(sum));
    }
  }
}

// ---------------- segmented scan, phase A: per-segment h_end (h0=0) + sum(dt).
// Lane = one channel; h[16] states in registers; B_t broadcast from LDS.
// HEND layout: ((seg*BB+b)*DINNER + c)*16 + s.  DTS hides in dead xp-half of XZ rows 0..511.
__global__ __launch_bounds__(256) void scanA_k(const float* __restrict__ DT,
    const float* __restrict__ XP, const float* __restrict__ BM,
    const float* __restrict__ Alog, float* __restrict__ HEND, float* __restrict__ DTS)
{
  __shared__ __align__(16) float Bs[SEGLEN*16];
  const int tid = threadIdx.x;
  const int seg = blockIdx.x, b = blockIdx.y, half = blockIdx.z;
  const int c = half*256 + tid;
  const int t0 = seg*SEGLEN;
  for (int e = tid; e < SEGLEN*16; e += 256) {
    int t = e >> 4, s = e & 15;
    Bs[e] = BM[((size_t)(t0+t)*BB + b)*16 + s];
  }
  float As[16];
  #pragma unroll
  for (int s = 0; s < 16; ++s) As[s] = -__expf(Alog[c*16+s]);
  float h[16];
  #pragma unroll
  for (int s = 0; s < 16; ++s) h[s] = 0.f;
  float dts = 0.f;
  __syncthreads();
  size_t n0 = (size_t)t0*BB + b;
  float dt = DT[n0*DINNER + c];
  float xp = XP[n0*DINNER + c];
  for (int t = 0; t < SEGLEN; ++t) {
    // prefetch next step
    float dtn = 0.f, xpn = 0.f;
    if (t+1 < SEGLEN) {
      size_t nn = (size_t)(t0+t+1)*BB + b;
      dtn = DT[nn*DINNER + c];
      xpn = XP[nn*DINNER + c];
    }
    dts += dt;
    float dtx = dt * xp;
    const float4 b0 = *(const float4*)&Bs[t*16+0];
    const float4 b1 = *(const float4*)&Bs[t*16+4];
    const float4 b2 = *(const float4*)&Bs[t*16+8];
    const float4 b3 = *(const float4*)&Bs[t*16+12];
    const float bv[16] = {b0.x,b0.y,b0.z,b0.w, b1.x,b1.y,b1.z,b1.w,
                          b2.x,b2.y,b2.z,b2.w, b3.x,b3.y,b3.z,b3.w};
    #pragma unroll
    for (int s = 0; s < 16; ++s)
      h[s] = fmaf(__expf(dt*As[s]), h[s], dtx*bv[s]);
    dt = dtn; xp = xpn;
  }
  float* hp = &HEND[(((size_t)seg*BB + b)*DINNER + c)*16];
  #pragma unroll
  for (int q = 0; q < 4; ++q)
    *(float4*)&hp[q*4] = make_float4(h[q*4], h[q*4+1], h[q*4+2], h[q*4+3]);
  DTS[((size_t)seg*BB + b)*1024 + c] = dts;
}

// ---------------- stitch: sequential over 64 segments, in-place HEND -> h0.
// One thread per (b,c,s); 65536 threads.
__global__ __launch_bounds__(256) void stitch_k(float* __restrict__ HEND,
    const float* __restrict__ DTS, const float* __restrict__ Alog)
{
  int g = blockIdx.x*256 + threadIdx.x;
  int b = g >> 13;
  int rem = g & 8191;          // c*16+s
  int cidx = rem >> 4;
  float A = -__expf(Alog[rem]);
  float h0 = 0.f;
  for (int k = 0; k < NSEG; ++k) {
    size_t idx = ((size_t)k*BB + b)*8192 + rem;
    float hend = HEND[idx];
    HEND[idx] = h0;
    float dts = DTS[((size_t)k*BB + b)*1024 + cidx];
    h0 = fmaf(__expf(dts*A), h0, hend);
  }
}

// ---------------- phase C: full scan with correct h0, fused gate + output.
__global__ __launch_bounds__(256) void scanC_k(const float* __restrict__ DT,
    const float* __restrict__ XP, const float* __restrict__ BM, const float* __restrict__ CM,
    const float* __restrict__ XZ, const float* __restrict__ Alog, const float* __restrict__ Dp,
    const float* __restrict__ H0, float* __restrict__ YG)
{
  __shared__ __align__(16) float Bs[SEGLEN*16];
  __shared__ __align__(16) float Cs[SEGLEN*16];
  const int tid = threadIdx.x;
  const int seg = blockIdx.x, b = blockIdx.y, half = blockIdx.z;
  const int c = half*256 + tid;
  const int t0 = seg*SEGLEN;
  for (int e = tid; e < SEGLEN*16; e += 256) {
    int t = e >> 4, s = e & 15;
    size_t nb = ((size_t)(t0+t)*BB + b)*16 + s;
    Bs[e] = BM[nb];
    Cs[e] = CM[nb];
  }
  float As[16];
  #pragma unroll
  for (int s = 0; s < 16; ++s) As[s] = -__expf(Alog[c*16+s]);
  float h[16];
  const float* hp = &H0[(((size_t)seg*BB + b)*DINNER + c)*16];
  #pragma unroll
  for (int q = 0; q < 4; ++q) {
    float4 hv = *(const float4*)&hp[q*4];
    h[q*4+0]=hv.x; h[q*4+1]=hv.y; h[q*4+2]=hv.z; h[q*4+3]=hv.w;
  }
  const float Dv = Dp[c];
  __syncthreads();
  size_t n0 = (size_t)t0*BB + b;
  float dt = DT[n0*DINNER + c];
  float xp = XP[n0*DINNER + c];
  float zg = XZ[n0*1024 + DINNER + c];
  for (int t = 0; t < SEGLEN; ++t) {
    float dtn = 0.f, xpn = 0.f, zgn = 0.f;
    if (t+1 < SEGLEN) {
      size_t nn = (size_t)(t0+t+1)*BB + b;
      dtn = DT[nn*DINNER + c];
      xpn = XP[nn*DINNER + c];
      zgn = XZ[nn*1024 + DINNER + c];
    }
    float dtx = dt * xp;
    const float4 b0 = *(const float4*)&Bs[t*16+0];
    const float4 b1 = *(const float4*)&Bs[t*16+4];
    const float4 b2 = *(const float4*)&Bs[t*16+8];
    const float4 b3 = *(const float4*)&Bs[t*16+12];
    const float4 c0 = *(const float4*)&Cs[t*16+0];
    const float4 c1 = *(const float4*)&Cs[t*16+4];
    const float4 c2 = *(const float4*)&Cs[t*16+8];
    const float4 c3 = *(const float4*)&Cs[t*16+12];
    const float bv[16] = {b0.x,b0.y,b0.z,b0.w, b1.x,b1.y,b1.z,b1.w,
                          b2.x,b2.y,b2.z,b2.w, b3.x,b3.y,b3.z,b3.w};
    const float cv[16] = {c0.x,c0.y,c0.z,c0.w, c1.x,c1.y,c1.z,c1.w,
                          c2.x,c2.y,c2.z,c2.w, c3.x,c3.y,c3.z,c3.w};
    float y0 = 0.f, y1 = 0.f, y2 = 0.f, y3 = 0.f;
    #pragma unroll
    for (int q = 0; q < 4; ++q) {
      h[q*4+0] = fmaf(__expf(dt*As[q*4+0]), h[q*4+0], dtx*bv[q*4+0]);
      h[q*4+1] = fmaf(__expf(dt*As[q*4+1]), h[q*4+1], dtx*bv[q*4+1]);
      h[q*4+2] = fmaf(__expf(dt*As[q*4+2]), h[q*4+2], dtx*bv[q*4+2]);
      h[q*4+3] = fmaf(__expf(dt*As[q*4+3]), h[q*4+3], dtx*bv[q*4+3]);
      y0 = fmaf(h[q*4+0], cv[q*4+0], y0);
      y1 = fmaf(h[q*4+1], cv[q*4+1], y1);
      y2 = fmaf(h[q*4+2], cv[q*4+2], y2);
      y3 = fmaf(h[q*4+3], cv[q*4+3], y3);
    }
    float y = (y0+y1) + (y2+y3);
    size_t n = (size_t)(t0+t)*BB + b;
    YG[n*DINNER + c] = (y + xp*Dv) * siluf(zg);
    dt = dtn; xp = xpn; zg = zgn;
  }
}

// ---------------- action head + Normal log-prob, 8 tokens/block (32 lanes per token)
__global__ __launch_bounds__(256) void head_logp_k(const float* __restrict__ X2,
    const float* __restrict__ Wh, const float* __restrict__ bh, const float* __restrict__ lstd,
    const float* __restrict__ a, float* __restrict__ out)
{
  int n = blockIdx.x*8 + (threadIdx.x >> 5);
  int j = threadIdx.x & 31;
  float accv = bh[j];
  const float* xr = &X2[(size_t)n*DMODEL];
  for (int k = 0; k < DMODEL; k += 4) {
    float4 xv = *(const float4*)&xr[k];
    accv = fmaf(xv.x, Wh[(k+0)*32 + j], accv);
    accv = fmaf(xv.y, Wh[(k+1)*32 + j], accv);
    accv = fmaf(xv.z, Wh[(k+2)*32 + j], accv);
    accv = fmaf(xv.w, Wh[(k+3)*32 + j], accv);
  }
  float ls = lstd[j];
  float z = (a[(size_t)n*32 + j] - accv) * __expf(-ls);
  float t = -0.5f*z*z - ls - 0.91893853320467274f;   // 0.5*log(2*pi)
  t += __shfl_xor(t, 1);
  t += __shfl_xor(t, 2);
  t += __shfl_xor(t, 4);
  t += __shfl_xor(t, 8);
  t += __shfl_xor(t, 16);
  if (j == 0) out[n] = t;
}

extern "C" void kernel_launch(void* const* d_in, const int* in_sizes, int n_in,
                              void* d_out, int out_size, void* d_ws, size_t ws_size,
                              hipStream_t stream)
{
  const float* s    = (const float*)d_in[0];
  const float* a    = (const float*)d_in[1];
  const float* Wemb = (const float*)d_in[2];
  const float* bemb = (const float*)d_in[3];
  const float* nw   = (const float*)d_in[4];
  const float* Win  = (const float*)d_in[5];
  const float* cw   = (const float*)d_in[6];
  const float* cb   = (const float*)d_in[7];
  const float* Wx   = (const float*)d_in[8];
  const float* Wdt  = (const float*)d_in[9];
  const float* bdt  = (const float*)d_in[10];
  const float* Alog = (const float*)d_in[11];
  const float* Dp   = (const float*)d_in[12];
  const float* Wout = (const float*)d_in[13];
  const float* Wh   = (const float*)d_in[14];
  const float* bh   = (const float*)d_in[15];
  const float* lstd = (const float*)d_in[16];

  float* X  = (float*)d_ws;                    // resid / final hidden (in-place)
  float* XN = X  + (size_t)NTOK*DMODEL;        // reused as HEND/H0 after in-proj GEMM
  float* XZ = XN + (size_t)NTOK*DMODEL;        // [xp | z], 1024 wide; rows 0..511 xp-half reused as DTS
  float* XP = XZ + (size_t)NTOK*1024;
  float* DT = XP + (size_t)NTOK*DINNER;
  float* BM = DT + (size_t)NTOK*DINNER;
  float* CM = BM + (size_t)NTOK*16;
  float* YG = CM + (size_t)NTOK*16;
  float* out = (float*)d_out;
  float* HEND = XN;                            // NSEG*BB*DINNER*16 = NTOK*DMODEL floats exactly
  float* DTS  = XZ;                            // indexed (seg*BB+b)*1024 + c  (dead xp-half)

  gemm128    <<<dim3(128,2), 256, 0, stream>>>(s,  Wemb, bemb,   nullptr, X,  NTOK, DMODEL, 128);
  rmsnorm_k  <<<4096,        256, 0, stream>>>(X, nw, XN);
  gemm128    <<<dim3(128,8), 256, 0, stream>>>(XN, Win,  nullptr, nullptr, XZ, NTOK, 1024, DMODEL);
  conv_silu_k<<<8192,        256, 0, stream>>>(XZ, cw, cb, XP);
  xdbl_dt_k  <<<256,         256, 0, stream>>>(XP, Wx, Wdt, bdt, DT, BM, CM);
  scanA_k    <<<dim3(NSEG,BB,2), 256, 0, stream>>>(DT, XP, BM, Alog, HEND, DTS);
  stitch_k   <<<256,         256, 0, stream>>>(HEND, DTS, Alog);
  scanC_k    <<<dim3(NSEG,BB,2), 256, 0, stream>>>(DT, XP, BM, CM, XZ, Alog, Dp, HEND, YG);
  gemm128    <<<dim3(128,2), 256, 0, stream>>>(YG, Wout, nullptr, X,       X,  NTOK, DMODEL, DINNER);
  head_logp_k<<<2048,        256, 0, stream>>>(X, Wh, bh, lstd, a, out);
}

// Round 6
// 409.917 us; speedup vs baseline: 2.0841x; 1.2436x over previous
//
#include <hip/hip_runtime.h>

typedef unsigned short u16;
typedef short bf16x8 __attribute__((ext_vector_type(8)));   // 8 bf16 = 4 VGPR
typedef float floatx4 __attribute__((ext_vector_type(4)));

#define LSEQ 2048
#define BB 8
#define NTOK (LSEQ*BB)        // 16384 tokens, n = l*B + b
#define DMODEL 256
#define DINNER 512
#define NSEG 64
#define SEGLEN 32             // LSEQ / NSEG

__device__ __forceinline__ float siluf(float x){ return x / (1.f + __expf(-x)); }
__device__ __forceinline__ u16 f2b(float f){
  unsigned u = __float_as_uint(f);
  unsigned r = (u + 0x7fffu + ((u >> 16) & 1u)) >> 16;
  return (u16)r;
}

// ---------------- elementwise fp32 -> bf16 cast
__global__ __launch_bounds__(256) void castb_k(const float* __restrict__ in,
    u16* __restrict__ out)
{
  int i = (blockIdx.x*256 + threadIdx.x)*4;
  float4 v = *(const float4*)&in[i];
  ushort4 o; o.x = f2b(v.x); o.y = f2b(v.y); o.z = f2b(v.z); o.w = f2b(v.w);
  *(ushort4*)&out[i] = o;
}

// ---------------- transpose + cast: W[K][N] fp32 -> WT[N][K] bf16 (32x32 LDS tiles)
__global__ __launch_bounds__(256) void tcast_k(const float* __restrict__ W,
    u16* __restrict__ WT, int K, int N)
{
  __shared__ float S[32][33];
  int n0 = blockIdx.x*32, k0 = blockIdx.y*32;
  int tx = threadIdx.x & 31, ty = threadIdx.x >> 5;   // ty 0..7
  #pragma unroll
  for (int i = 0; i < 4; ++i)
    S[ty + 8*i][tx] = W[(size_t)(k0 + ty + 8*i)*N + n0 + tx];
  __syncthreads();
  #pragma unroll
  for (int i = 0; i < 4; ++i)
    WT[(size_t)(n0 + ty + 8*i)*K + k0 + tx] = f2b(S[tx][ty + 8*i]);
}

// ---------------- bf16 MFMA GEMM: C = A(MxK,bf16) @ W(KxN via WT[N][K],bf16) [+bias][+resid]
// 256 thr = 4 waves; block tile 128x128, wave tile 64x64 (4x4 MFMA 16x16x32).
// A-frag: A[m=lane&15][k=quad*8+j]; B-frag: WT[n=lane&15][k=quad*8+j];
// D: col=lane&15, row=quad*4+reg  [m89-verified layout]
template<int K>
__global__ __launch_bounds__(256) void gemm_mfma(
    const u16* __restrict__ Ab, const u16* __restrict__ WT,
    const float* __restrict__ bias, const float* __restrict__ resid,
    float* __restrict__ C, int N)
{
  const int tid = threadIdx.x;
  const int wave = tid >> 6, lane = tid & 63;
  const int quad = lane >> 4, l16 = lane & 15;
  const int bm = blockIdx.x*128 + (wave & 1)*64;
  const int bn = blockIdx.y*128 + (wave >> 1)*64;
  floatx4 acc[4][4];
  #pragma unroll
  for (int r = 0; r < 4; ++r)
    #pragma unroll
    for (int c = 0; c < 4; ++c) acc[r][c] = (floatx4){0.f,0.f,0.f,0.f};

  const u16* Ap = Ab + (size_t)(bm + l16)*K + quad*8;
  const u16* Bp = WT + (size_t)(bn + l16)*K + quad*8;
  #pragma unroll 2
  for (int k0 = 0; k0 < K; k0 += 32) {
    bf16x8 af[4], bf[4];
    #pragma unroll
    for (int r = 0; r < 4; ++r) af[r] = *(const bf16x8*)(Ap + (size_t)r*16*K + k0);
    #pragma unroll
    for (int c = 0; c < 4; ++c) bf[c] = *(const bf16x8*)(Bp + (size_t)c*16*K + k0);
    #pragma unroll
    for (int r = 0; r < 4; ++r)
      #pragma unroll
      for (int c = 0; c < 4; ++c)
        acc[r][c] = __builtin_amdgcn_mfma_f32_16x16x32_bf16(af[r], bf[c], acc[r][c], 0, 0, 0);
  }
  #pragma unroll
  for (int c = 0; c < 4; ++c) {
    int n = bn + c*16 + l16;
    float bv = bias ? bias[n] : 0.f;
    #pragma unroll
    for (int r = 0; r < 4; ++r) {
      #pragma unroll
      for (int reg = 0; reg < 4; ++reg) {
        int m = bm + r*16 + quad*4 + reg;
        float t = acc[r][c][reg] + bv;
        if (resid) t += resid[(size_t)m*N + n];
        C[(size_t)m*N + n] = t;
      }
    }
  }
}

// ---------------- RMSNorm: one wave per token, writes bf16 for the MFMA in-proj
__global__ __launch_bounds__(256) void rmsnorm_k(const float* __restrict__ X,
    const float* __restrict__ w, u16* __restrict__ XNb)
{
  int n = blockIdx.x*4 + (threadIdx.x >> 6);
  int lane = threadIdx.x & 63;
  const float4 x = *(const float4*)&X[(size_t)n*DMODEL + lane*4];
  float ss = x.x*x.x + x.y*x.y + x.z*x.z + x.w*x.w;
  #pragma unroll
  for (int m = 1; m < 64; m <<= 1) ss += __shfl_xor(ss, m);
  float r = rsqrtf(ss * (1.f/DMODEL) + 1e-5f);
  ushort4 o;
  o.x = f2b(x.x * r * w[lane*4+0]);
  o.y = f2b(x.y * r * w[lane*4+1]);
  o.z = f2b(x.z * r * w[lane*4+2]);
  o.w = f2b(x.w * r * w[lane*4+3]);
  *(ushort4*)&XNb[(size_t)n*DMODEL + lane*4] = o;
}

// ---------------- causal depthwise conv (K=4) + SiLU; xp = first 512 cols of XZ
__global__ __launch_bounds__(256) void conv_silu_k(const float* __restrict__ XZ,
    const float* __restrict__ cw, const float* __restrict__ cb, float* __restrict__ XP)
{
  int g = blockIdx.x*256 + threadIdx.x;   // NTOK * 128 c4-groups
  int c4 = (g & 127) << 2;
  int n = g >> 7;
  int l = n >> 3;
  float w[4][4];
  #pragma unroll
  for (int i = 0; i < 4; ++i)
    #pragma unroll
    for (int k = 0; k < 4; ++k) w[i][k] = cw[(c4+i)*4 + k];
  float acc[4];
  #pragma unroll
  for (int i = 0; i < 4; ++i) acc[i] = cb[c4+i];
  #pragma unroll
  for (int k = 0; k < 4; ++k) {
    int lp = l - 3 + k;
    if (lp >= 0) {
      const float4 xv = *(const float4*)&XZ[(size_t)(n - BB*(3-k))*1024 + c4];
      acc[0] = fmaf(w[0][k], xv.x, acc[0]);
      acc[1] = fmaf(w[1][k], xv.y, acc[1]);
      acc[2] = fmaf(w[2][k], xv.z, acc[2]);
      acc[3] = fmaf(w[3][k], xv.w, acc[3]);
    }
  }
  float4 o;
  o.x = siluf(acc[0]); o.y = siluf(acc[1]); o.z = siluf(acc[2]); o.w = siluf(acc[3]);
  *(float4*)&XP[(size_t)n*DINNER + c4] = o;
}

// ---------------- fused x_dbl = xp@W_x ; dt = softplus(x_dbl[:,:16]@W_dt + b_dt); emit B,C
__global__ __launch_bounds__(256) void xdbl_dt_k(const float* __restrict__ XP,
    const float* __restrict__ Wx, const float* __restrict__ Wdt, const float* __restrict__ bdt,
    float* __restrict__ DT, float* __restrict__ BM, float* __restrict__ CM)
{
  __shared__ __align__(16) float SH[64*132];
  __shared__ __align__(16) float Ws[128*49];
  const int tid = threadIdx.x;
  const int tb = blockIdx.x * 64;
  const int t2 = tid >> 2, jq = tid & 3;
  float acc[12];
  #pragma unroll
  for (int i = 0; i < 12; ++i) acc[i] = 0.f;
  for (int kc = 0; kc < 4; ++kc) {
    for (int e = tid; e < 64*32; e += 256) {
      int m = e >> 5, kq = e & 31;
      float4 v = *(const float4*)&XP[(size_t)(tb+m)*DINNER + kc*128 + kq*4];
      SH[m*132 + kq*4+0] = v.x; SH[m*132 + kq*4+1] = v.y;
      SH[m*132 + kq*4+2] = v.z; SH[m*132 + kq*4+3] = v.w;
    }
    for (int e = tid; e < 128*12; e += 256) {
      int kk = e / 12, nq = e % 12;
      float4 v = *(const float4*)&Wx[(size_t)(kc*128+kk)*48 + nq*4];
      Ws[kk*49 + nq*4+0] = v.x; Ws[kk*49 + nq*4+1] = v.y;
      Ws[kk*49 + nq*4+2] = v.z; Ws[kk*49 + nq*4+3] = v.w;
    }
    __syncthreads();
    for (int kk = 0; kk < 128; ++kk) {
      float xv = SH[t2*132 + kk];
      #pragma unroll
      for (int i = 0; i < 12; ++i)
        acc[i] = fmaf(xv, Ws[kk*49 + jq + 4*i], acc[i]);
    }
    __syncthreads();
  }
  #pragma unroll
  for (int i = 0; i < 12; ++i) SH[t2*52 + jq + 4*i] = acc[i];
  __syncthreads();
  for (int e = tid; e < 64*16; e += 256) {
    int t = e >> 4, s2 = e & 15;
    BM[(size_t)(tb+t)*16 + s2] = SH[t*52 + 16+s2];
    CM[(size_t)(tb+t)*16 + s2] = SH[t*52 + 32+s2];
  }
  #pragma unroll
  for (int cc = 0; cc < 2; ++cc) {
    int c = cc*256 + tid;
    float wreg[16];
    #pragma unroll
    for (int r = 0; r < 16; ++r) wreg[r] = Wdt[r*DINNER + c];
    float bd = bdt[c];
    for (int t = 0; t < 64; ++t) {
      float sum = bd;
      #pragma unroll
      for (int r = 0; r < 16; ++r) sum = fmaf(SH[t*52 + r], wreg[r], sum);
      DT[(size_t)(tb+t)*DINNER + c] = (sum > 20.f) ? sum : log1pf(__expf(sum));
    }
  }
}

// ---------------- segmented scan, phase A: per-segment h_end (h0=0) + sum(dt)
__global__ __launch_bounds__(256) void scanA_k(const float* __restrict__ DT,
    const float* __restrict__ XP, const float* __restrict__ BM,
    const float* __restrict__ Alog, float* __restrict__ HEND, float* __restrict__ DTS)
{
  __shared__ __align__(16) float Bs[SEGLEN*16];
  const int tid = threadIdx.x;
  const int seg = blockIdx.x, b = blockIdx.y, half = blockIdx.z;
  const int c = half*256 + tid;
  const int t0 = seg*SEGLEN;
  for (int e = tid; e < SEGLEN*16; e += 256) {
    int t = e >> 4, s = e & 15;
    Bs[e] = BM[((size_t)(t0+t)*BB + b)*16 + s];
  }
  float As[16];
  #pragma unroll
  for (int s = 0; s < 16; ++s) As[s] = -__expf(Alog[c*16+s]);
  float h[16];
  #pragma unroll
  for (int s = 0; s < 16; ++s) h[s] = 0.f;
  float dts = 0.f;
  __syncthreads();
  size_t n0 = (size_t)t0*BB + b;
  float dt = DT[n0*DINNER + c];
  float xp = XP[n0*DINNER + c];
  for (int t = 0; t < SEGLEN; ++t) {
    float dtn = 0.f, xpn = 0.f;
    if (t+1 < SEGLEN) {
      size_t nn = (size_t)(t0+t+1)*BB + b;
      dtn = DT[nn*DINNER + c];
      xpn = XP[nn*DINNER + c];
    }
    dts += dt;
    float dtx = dt * xp;
    const float4 b0 = *(const float4*)&Bs[t*16+0];
    const float4 b1 = *(const float4*)&Bs[t*16+4];
    const float4 b2 = *(const float4*)&Bs[t*16+8];
    const float4 b3 = *(const float4*)&Bs[t*16+12];
    const float bv[16] = {b0.x,b0.y,b0.z,b0.w, b1.x,b1.y,b1.z,b1.w,
                          b2.x,b2.y,b2.z,b2.w, b3.x,b3.y,b3.z,b3.w};
    #pragma unroll
    for (int s = 0; s < 16; ++s)
      h[s] = fmaf(__expf(dt*As[s]), h[s], dtx*bv[s]);
    dt = dtn; xp = xpn;
  }
  float* hp = &HEND[(((size_t)seg*BB + b)*DINNER + c)*16];
  #pragma unroll
  for (int q = 0; q < 4; ++q)
    *(float4*)&hp[q*4] = make_float4(h[q*4], h[q*4+1], h[q*4+2], h[q*4+3]);
  DTS[((size_t)seg*BB + b)*1024 + c] = dts;
}

// ---------------- stitch: sequential over 64 segments, in-place HEND -> h0
__global__ __launch_bounds__(256) void stitch_k(float* __restrict__ HEND,
    const float* __restrict__ DTS, const float* __restrict__ Alog)
{
  int g = blockIdx.x*256 + threadIdx.x;
  int b = g >> 13;
  int rem = g & 8191;          // c*16+s
  int cidx = rem >> 4;
  float A = -__expf(Alog[rem]);
  float h0 = 0.f;
  for (int k = 0; k < NSEG; ++k) {
    size_t idx = ((size_t)k*BB + b)*8192 + rem;
    float hend = HEND[idx];
    HEND[idx] = h0;
    float dts = DTS[((size_t)k*BB + b)*1024 + cidx];
    h0 = fmaf(__expf(dts*A), h0, hend);
  }
}

// ---------------- phase C: full scan with correct h0, fused gate + bf16 output
__global__ __launch_bounds__(256) void scanC_k(const float* __restrict__ DT,
    const float* __restrict__ XP, const float* __restrict__ BM, const float* __restrict__ CM,
    const float* __restrict__ XZ, const float* __restrict__ Alog, const float* __restrict__ Dp,
    const float* __restrict__ H0, u16* __restrict__ YGb)
{
  __shared__ __align__(16) float Bs[SEGLEN*16];
  __shared__ __align__(16) float Cs[SEGLEN*16];
  const int tid = threadIdx.x;
  const int seg = blockIdx.x, b = blockIdx.y, half = blockIdx.z;
  const int c = half*256 + tid;
  const int t0 = seg*SEGLEN;
  for (int e = tid; e < SEGLEN*16; e += 256) {
    int t = e >> 4, s = e & 15;
    size_t nb = ((size_t)(t0+t)*BB + b)*16 + s;
    Bs[e] = BM[nb];
    Cs[e] = CM[nb];
  }
  float As[16];
  #pragma unroll
  for (int s = 0; s < 16; ++s) As[s] = -__expf(Alog[c*16+s]);
  float h[16];
  const float* hp = &H0[(((size_t)seg*BB + b)*DINNER + c)*16];
  #pragma unroll
  for (int q = 0; q < 4; ++q) {
    float4 hv = *(const float4*)&hp[q*4];
    h[q*4+0]=hv.x; h[q*4+1]=hv.y; h[q*4+2]=hv.z; h[q*4+3]=hv.w;
  }
  const float Dv = Dp[c];
  __syncthreads();
  size_t n0 = (size_t)t0*BB + b;
  float dt = DT[n0*DINNER + c];
  float xp = XP[n0*DINNER + c];
  float zg = XZ[n0*1024 + DINNER + c];
  for (int t = 0; t < SEGLEN; ++t) {
    float dtn = 0.f, xpn = 0.f, zgn = 0.f;
    if (t+1 < SEGLEN) {
      size_t nn = (size_t)(t0+t+1)*BB + b;
      dtn = DT[nn*DINNER + c];
      xpn = XP[nn*DINNER + c];
      zgn = XZ[nn*1024 + DINNER + c];
    }
    float dtx = dt * xp;
    const float4 b0 = *(const float4*)&Bs[t*16+0];
    const float4 b1 = *(const float4*)&Bs[t*16+4];
    const float4 b2 = *(const float4*)&Bs[t*16+8];
    const float4 b3 = *(const float4*)&Bs[t*16+12];
    const float4 c0 = *(const float4*)&Cs[t*16+0];
    const float4 c1 = *(const float4*)&Cs[t*16+4];
    const float4 c2 = *(const float4*)&Cs[t*16+8];
    const float4 c3 = *(const float4*)&Cs[t*16+12];
    const float bv[16] = {b0.x,b0.y,b0.z,b0.w, b1.x,b1.y,b1.z,b1.w,
                          b2.x,b2.y,b2.z,b2.w, b3.x,b3.y,b3.z,b3.w};
    const float cv[16] = {c0.x,c0.y,c0.z,c0.w, c1.x,c1.y,c1.z,c1.w,
                          c2.x,c2.y,c2.z,c2.w, c3.x,c3.y,c3.z,c3.w};
    float y0 = 0.f, y1 = 0.f, y2 = 0.f, y3 = 0.f;
    #pragma unroll
    for (int q = 0; q < 4; ++q) {
      h[q*4+0] = fmaf(__expf(dt*As[q*4+0]), h[q*4+0], dtx*bv[q*4+0]);
      h[q*4+1] = fmaf(__expf(dt*As[q*4+1]), h[q*4+1], dtx*bv[q*4+1]);
      h[q*4+2] = fmaf(__expf(dt*As[q*4+2]), h[q*4+2], dtx*bv[q*4+2]);
      h[q*4+3] = fmaf(__expf(dt*As[q*4+3]), h[q*4+3], dtx*bv[q*4+3]);
      y0 = fmaf(h[q*4+0], cv[q*4+0], y0);
      y1 = fmaf(h[q*4+1], cv[q*4+1], y1);
      y2 = fmaf(h[q*4+2], cv[q*4+2], y2);
      y3 = fmaf(h[q*4+3], cv[q*4+3], y3);
    }
    float y = (y0+y1) + (y2+y3);
    size_t n = (size_t)(t0+t)*BB + b;
    YGb[n*DINNER + c] = f2b((y + xp*Dv) * siluf(zg));
    dt = dtn; xp = xpn; zg = zgn;
  }
}

// ---------------- action head + Normal log-prob, 8 tokens/block (32 lanes per token)
__global__ __launch_bounds__(256) void head_logp_k(const float* __restrict__ X2,
    const float* __restrict__ Wh, const float* __restrict__ bh, const float* __restrict__ lstd,
    const float* __restrict__ a, float* __restrict__ out)
{
  int n = blockIdx.x*8 + (threadIdx.x >> 5);
  int j = threadIdx.x & 31;
  float accv = bh[j];
  const float* xr = &X2[(size_t)n*DMODEL];
  for (int k = 0; k < DMODEL; k += 4) {
    float4 xv = *(const float4*)&xr[k];
    accv = fmaf(xv.x, Wh[(k+0)*32 + j], accv);
    accv = fmaf(xv.y, Wh[(k+1)*32 + j], accv);
    accv = fmaf(xv.z, Wh[(k+2)*32 + j], accv);
    accv = fmaf(xv.w, Wh[(k+3)*32 + j], accv);
  }
  float ls = lstd[j];
  float z = (a[(size_t)n*32 + j] - accv) * __expf(-ls);
  float t = -0.5f*z*z - ls - 0.91893853320467274f;   // 0.5*log(2*pi)
  t += __shfl_xor(t, 1);
  t += __shfl_xor(t, 2);
  t += __shfl_xor(t, 4);
  t += __shfl_xor(t, 8);
  t += __shfl_xor(t, 16);
  if (j == 0) out[n] = t;
}

extern "C" void kernel_launch(void* const* d_in, const int* in_sizes, int n_in,
                              void* d_out, int out_size, void* d_ws, size_t ws_size,
                              hipStream_t stream)
{
  const float* s    = (const float*)d_in[0];
  const float* a    = (const float*)d_in[1];
  const float* Wemb = (const float*)d_in[2];
  const float* bemb = (const float*)d_in[3];
  const float* nw   = (const float*)d_in[4];
  const float* Win  = (const float*)d_in[5];
  const float* cw   = (const float*)d_in[6];
  const float* cb   = (const float*)d_in[7];
  const float* Wx   = (const float*)d_in[8];
  const float* Wdt  = (const float*)d_in[9];
  const float* bdt  = (const float*)d_in[10];
  const float* Alog = (const float*)d_in[11];
  const float* Dp   = (const float*)d_in[12];
  const float* Wout = (const float*)d_in[13];
  const float* Wh   = (const float*)d_in[14];
  const float* bh   = (const float*)d_in[15];
  const float* lstd = (const float*)d_in[16];

  float* X  = (float*)d_ws;                    // resid / final hidden (in-place)
  float* XN = X  + (size_t)NTOK*DMODEL;        // fp32 slot reused as HEND/H0
  float* XZ = XN + (size_t)NTOK*DMODEL;        // [xp | z]; rows 0..511 xp-half reused as DTS
  float* XP = XZ + (size_t)NTOK*1024;
  float* DT = XP + (size_t)NTOK*DINNER;
  float* BM = DT + (size_t)NTOK*DINNER;
  float* CM = BM + (size_t)NTOK*16;
  float* YGslot = CM + (size_t)NTOK*16;        // old fp32 YG slot (33.5 MB) hosts bf16 bufs
  float* out = (float*)d_out;
  float* HEND = XN;
  float* DTS  = XZ;

  u16* YGb = (u16*)YGslot;                     // NTOK*512 bf16
  u16* sb  = YGb + (size_t)NTOK*DINNER;        // NTOK*128 bf16
  u16* XNb = sb  + (size_t)NTOK*128;           // NTOK*256 bf16
  u16* WTe = XNb + (size_t)NTOK*DMODEL;        // 256*128
  u16* WTi = WTe + 256*128;                    // 1024*256
  u16* WTo = WTi + 1024*256;                   // 256*512

  tcast_k   <<<dim3(DMODEL/32, 128/32),    256, 0, stream>>>(Wemb, WTe, 128, DMODEL);
  tcast_k   <<<dim3(1024/32,  DMODEL/32),  256, 0, stream>>>(Win,  WTi, DMODEL, 1024);
  tcast_k   <<<dim3(DMODEL/32, DINNER/32), 256, 0, stream>>>(Wout, WTo, DINNER, DMODEL);
  castb_k   <<<NTOK*128/1024,              256, 0, stream>>>(s, sb);

  gemm_mfma<128><<<dim3(128,2), 256, 0, stream>>>(sb,  WTe, bemb,   nullptr, X,  DMODEL);
  rmsnorm_k     <<<4096,        256, 0, stream>>>(X, nw, XNb);
  gemm_mfma<256><<<dim3(128,8), 256, 0, stream>>>(XNb, WTi, nullptr, nullptr, XZ, 1024);
  conv_silu_k   <<<8192,        256, 0, stream>>>(XZ, cw, cb, XP);
  xdbl_dt_k     <<<256,         256, 0, stream>>>(XP, Wx, Wdt, bdt, DT, BM, CM);
  scanA_k       <<<dim3(NSEG,BB,2), 256, 0, stream>>>(DT, XP, BM, Alog, HEND, DTS);
  stitch_k      <<<256,         256, 0, stream>>>(HEND, DTS, Alog);
  scanC_k       <<<dim3(NSEG,BB,2), 256, 0, stream>>>(DT, XP, BM, CM, XZ, Alog, Dp, HEND, YGb);
  gemm_mfma<512><<<dim3(128,2), 256, 0, stream>>>(YGb, WTo, nullptr, X,      X,  DMODEL);
  head_logp_k   <<<2048,        256, 0, stream>>>(X, Wh, bh, lstd, a, out);
}

// Round 7
// 406.126 us; speedup vs baseline: 2.1036x; 1.0093x over previous
//
#include <hip/hip_runtime.h>

typedef unsigned short u16;
typedef short bf16x8 __attribute__((ext_vector_type(8)));   // 8 bf16 = 4 VGPR
typedef float floatx4 __attribute__((ext_vector_type(4)));

#define LSEQ 2048
#define BB 8
#define NTOK (LSEQ*BB)        // 16384 tokens, n = l*B + b
#define DMODEL 256
#define DINNER 512
#define NSEG 64
#define SEGLEN 32             // LSEQ / NSEG

__device__ __forceinline__ float siluf(float x){ return x / (1.f + __expf(-x)); }
__device__ __forceinline__ u16 f2b(float f){
  unsigned u = __float_as_uint(f);
  unsigned r = (u + 0x7fffu + ((u >> 16) & 1u)) >> 16;
  return (u16)r;
}

// ---------------- elementwise fp32 -> bf16 cast
__global__ __launch_bounds__(256) void castb_k(const float* __restrict__ in,
    u16* __restrict__ out)
{
  int i = (blockIdx.x*256 + threadIdx.x)*4;
  float4 v = *(const float4*)&in[i];
  ushort4 o; o.x = f2b(v.x); o.y = f2b(v.y); o.z = f2b(v.z); o.w = f2b(v.w);
  *(ushort4*)&out[i] = o;
}

// ---------------- transpose + cast: W[K][N] fp32 -> WT[N][K] bf16 (32x32 LDS tiles)
__global__ __launch_bounds__(256) void tcast_k(const float* __restrict__ W,
    u16* __restrict__ WT, int K, int N)
{
  __shared__ float S[32][33];
  int n0 = blockIdx.x*32, k0 = blockIdx.y*32;
  int tx = threadIdx.x & 31, ty = threadIdx.x >> 5;   // ty 0..7
  #pragma unroll
  for (int i = 0; i < 4; ++i)
    S[ty + 8*i][tx] = W[(size_t)(k0 + ty + 8*i)*N + n0 + tx];
  __syncthreads();
  #pragma unroll
  for (int i = 0; i < 4; ++i)
    WT[(size_t)(n0 + ty + 8*i)*K + k0 + tx] = f2b(S[tx][ty + 8*i]);
}

// ---------------- Wx[512][48] -> WxT[48][512] bf16 (tiny)
__global__ __launch_bounds__(256) void tcastWx_k(const float* __restrict__ Wx,
    u16* __restrict__ WxT)
{
  int idx = blockIdx.x*256 + threadIdx.x;    // 48*512
  int n = idx >> 9, k = idx & 511;
  WxT[idx] = f2b(Wx[k*48 + n]);
}

// ---------------- Wdt[16][512] -> WdtTp[512][32] bf16, rows r>=16 zero (tiny)
__global__ __launch_bounds__(256) void tcastWdt_k(const float* __restrict__ Wdt,
    u16* __restrict__ WdtTp)
{
  int idx = blockIdx.x*256 + threadIdx.x;    // 512*32
  int c = idx >> 5, r = idx & 31;
  WdtTp[idx] = (r < 16) ? f2b(Wdt[r*512 + c]) : (u16)0;
}

// ---------------- bf16 MFMA GEMM: C = A(MxK,bf16) @ W(KxN via WT[N][K],bf16) [+bias][+resid]
template<int K>
__global__ __launch_bounds__(256) void gemm_mfma(
    const u16* __restrict__ Ab, const u16* __restrict__ WT,
    const float* __restrict__ bias, const float* __restrict__ resid,
    float* __restrict__ C, int N)
{
  const int tid = threadIdx.x;
  const int wave = tid >> 6, lane = tid & 63;
  const int quad = lane >> 4, l16 = lane & 15;
  const int bm = blockIdx.x*128 + (wave & 1)*64;
  const int bn = blockIdx.y*128 + (wave >> 1)*64;
  floatx4 acc[4][4];
  #pragma unroll
  for (int r = 0; r < 4; ++r)
    #pragma unroll
    for (int c = 0; c < 4; ++c) acc[r][c] = (floatx4){0.f,0.f,0.f,0.f};

  const u16* Ap = Ab + (size_t)(bm + l16)*K + quad*8;
  const u16* Bp = WT + (size_t)(bn + l16)*K + quad*8;
  #pragma unroll 2
  for (int k0 = 0; k0 < K; k0 += 32) {
    bf16x8 af[4], bf[4];
    #pragma unroll
    for (int r = 0; r < 4; ++r) af[r] = *(const bf16x8*)(Ap + (size_t)r*16*K + k0);
    #pragma unroll
    for (int c = 0; c < 4; ++c) bf[c] = *(const bf16x8*)(Bp + (size_t)c*16*K + k0);
    #pragma unroll
    for (int r = 0; r < 4; ++r)
      #pragma unroll
      for (int c = 0; c < 4; ++c)
        acc[r][c] = __builtin_amdgcn_mfma_f32_16x16x32_bf16(af[r], bf[c], acc[r][c], 0, 0, 0);
  }
  #pragma unroll
  for (int c = 0; c < 4; ++c) {
    int n = bn + c*16 + l16;
    float bv = bias ? bias[n] : 0.f;
    #pragma unroll
    for (int r = 0; r < 4; ++r) {
      #pragma unroll
      for (int reg = 0; reg < 4; ++reg) {
        int m = bm + r*16 + quad*4 + reg;
        float t = acc[r][c][reg] + bv;
        if (resid) t += resid[(size_t)m*N + n];
        C[(size_t)m*N + n] = t;
      }
    }
  }
}

// ---------------- RMSNorm: one wave per token, writes bf16 for the MFMA in-proj
__global__ __launch_bounds__(256) void rmsnorm_k(const float* __restrict__ X,
    const float* __restrict__ w, u16* __restrict__ XNb)
{
  int n = blockIdx.x*4 + (threadIdx.x >> 6);
  int lane = threadIdx.x & 63;
  const float4 x = *(const float4*)&X[(size_t)n*DMODEL + lane*4];
  float ss = x.x*x.x + x.y*x.y + x.z*x.z + x.w*x.w;
  #pragma unroll
  for (int m = 1; m < 64; m <<= 1) ss += __shfl_xor(ss, m);
  float r = rsqrtf(ss * (1.f/DMODEL) + 1e-5f);
  ushort4 o;
  o.x = f2b(x.x * r * w[lane*4+0]);
  o.y = f2b(x.y * r * w[lane*4+1]);
  o.z = f2b(x.z * r * w[lane*4+2]);
  o.w = f2b(x.w * r * w[lane*4+3]);
  *(ushort4*)&XNb[(size_t)n*DMODEL + lane*4] = o;
}

// ---------------- causal depthwise conv (K=4) + SiLU; emits fp32 XP and bf16 XPb
__global__ __launch_bounds__(256) void conv_silu_k(const float* __restrict__ XZ,
    const float* __restrict__ cw, const float* __restrict__ cb,
    float* __restrict__ XP, u16* __restrict__ XPb)
{
  int g = blockIdx.x*256 + threadIdx.x;   // NTOK * 128 c4-groups
  int c4 = (g & 127) << 2;
  int n = g >> 7;
  int l = n >> 3;
  float w[4][4];
  #pragma unroll
  for (int i = 0; i < 4; ++i)
    #pragma unroll
    for (int k = 0; k < 4; ++k) w[i][k] = cw[(c4+i)*4 + k];
  float acc[4];
  #pragma unroll
  for (int i = 0; i < 4; ++i) acc[i] = cb[c4+i];
  #pragma unroll
  for (int k = 0; k < 4; ++k) {
    int lp = l - 3 + k;
    if (lp >= 0) {
      const float4 xv = *(const float4*)&XZ[(size_t)(n - BB*(3-k))*1024 + c4];
      acc[0] = fmaf(w[0][k], xv.x, acc[0]);
      acc[1] = fmaf(w[1][k], xv.y, acc[1]);
      acc[2] = fmaf(w[2][k], xv.z, acc[2]);
      acc[3] = fmaf(w[3][k], xv.w, acc[3]);
    }
  }
  float4 o;
  o.x = siluf(acc[0]); o.y = siluf(acc[1]); o.z = siluf(acc[2]); o.w = siluf(acc[3]);
  *(float4*)&XP[(size_t)n*DINNER + c4] = o;
  ushort4 ob; ob.x = f2b(o.x); ob.y = f2b(o.y); ob.z = f2b(o.z); ob.w = f2b(o.w);
  *(ushort4*)&XPb[(size_t)n*DINNER + c4] = ob;
}

// ---------------- fused MFMA x_dbl + dt: 128 thr = 2 waves, 16 tokens/wave.
// GEMM1: x_dbl = XPb @ WxT^T (N=48: [0:16)=dtr, [16:32)=B, [32:48)=C), K=512.
// dtr tile goes through per-wave LDS (48B row stride) into A-frag layout;
// GEMM2: dt = softplus(dtr @ WdtTp^T + b_dt), N=512, K=32 (padded).
__global__ __launch_bounds__(128) void xdbl_mfma_k(const u16* __restrict__ XPb,
    const u16* __restrict__ WxT, const u16* __restrict__ WdtTp,
    const float* __restrict__ bdt,
    float* __restrict__ DT, float* __restrict__ BM, float* __restrict__ CM)
{
  __shared__ u16 XDs[2][16*24];          // per-wave 16 tokens x 24-u16 stride (48B)
  const int tid = threadIdx.x;
  const int wave = tid >> 6, lane = tid & 63;
  const int quad = lane >> 4, l16 = lane & 15;
  const int tok0 = blockIdx.x*32 + wave*16;

  floatx4 acc[3];
  #pragma unroll
  for (int j = 0; j < 3; ++j) acc[j] = (floatx4){0.f,0.f,0.f,0.f};
  const u16* Ap = XPb + (size_t)(tok0 + l16)*DINNER + quad*8;
  const u16* Bp = WxT + (size_t)l16*DINNER + quad*8;
  #pragma unroll 4
  for (int k0 = 0; k0 < DINNER; k0 += 32) {
    bf16x8 af = *(const bf16x8*)(Ap + k0);
    #pragma unroll
    for (int j = 0; j < 3; ++j) {
      bf16x8 bf = *(const bf16x8*)(Bp + (size_t)j*16*DINNER + k0);
      acc[j] = __builtin_amdgcn_mfma_f32_16x16x32_bf16(af, bf, acc[j], 0, 0, 0);
    }
  }
  // B, C out; dtr tile -> LDS (bf16)
  #pragma unroll
  for (int reg = 0; reg < 4; ++reg) {
    int tl = quad*4 + reg;
    size_t t = (size_t)(tok0 + tl);
    BM[t*16 + l16] = acc[1][reg];
    CM[t*16 + l16] = acc[2][reg];
    XDs[wave][tl*24 + l16] = f2b(acc[0][reg]);
  }
  __syncthreads();
  bf16x8 af2 = {0,0,0,0,0,0,0,0};
  if (quad < 2) af2 = *(const bf16x8*)&XDs[wave][l16*24 + quad*8];
  const floatx4 zero = (floatx4){0.f,0.f,0.f,0.f};
  for (int j = 0; j < 32; ++j) {
    bf16x8 bf = *(const bf16x8*)(WdtTp + (size_t)(j*16 + l16)*32 + quad*8);
    floatx4 d = __builtin_amdgcn_mfma_f32_16x16x32_bf16(af2, bf, zero, 0, 0, 0);
    int c = j*16 + l16;
    float bd = bdt[c];
    #pragma unroll
    for (int reg = 0; reg < 4; ++reg) {
      size_t t = (size_t)(tok0 + quad*4 + reg);
      float sum = d[reg] + bd;
      DT[t*DINNER + c] = (sum > 20.f) ? sum : log1pf(__expf(sum));
    }
  }
}

// ---------------- segmented scan, phase A: per-segment h_end (h0=0) + sum(dt)
__global__ __launch_bounds__(256) void scanA_k(const float* __restrict__ DT,
    const float* __restrict__ XP, const float* __restrict__ BM,
    const float* __restrict__ Alog, float* __restrict__ HEND, float* __restrict__ DTS)
{
  __shared__ __align__(16) float Bs[SEGLEN*16];
  const int tid = threadIdx.x;
  const int seg = blockIdx.x, b = blockIdx.y, half = blockIdx.z;
  const int c = half*256 + tid;
  const int t0 = seg*SEGLEN;
  for (int e = tid; e < SEGLEN*16; e += 256) {
    int t = e >> 4, s = e & 15;
    Bs[e] = BM[((size_t)(t0+t)*BB + b)*16 + s];
  }
  float As[16];
  #pragma unroll
  for (int s = 0; s < 16; ++s) As[s] = -__expf(Alog[c*16+s]);
  float h[16];
  #pragma unroll
  for (int s = 0; s < 16; ++s) h[s] = 0.f;
  float dts = 0.f;
  __syncthreads();
  size_t n0 = (size_t)t0*BB + b;
  float dt = DT[n0*DINNER + c];
  float xp = XP[n0*DINNER + c];
  for (int t = 0; t < SEGLEN; ++t) {
    float dtn = 0.f, xpn = 0.f;
    if (t+1 < SEGLEN) {
      size_t nn = (size_t)(t0+t+1)*BB + b;
      dtn = DT[nn*DINNER + c];
      xpn = XP[nn*DINNER + c];
    }
    dts += dt;
    float dtx = dt * xp;
    const float4 b0 = *(const float4*)&Bs[t*16+0];
    const float4 b1 = *(const float4*)&Bs[t*16+4];
    const float4 b2 = *(const float4*)&Bs[t*16+8];
    const float4 b3 = *(const float4*)&Bs[t*16+12];
    const float bv[16] = {b0.x,b0.y,b0.z,b0.w, b1.x,b1.y,b1.z,b1.w,
                          b2.x,b2.y,b2.z,b2.w, b3.x,b3.y,b3.z,b3.w};
    #pragma unroll
    for (int s = 0; s < 16; ++s)
      h[s] = fmaf(__expf(dt*As[s]), h[s], dtx*bv[s]);
    dt = dtn; xp = xpn;
  }
  float* hp = &HEND[(((size_t)seg*BB + b)*DINNER + c)*16];
  #pragma unroll
  for (int q = 0; q < 4; ++q)
    *(float4*)&hp[q*4] = make_float4(h[q*4], h[q*4+1], h[q*4+2], h[q*4+3]);
  DTS[((size_t)seg*BB + b)*1024 + c] = dts;
}

// ---------------- stitch: sequential over 64 segments, in-place HEND -> h0
__global__ __launch_bounds__(256) void stitch_k(float* __restrict__ HEND,
    const float* __restrict__ DTS, const float* __restrict__ Alog)
{
  int g = blockIdx.x*256 + threadIdx.x;
  int b = g >> 13;
  int rem = g & 8191;          // c*16+s
  int cidx = rem >> 4;
  float A = -__expf(Alog[rem]);
  float h0 = 0.f;
  for (int k = 0; k < NSEG; ++k) {
    size_t idx = ((size_t)k*BB + b)*8192 + rem;
    float hend = HEND[idx];
    HEND[idx] = h0;
    float dts = DTS[((size_t)k*BB + b)*1024 + cidx];
    h0 = fmaf(__expf(dts*A), h0, hend);
  }
}

// ---------------- phase C: full scan with correct h0, fused gate + bf16 output
__global__ __launch_bounds__(256) void scanC_k(const float* __restrict__ DT,
    const float* __restrict__ XP, const float* __restrict__ BM, const float* __restrict__ CM,
    const float* __restrict__ XZ, const float* __restrict__ Alog, const float* __restrict__ Dp,
    const float* __restrict__ H0, u16* __restrict__ YGb)
{
  __shared__ __align__(16) float Bs[SEGLEN*16];
  __shared__ __align__(16) float Cs[SEGLEN*16];
  const int tid = threadIdx.x;
  const int seg = blockIdx.x, b = blockIdx.y, half = blockIdx.z;
  const int c = half*256 + tid;
  const int t0 = seg*SEGLEN;
  for (int e = tid; e < SEGLEN*16; e += 256) {
    int t = e >> 4, s = e & 15;
    size_t nb = ((size_t)(t0+t)*BB + b)*16 + s;
    Bs[e] = BM[nb];
    Cs[e] = CM[nb];
  }
  float As[16];
  #pragma unroll
  for (int s = 0; s < 16; ++s) As[s] = -__expf(Alog[c*16+s]);
  float h[16];
  const float* hp = &H0[(((size_t)seg*BB + b)*DINNER + c)*16];
  #pragma unroll
  for (int q = 0; q < 4; ++q) {
    float4 hv = *(const float4*)&hp[q*4];
    h[q*4+0]=hv.x; h[q*4+1]=hv.y; h[q*4+2]=hv.z; h[q*4+3]=hv.w;
  }
  const float Dv = Dp[c];
  __syncthreads();
  size_t n0 = (size_t)t0*BB + b;
  float dt = DT[n0*DINNER + c];
  float xp = XP[n0*DINNER + c];
  float zg = XZ[n0*1024 + DINNER + c];
  for (int t = 0; t < SEGLEN; ++t) {
    float dtn = 0.f, xpn = 0.f, zgn = 0.f;
    if (t+1 < SEGLEN) {
      size_t nn = (size_t)(t0+t+1)*BB + b;
      dtn = DT[nn*DINNER + c];
      xpn = XP[nn*DINNER + c];
      zgn = XZ[nn*1024 + DINNER + c];
    }
    float dtx = dt * xp;
    const float4 b0 = *(const float4*)&Bs[t*16+0];
    const float4 b1 = *(const float4*)&Bs[t*16+4];
    const float4 b2 = *(const float4*)&Bs[t*16+8];
    const float4 b3 = *(const float4*)&Bs[t*16+12];
    const float4 c0 = *(const float4*)&Cs[t*16+0];
    const float4 c1 = *(const float4*)&Cs[t*16+4];
    const float4 c2 = *(const float4*)&Cs[t*16+8];
    const float4 c3 = *(const float4*)&Cs[t*16+12];
    const float bv[16] = {b0.x,b0.y,b0.z,b0.w, b1.x,b1.y,b1.z,b1.w,
                          b2.x,b2.y,b2.z,b2.w, b3.x,b3.y,b3.z,b3.w};
    const float cv[16] = {c0.x,c0.y,c0.z,c0.w, c1.x,c1.y,c1.z,c1.w,
                          c2.x,c2.y,c2.z,c2.w, c3.x,c3.y,c3.z,c3.w};
    float y0 = 0.f, y1 = 0.f, y2 = 0.f, y3 = 0.f;
    #pragma unroll
    for (int q = 0; q < 4; ++q) {
      h[q*4+0] = fmaf(__expf(dt*As[q*4+0]), h[q*4+0], dtx*bv[q*4+0]);
      h[q*4+1] = fmaf(__expf(dt*As[q*4+1]), h[q*4+1], dtx*bv[q*4+1]);
      h[q*4+2] = fmaf(__expf(dt*As[q*4+2]), h[q*4+2], dtx*bv[q*4+2]);
      h[q*4+3] = fmaf(__expf(dt*As[q*4+3]), h[q*4+3], dtx*bv[q*4+3]);
      y0 = fmaf(h[q*4+0], cv[q*4+0], y0);
      y1 = fmaf(h[q*4+1], cv[q*4+1], y1);
      y2 = fmaf(h[q*4+2], cv[q*4+2], y2);
      y3 = fmaf(h[q*4+3], cv[q*4+3], y3);
    }
    float y = (y0+y1) + (y2+y3);
    size_t n = (size_t)(t0+t)*BB + b;
    YGb[n*DINNER + c] = f2b((y + xp*Dv) * siluf(zg));
    dt = dtn; xp = xpn; zg = zgn;
  }
}

// ---------------- action head + Normal log-prob, 8 tokens/block (32 lanes per token)
__global__ __launch_bounds__(256) void head_logp_k(const float* __restrict__ X2,
    const float* __restrict__ Wh, const float* __restrict__ bh, const float* __restrict__ lstd,
    const float* __restrict__ a, float* __restrict__ out)
{
  int n = blockIdx.x*8 + (threadIdx.x >> 5);
  int j = threadIdx.x & 31;
  float accv = bh[j];
  const float* xr = &X2[(size_t)n*DMODEL];
  for (int k = 0; k < DMODEL; k += 4) {
    float4 xv = *(const float4*)&xr[k];
    accv = fmaf(xv.x, Wh[(k+0)*32 + j], accv);
    accv = fmaf(xv.y, Wh[(k+1)*32 + j], accv);
    accv = fmaf(xv.z, Wh[(k+2)*32 + j], accv);
    accv = fmaf(xv.w, Wh[(k+3)*32 + j], accv);
  }
  float ls = lstd[j];
  float z = (a[(size_t)n*32 + j] - accv) * __expf(-ls);
  float t = -0.5f*z*z - ls - 0.91893853320467274f;   // 0.5*log(2*pi)
  t += __shfl_xor(t, 1);
  t += __shfl_xor(t, 2);
  t += __shfl_xor(t, 4);
  t += __shfl_xor(t, 8);
  t += __shfl_xor(t, 16);
  if (j == 0) out[n] = t;
}

extern "C" void kernel_launch(void* const* d_in, const int* in_sizes, int n_in,
                              void* d_out, int out_size, void* d_ws, size_t ws_size,
                              hipStream_t stream)
{
  const float* s    = (const float*)d_in[0];
  const float* a    = (const float*)d_in[1];
  const float* Wemb = (const float*)d_in[2];
  const float* bemb = (const float*)d_in[3];
  const float* nw   = (const float*)d_in[4];
  const float* Win  = (const float*)d_in[5];
  const float* cw   = (const float*)d_in[6];
  const float* cb   = (const float*)d_in[7];
  const float* Wx   = (const float*)d_in[8];
  const float* Wdt  = (const float*)d_in[9];
  const float* bdt  = (const float*)d_in[10];
  const float* Alog = (const float*)d_in[11];
  const float* Dp   = (const float*)d_in[12];
  const float* Wout = (const float*)d_in[13];
  const float* Wh   = (const float*)d_in[14];
  const float* bh   = (const float*)d_in[15];
  const float* lstd = (const float*)d_in[16];

  float* X  = (float*)d_ws;                    // resid / final hidden (in-place)
  float* XN = X  + (size_t)NTOK*DMODEL;        // slot: XPb until xdbl, then HEND/H0
  float* XZ = XN + (size_t)NTOK*DMODEL;        // [xp | z]; xp-half rows reused as DTS
  float* XP = XZ + (size_t)NTOK*1024;
  float* DT = XP + (size_t)NTOK*DINNER;
  float* BM = DT + (size_t)NTOK*DINNER;
  float* CM = BM + (size_t)NTOK*16;
  float* YGslot = CM + (size_t)NTOK*16;        // old fp32 YG slot (33.5 MB) hosts bf16 bufs
  float* out = (float*)d_out;
  float* HEND = XN;
  float* DTS  = XZ;
  u16* XPb = (u16*)XN;                         // NTOK*512 bf16 = NTOK*256 fp32 exactly

  u16* YGb = (u16*)YGslot;                     // NTOK*512 bf16
  u16* sb  = YGb + (size_t)NTOK*DINNER;        // NTOK*128 bf16
  u16* XNb = sb  + (size_t)NTOK*128;           // NTOK*256 bf16
  u16* WTe = XNb + (size_t)NTOK*DMODEL;        // 256*128
  u16* WTi = WTe + 256*128;                    // 1024*256
  u16* WTo = WTi + 1024*256;                   // 256*512
  u16* WxT = WTo + 256*512;                    // 48*512
  u16* WdtTp = WxT + 48*512;                   // 512*32

  tcast_k   <<<dim3(DMODEL/32, 128/32),    256, 0, stream>>>(Wemb, WTe, 128, DMODEL);
  tcast_k   <<<dim3(1024/32,  DMODEL/32),  256, 0, stream>>>(Win,  WTi, DMODEL, 1024);
  tcast_k   <<<dim3(DMODEL/32, DINNER/32), 256, 0, stream>>>(Wout, WTo, DINNER, DMODEL);
  tcastWx_k <<<48*512/256,                 256, 0, stream>>>(Wx, WxT);
  tcastWdt_k<<<512*32/256,                 256, 0, stream>>>(Wdt, WdtTp);
  castb_k   <<<NTOK*128/1024,              256, 0, stream>>>(s, sb);

  gemm_mfma<128><<<dim3(128,2), 256, 0, stream>>>(sb,  WTe, bemb,   nullptr, X,  DMODEL);
  rmsnorm_k     <<<4096,        256, 0, stream>>>(X, nw, XNb);
  gemm_mfma<256><<<dim3(128,8), 256, 0, stream>>>(XNb, WTi, nullptr, nullptr, XZ, 1024);
  conv_silu_k   <<<8192,        256, 0, stream>>>(XZ, cw, cb, XP, XPb);
  xdbl_mfma_k   <<<512,         128, 0, stream>>>(XPb, WxT, WdtTp, bdt, DT, BM, CM);
  scanA_k       <<<dim3(NSEG,BB,2), 256, 0, stream>>>(DT, XP, BM, Alog, HEND, DTS);
  stitch_k      <<<256,         256, 0, stream>>>(HEND, DTS, Alog);
  scanC_k       <<<dim3(NSEG,BB,2), 256, 0, stream>>>(DT, XP, BM, CM, XZ, Alog, Dp, HEND, YGb);
  gemm_mfma<512><<<dim3(128,2), 256, 0, stream>>>(YGb, WTo, nullptr, X,      X,  DMODEL);
  head_logp_k   <<<2048,        256, 0, stream>>>(X, Wh, bh, lstd, a, out);
}

// Round 8
// 349.347 us; speedup vs baseline: 2.4455x; 1.1625x over previous
//
#include <hip/hip_runtime.h>

typedef unsigned short u16;
typedef short bf16x8 __attribute__((ext_vector_type(8)));   // 8 bf16 = 4 VGPR
typedef float floatx4 __attribute__((ext_vector_type(4)));

#define LSEQ 2048
#define BB 8
#define NTOK (LSEQ*BB)        // 16384 tokens, n = l*B + b
#define DMODEL 256
#define DINNER 512
#define NSEG 64
#define SEGLEN 32             // LSEQ / NSEG

__device__ __forceinline__ float siluf(float x){ return x / (1.f + __expf(-x)); }
__device__ __forceinline__ u16 f2b(float f){
  unsigned u = __float_as_uint(f);
  unsigned r = (u + 0x7fffu + ((u >> 16) & 1u)) >> 16;
  return (u16)r;
}

// ---------------- elementwise fp32 -> bf16 cast
__global__ __launch_bounds__(256) void castb_k(const float* __restrict__ in,
    u16* __restrict__ out)
{
  int i = (blockIdx.x*256 + threadIdx.x)*4;
  float4 v = *(const float4*)&in[i];
  ushort4 o; o.x = f2b(v.x); o.y = f2b(v.y); o.z = f2b(v.z); o.w = f2b(v.w);
  *(ushort4*)&out[i] = o;
}

// ---------------- transpose + cast: W[K][N] fp32 -> WT[N][K] bf16 (32x32 LDS tiles)
__global__ __launch_bounds__(256) void tcast_k(const float* __restrict__ W,
    u16* __restrict__ WT, int K, int N)
{
  __shared__ float S[32][33];
  int n0 = blockIdx.x*32, k0 = blockIdx.y*32;
  int tx = threadIdx.x & 31, ty = threadIdx.x >> 5;   // ty 0..7
  #pragma unroll
  for (int i = 0; i < 4; ++i)
    S[ty + 8*i][tx] = W[(size_t)(k0 + ty + 8*i)*N + n0 + tx];
  __syncthreads();
  #pragma unroll
  for (int i = 0; i < 4; ++i)
    WT[(size_t)(n0 + ty + 8*i)*K + k0 + tx] = f2b(S[tx][ty + 8*i]);
}

// ---------------- Wx[512][48] -> WxT[48][512] bf16 (tiny)
__global__ __launch_bounds__(256) void tcastWx_k(const float* __restrict__ Wx,
    u16* __restrict__ WxT)
{
  int idx = blockIdx.x*256 + threadIdx.x;    // 48*512
  int n = idx >> 9, k = idx & 511;
  WxT[idx] = f2b(Wx[k*48 + n]);
}

// ---------------- Wdt[16][512] -> WdtTp[512][32] bf16, rows r>=16 zero (tiny)
__global__ __launch_bounds__(256) void tcastWdt_k(const float* __restrict__ Wdt,
    u16* __restrict__ WdtTp)
{
  int idx = blockIdx.x*256 + threadIdx.x;    // 512*32
  int c = idx >> 5, r = idx & 31;
  WdtTp[idx] = (r < 16) ? f2b(Wdt[r*512 + c]) : (u16)0;
}

// ---------------- bf16 MFMA GEMM: C = A(MxK,bf16) @ W(KxN via WT[N][K],bf16) [+bias][+resid]
template<int K>
__global__ __launch_bounds__(256) void gemm_mfma(
    const u16* __restrict__ Ab, const u16* __restrict__ WT,
    const float* __restrict__ bias, const float* __restrict__ resid,
    float* __restrict__ C, int N)
{
  const int tid = threadIdx.x;
  const int wave = tid >> 6, lane = tid & 63;
  const int quad = lane >> 4, l16 = lane & 15;
  const int bm = blockIdx.x*128 + (wave & 1)*64;
  const int bn = blockIdx.y*128 + (wave >> 1)*64;
  floatx4 acc[4][4];
  #pragma unroll
  for (int r = 0; r < 4; ++r)
    #pragma unroll
    for (int c = 0; c < 4; ++c) acc[r][c] = (floatx4){0.f,0.f,0.f,0.f};

  const u16* Ap = Ab + (size_t)(bm + l16)*K + quad*8;
  const u16* Bp = WT + (size_t)(bn + l16)*K + quad*8;
  #pragma unroll 2
  for (int k0 = 0; k0 < K; k0 += 32) {
    bf16x8 af[4], bf[4];
    #pragma unroll
    for (int r = 0; r < 4; ++r) af[r] = *(const bf16x8*)(Ap + (size_t)r*16*K + k0);
    #pragma unroll
    for (int c = 0; c < 4; ++c) bf[c] = *(const bf16x8*)(Bp + (size_t)c*16*K + k0);
    #pragma unroll
    for (int r = 0; r < 4; ++r)
      #pragma unroll
      for (int c = 0; c < 4; ++c)
        acc[r][c] = __builtin_amdgcn_mfma_f32_16x16x32_bf16(af[r], bf[c], acc[r][c], 0, 0, 0);
  }
  #pragma unroll
  for (int c = 0; c < 4; ++c) {
    int n = bn + c*16 + l16;
    float bv = bias ? bias[n] : 0.f;
    #pragma unroll
    for (int r = 0; r < 4; ++r) {
      #pragma unroll
      for (int reg = 0; reg < 4; ++reg) {
        int m = bm + r*16 + quad*4 + reg;
        float t = acc[r][c][reg] + bv;
        if (resid) t += resid[(size_t)m*N + n];
        C[(size_t)m*N + n] = t;
      }
    }
  }
}

// ---------------- RMSNorm: one wave per token, writes bf16 for the MFMA in-proj
__global__ __launch_bounds__(256) void rmsnorm_k(const float* __restrict__ X,
    const float* __restrict__ w, u16* __restrict__ XNb)
{
  int n = blockIdx.x*4 + (threadIdx.x >> 6);
  int lane = threadIdx.x & 63;
  const float4 x = *(const float4*)&X[(size_t)n*DMODEL + lane*4];
  float ss = x.x*x.x + x.y*x.y + x.z*x.z + x.w*x.w;
  #pragma unroll
  for (int m = 1; m < 64; m <<= 1) ss += __shfl_xor(ss, m);
  float r = rsqrtf(ss * (1.f/DMODEL) + 1e-5f);
  ushort4 o;
  o.x = f2b(x.x * r * w[lane*4+0]);
  o.y = f2b(x.y * r * w[lane*4+1]);
  o.z = f2b(x.z * r * w[lane*4+2]);
  o.w = f2b(x.w * r * w[lane*4+3]);
  *(ushort4*)&XNb[(size_t)n*DMODEL + lane*4] = o;
}

// ---------------- causal depthwise conv (K=4) + SiLU; emits fp32 XP and bf16 XPb
__global__ __launch_bounds__(256) void conv_silu_k(const float* __restrict__ XZ,
    const float* __restrict__ cw, const float* __restrict__ cb,
    float* __restrict__ XP, u16* __restrict__ XPb)
{
  int g = blockIdx.x*256 + threadIdx.x;   // NTOK * 128 c4-groups
  int c4 = (g & 127) << 2;
  int n = g >> 7;
  int l = n >> 3;
  float w[4][4];
  #pragma unroll
  for (int i = 0; i < 4; ++i)
    #pragma unroll
    for (int k = 0; k < 4; ++k) w[i][k] = cw[(c4+i)*4 + k];
  float acc[4];
  #pragma unroll
  for (int i = 0; i < 4; ++i) acc[i] = cb[c4+i];
  #pragma unroll
  for (int k = 0; k < 4; ++k) {
    int lp = l - 3 + k;
    if (lp >= 0) {
      const float4 xv = *(const float4*)&XZ[(size_t)(n - BB*(3-k))*1024 + c4];
      acc[0] = fmaf(w[0][k], xv.x, acc[0]);
      acc[1] = fmaf(w[1][k], xv.y, acc[1]);
      acc[2] = fmaf(w[2][k], xv.z, acc[2]);
      acc[3] = fmaf(w[3][k], xv.w, acc[3]);
    }
  }
  float4 o;
  o.x = siluf(acc[0]); o.y = siluf(acc[1]); o.z = siluf(acc[2]); o.w = siluf(acc[3]);
  *(float4*)&XP[(size_t)n*DINNER + c4] = o;
  ushort4 ob; ob.x = f2b(o.x); ob.y = f2b(o.y); ob.z = f2b(o.z); ob.w = f2b(o.w);
  *(ushort4*)&XPb[(size_t)n*DINNER + c4] = ob;
}

// ---------------- GEMM1 of x_dbl: B/C/dtr = XPb @ WxT^T (N=48, K=512, fully unrolled)
// Emits BM, CM (fp32) and DTRb[tok][32] bf16 (cols 16..31 zero) for the dt GEMM.
__global__ __launch_bounds__(128) void xdblBC_k(const u16* __restrict__ XPb,
    const u16* __restrict__ WxT,
    float* __restrict__ BM, float* __restrict__ CM, u16* __restrict__ DTRb)
{
  const int tid = threadIdx.x;
  const int wave = tid >> 6, lane = tid & 63;
  const int quad = lane >> 4, l16 = lane & 15;
  const int tok0 = blockIdx.x*32 + wave*16;

  floatx4 acc[3];
  #pragma unroll
  for (int j = 0; j < 3; ++j) acc[j] = (floatx4){0.f,0.f,0.f,0.f};
  const u16* Ap = XPb + (size_t)(tok0 + l16)*DINNER + quad*8;
  const u16* Bp = WxT + (size_t)l16*DINNER + quad*8;
  #pragma unroll
  for (int k0 = 0; k0 < DINNER; k0 += 32) {
    bf16x8 af = *(const bf16x8*)(Ap + k0);
    #pragma unroll
    for (int j = 0; j < 3; ++j) {
      bf16x8 bf = *(const bf16x8*)(Bp + (size_t)j*16*DINNER + k0);
      acc[j] = __builtin_amdgcn_mfma_f32_16x16x32_bf16(af, bf, acc[j], 0, 0, 0);
    }
  }
  #pragma unroll
  for (int reg = 0; reg < 4; ++reg) {
    size_t t = (size_t)(tok0 + quad*4 + reg);
    BM[t*16 + l16] = acc[1][reg];
    CM[t*16 + l16] = acc[2][reg];
    DTRb[t*32 + l16]      = f2b(acc[0][reg]);
    DTRb[t*32 + 16 + l16] = 0;
  }
}

// ---------------- dt GEMM: DT = softplus(DTRb @ WdtTp^T + b_dt); M=NTOK,N=512,K=32
__global__ __launch_bounds__(256) void dtg_k(const u16* __restrict__ DTRb,
    const u16* __restrict__ WdtTp, const float* __restrict__ bdt,
    float* __restrict__ DT)
{
  const int tid = threadIdx.x;
  const int wave = tid >> 6, lane = tid & 63;
  const int quad = lane >> 4, l16 = lane & 15;
  const int bm = blockIdx.x*128 + (wave & 1)*64;
  const int bn = blockIdx.y*128 + (wave >> 1)*64;
  bf16x8 af[4], bf[4];
  #pragma unroll
  for (int r = 0; r < 4; ++r)
    af[r] = *(const bf16x8*)(DTRb + (size_t)(bm + r*16 + l16)*32 + quad*8);
  #pragma unroll
  for (int c = 0; c < 4; ++c)
    bf[c] = *(const bf16x8*)(WdtTp + (size_t)(bn + c*16 + l16)*32 + quad*8);
  #pragma unroll
  for (int c = 0; c < 4; ++c) {
    int n = bn + c*16 + l16;
    float bd = bdt[n];
    #pragma unroll
    for (int r = 0; r < 4; ++r) {
      floatx4 d = __builtin_amdgcn_mfma_f32_16x16x32_bf16(af[r], bf[c],
                    (floatx4){0.f,0.f,0.f,0.f}, 0, 0, 0);
      #pragma unroll
      for (int reg = 0; reg < 4; ++reg) {
        int m = bm + r*16 + quad*4 + reg;
        float sum = d[reg] + bd;
        DT[(size_t)m*DINNER + n] = (sum > 20.f) ? sum : __logf(1.f + __expf(sum));
      }
    }
  }
}

// ---------------- segmented scan, phase A: per-segment h_end (h0=0) + sum(dt)
__global__ __launch_bounds__(256) void scanA_k(const float* __restrict__ DT,
    const float* __restrict__ XP, const float* __restrict__ BM,
    const float* __restrict__ Alog, float* __restrict__ HEND, float* __restrict__ DTS)
{
  __shared__ __align__(16) float Bs[SEGLEN*16];
  const int tid = threadIdx.x;
  const int seg = blockIdx.x, b = blockIdx.y, half = blockIdx.z;
  const int c = half*256 + tid;
  const int t0 = seg*SEGLEN;
  for (int e = tid; e < SEGLEN*16; e += 256) {
    int t = e >> 4, s = e & 15;
    Bs[e] = BM[((size_t)(t0+t)*BB + b)*16 + s];
  }
  float As[16];
  #pragma unroll
  for (int s = 0; s < 16; ++s) As[s] = -__expf(Alog[c*16+s]);
  float h[16];
  #pragma unroll
  for (int s = 0; s < 16; ++s) h[s] = 0.f;
  float dts = 0.f;
  __syncthreads();
  size_t n0 = (size_t)t0*BB + b;
  float dt = DT[n0*DINNER + c];
  float xp = XP[n0*DINNER + c];
  for (int t = 0; t < SEGLEN; ++t) {
    float dtn = 0.f, xpn = 0.f;
    if (t+1 < SEGLEN) {
      size_t nn = (size_t)(t0+t+1)*BB + b;
      dtn = DT[nn*DINNER + c];
      xpn = XP[nn*DINNER + c];
    }
    dts += dt;
    float dtx = dt * xp;
    const float4 b0 = *(const float4*)&Bs[t*16+0];
    const float4 b1 = *(const float4*)&Bs[t*16+4];
    const float4 b2 = *(const float4*)&Bs[t*16+8];
    const float4 b3 = *(const float4*)&Bs[t*16+12];
    const float bv[16] = {b0.x,b0.y,b0.z,b0.w, b1.x,b1.y,b1.z,b1.w,
                          b2.x,b2.y,b2.z,b2.w, b3.x,b3.y,b3.z,b3.w};
    #pragma unroll
    for (int s = 0; s < 16; ++s)
      h[s] = fmaf(__expf(dt*As[s]), h[s], dtx*bv[s]);
    dt = dtn; xp = xpn;
  }
  float* hp = &HEND[(((size_t)seg*BB + b)*DINNER + c)*16];
  #pragma unroll
  for (int q = 0; q < 4; ++q)
    *(float4*)&hp[q*4] = make_float4(h[q*4], h[q*4+1], h[q*4+2], h[q*4+3]);
  DTS[((size_t)seg*BB + b)*1024 + c] = dts;
}

// ---------------- stitch: sequential over 64 segments, in-place HEND -> h0
__global__ __launch_bounds__(256) void stitch_k(float* __restrict__ HEND,
    const float* __restrict__ DTS, const float* __restrict__ Alog)
{
  int g = blockIdx.x*256 + threadIdx.x;
  int b = g >> 13;
  int rem = g & 8191;          // c*16+s
  int cidx = rem >> 4;
  float A = -__expf(Alog[rem]);
  float h0 = 0.f;
  for (int k = 0; k < NSEG; ++k) {
    size_t idx = ((size_t)k*BB + b)*8192 + rem;
    float hend = HEND[idx];
    HEND[idx] = h0;
    float dts = DTS[((size_t)k*BB + b)*1024 + cidx];
    h0 = fmaf(__expf(dts*A), h0, hend);
  }
}

// ---------------- phase C: full scan with correct h0, fused gate + bf16 output
__global__ __launch_bounds__(256) void scanC_k(const float* __restrict__ DT,
    const float* __restrict__ XP, const float* __restrict__ BM, const float* __restrict__ CM,
    const float* __restrict__ XZ, const float* __restrict__ Alog, const float* __restrict__ Dp,
    const float* __restrict__ H0, u16* __restrict__ YGb)
{
  __shared__ __align__(16) float Bs[SEGLEN*16];
  __shared__ __align__(16) float Cs[SEGLEN*16];
  const int tid = threadIdx.x;
  const int seg = blockIdx.x, b = blockIdx.y, half = blockIdx.z;
  const int c = half*256 + tid;
  const int t0 = seg*SEGLEN;
  for (int e = tid; e < SEGLEN*16; e += 256) {
    int t = e >> 4, s = e & 15;
    size_t nb = ((size_t)(t0+t)*BB + b)*16 + s;
    Bs[e] = BM[nb];
    Cs[e] = CM[nb];
  }
  float As[16];
  #pragma unroll
  for (int s = 0; s < 16; ++s) As[s] = -__expf(Alog[c*16+s]);
  float h[16];
  const float* hp = &H0[(((size_t)seg*BB + b)*DINNER + c)*16];
  #pragma unroll
  for (int q = 0; q < 4; ++q) {
    float4 hv = *(const float4*)&hp[q*4];
    h[q*4+0]=hv.x; h[q*4+1]=hv.y; h[q*4+2]=hv.z; h[q*4+3]=hv.w;
  }
  const float Dv = Dp[c];
  __syncthreads();
  size_t n0 = (size_t)t0*BB + b;
  float dt = DT[n0*DINNER + c];
  float xp = XP[n0*DINNER + c];
  float zg = XZ[n0*1024 + DINNER + c];
  for (int t = 0; t < SEGLEN; ++t) {
    float dtn = 0.f, xpn = 0.f, zgn = 0.f;
    if (t+1 < SEGLEN) {
      size_t nn = (size_t)(t0+t+1)*BB + b;
      dtn = DT[nn*DINNER + c];
      xpn = XP[nn*DINNER + c];
      zgn = XZ[nn*1024 + DINNER + c];
    }
    float dtx = dt * xp;
    const float4 b0 = *(const float4*)&Bs[t*16+0];
    const float4 b1 = *(const float4*)&Bs[t*16+4];
    const float4 b2 = *(const float4*)&Bs[t*16+8];
    const float4 b3 = *(const float4*)&Bs[t*16+12];
    const float4 c0 = *(const float4*)&Cs[t*16+0];
    const float4 c1 = *(const float4*)&Cs[t*16+4];
    const float4 c2 = *(const float4*)&Cs[t*16+8];
    const float4 c3 = *(const float4*)&Cs[t*16+12];
    const float bv[16] = {b0.x,b0.y,b0.z,b0.w, b1.x,b1.y,b1.z,b1.w,
                          b2.x,b2.y,b2.z,b2.w, b3.x,b3.y,b3.z,b3.w};
    const float cv[16] = {c0.x,c0.y,c0.z,c0.w, c1.x,c1.y,c1.z,c1.w,
                          c2.x,c2.y,c2.z,c2.w, c3.x,c3.y,c3.z,c3.w};
    float y0 = 0.f, y1 = 0.f, y2 = 0.f, y3 = 0.f;
    #pragma unroll
    for (int q = 0; q < 4; ++q) {
      h[q*4+0] = fmaf(__expf(dt*As[q*4+0]), h[q*4+0], dtx*bv[q*4+0]);
      h[q*4+1] = fmaf(__expf(dt*As[q*4+1]), h[q*4+1], dtx*bv[q*4+1]);
      h[q*4+2] = fmaf(__expf(dt*As[q*4+2]), h[q*4+2], dtx*bv[q*4+2]);
      h[q*4+3] = fmaf(__expf(dt*As[q*4+3]), h[q*4+3], dtx*bv[q*4+3]);
      y0 = fmaf(h[q*4+0], cv[q*4+0], y0);
      y1 = fmaf(h[q*4+1], cv[q*4+1], y1);
      y2 = fmaf(h[q*4+2], cv[q*4+2], y2);
      y3 = fmaf(h[q*4+3], cv[q*4+3], y3);
    }
    float y = (y0+y1) + (y2+y3);
    size_t n = (size_t)(t0+t)*BB + b;
    YGb[n*DINNER + c] = f2b((y + xp*Dv) * siluf(zg));
    dt = dtn; xp = xpn; zg = zgn;
  }
}

// ---------------- action head + Normal log-prob, 8 tokens/block (32 lanes per token)
__global__ __launch_bounds__(256) void head_logp_k(const float* __restrict__ X2,
    const float* __restrict__ Wh, const float* __restrict__ bh, const float* __restrict__ lstd,
    const float* __restrict__ a, float* __restrict__ out)
{
  int n = blockIdx.x*8 + (threadIdx.x >> 5);
  int j = threadIdx.x & 31;
  float accv = bh[j];
  const float* xr = &X2[(size_t)n*DMODEL];
  for (int k = 0; k < DMODEL; k += 4) {
    float4 xv = *(const float4*)&xr[k];
    accv = fmaf(xv.x, Wh[(k+0)*32 + j], accv);
    accv = fmaf(xv.y, Wh[(k+1)*32 + j], accv);
    accv = fmaf(xv.z, Wh[(k+2)*32 + j], accv);
    accv = fmaf(xv.w, Wh[(k+3)*32 + j], accv);
  }
  float ls = lstd[j];
  float z = (a[(size_t)n*32 + j] - accv) * __expf(-ls);
  float t = -0.5f*z*z - ls - 0.91893853320467274f;   // 0.5*log(2*pi)
  t += __shfl_xor(t, 1);
  t += __shfl_xor(t, 2);
  t += __shfl_xor(t, 4);
  t += __shfl_xor(t, 8);
  t += __shfl_xor(t, 16);
  if (j == 0) out[n] = t;
}

extern "C" void kernel_launch(void* const* d_in, const int* in_sizes, int n_in,
                              void* d_out, int out_size, void* d_ws, size_t ws_size,
                              hipStream_t stream)
{
  const float* s    = (const float*)d_in[0];
  const float* a    = (const float*)d_in[1];
  const float* Wemb = (const float*)d_in[2];
  const float* bemb = (const float*)d_in[3];
  const float* nw   = (const float*)d_in[4];
  const float* Win  = (const float*)d_in[5];
  const float* cw   = (const float*)d_in[6];
  const float* cb   = (const float*)d_in[7];
  const float* Wx   = (const float*)d_in[8];
  const float* Wdt  = (const float*)d_in[9];
  const float* bdt  = (const float*)d_in[10];
  const float* Alog = (const float*)d_in[11];
  const float* Dp   = (const float*)d_in[12];
  const float* Wout = (const float*)d_in[13];
  const float* Wh   = (const float*)d_in[14];
  const float* bh   = (const float*)d_in[15];
  const float* lstd = (const float*)d_in[16];

  float* X  = (float*)d_ws;                    // resid / final hidden (in-place)
  float* XN = X  + (size_t)NTOK*DMODEL;        // slot: XPb until xdbl, then HEND/H0
  float* XZ = XN + (size_t)NTOK*DMODEL;        // [xp | z]; xp-half rows reused as DTS
  float* XP = XZ + (size_t)NTOK*1024;
  float* DT = XP + (size_t)NTOK*DINNER;
  float* BM = DT + (size_t)NTOK*DINNER;
  float* CM = BM + (size_t)NTOK*16;
  float* YGslot = CM + (size_t)NTOK*16;        // old fp32 YG slot (33.5 MB) hosts bf16 bufs
  float* out = (float*)d_out;
  float* HEND = XN;
  float* DTS  = XZ;
  u16* XPb = (u16*)XN;                         // NTOK*512 bf16 = NTOK*256 fp32 exactly

  u16* YGb = (u16*)YGslot;                     // NTOK*512 bf16
  u16* sb  = YGb + (size_t)NTOK*DINNER;        // NTOK*128 bf16
  u16* XNb = sb  + (size_t)NTOK*128;           // NTOK*256 bf16
  u16* WTe = XNb + (size_t)NTOK*DMODEL;        // 256*128
  u16* WTi = WTe + 256*128;                    // 1024*256
  u16* WTo = WTi + 1024*256;                   // 256*512
  u16* WxT = WTo + 256*512;                    // 48*512
  u16* WdtTp = WxT + 48*512;                   // 512*32
  u16* DTRb  = WdtTp + 512*32;                 // NTOK*32 bf16 (dtr tile, cols 16..31 zero)

  tcast_k   <<<dim3(DMODEL/32, 128/32),    256, 0, stream>>>(Wemb, WTe, 128, DMODEL);
  tcast_k   <<<dim3(1024/32,  DMODEL/32),  256, 0, stream>>>(Win,  WTi, DMODEL, 1024);
  tcast_k   <<<dim3(DMODEL/32, DINNER/32), 256, 0, stream>>>(Wout, WTo, DINNER, DMODEL);
  tcastWx_k <<<48*512/256,                 256, 0, stream>>>(Wx, WxT);
  tcastWdt_k<<<512*32/256,                 256, 0, stream>>>(Wdt, WdtTp);
  castb_k   <<<NTOK*128/1024,              256, 0, stream>>>(s, sb);

  gemm_mfma<128><<<dim3(128,2), 256, 0, stream>>>(sb,  WTe, bemb,   nullptr, X,  DMODEL);
  rmsnorm_k     <<<4096,        256, 0, stream>>>(X, nw, XNb);
  gemm_mfma<256><<<dim3(128,8), 256, 0, stream>>>(XNb, WTi, nullptr, nullptr, XZ, 1024);
  conv_silu_k   <<<8192,        256, 0, stream>>>(XZ, cw, cb, XP, XPb);
  xdblBC_k      <<<512,         128, 0, stream>>>(XPb, WxT, BM, CM, DTRb);
  dtg_k         <<<dim3(128,4), 256, 0, stream>>>(DTRb, WdtTp, bdt, DT);
  scanA_k       <<<dim3(NSEG,BB,2), 256, 0, stream>>>(DT, XP, BM, Alog, HEND, DTS);
  stitch_k      <<<256,         256, 0, stream>>>(HEND, DTS, Alog);
  scanC_k       <<<dim3(NSEG,BB,2), 256, 0, stream>>>(DT, XP, BM, CM, XZ, Alog, Dp, HEND, YGb);
  gemm_mfma<512><<<dim3(128,2), 256, 0, stream>>>(YGb, WTo, nullptr, X,      X,  DMODEL);
  head_logp_k   <<<2048,        256, 0, stream>>>(X, Wh, bh, lstd, a, out);
}

// Round 9
// 336.294 us; speedup vs baseline: 2.5404x; 1.0388x over previous
//
#include <hip/hip_runtime.h>

typedef unsigned short u16;
typedef short bf16x8 __attribute__((ext_vector_type(8)));   // 8 bf16 = 4 VGPR
typedef float floatx4 __attribute__((ext_vector_type(4)));

#define LSEQ 2048
#define BB 8
#define NTOK (LSEQ*BB)        // 16384 tokens, n = l*B + b
#define DMODEL 256
#define DINNER 512
#define NSEG 128
#define SEGLEN 16             // LSEQ / NSEG

__device__ __forceinline__ float siluf(float x){ return x / (1.f + __expf(-x)); }
__device__ __forceinline__ float b2f(u16 x){ return __uint_as_float(((unsigned)x) << 16); }
__device__ __forceinline__ u16 f2b(float f){
  unsigned u = __float_as_uint(f);
  unsigned r = (u + 0x7fffu + ((u >> 16) & 1u)) >> 16;
  return (u16)r;
}

// ---------------- elementwise fp32 -> bf16 cast
__global__ __launch_bounds__(256) void castb_k(const float* __restrict__ in,
    u16* __restrict__ out)
{
  int i = (blockIdx.x*256 + threadIdx.x)*4;
  float4 v = *(const float4*)&in[i];
  ushort4 o; o.x = f2b(v.x); o.y = f2b(v.y); o.z = f2b(v.z); o.w = f2b(v.w);
  *(ushort4*)&out[i] = o;
}

// ---------------- transpose + cast: W[K][N] fp32 -> WT[N][K] bf16 (32x32 LDS tiles)
__global__ __launch_bounds__(256) void tcast_k(const float* __restrict__ W,
    u16* __restrict__ WT, int K, int N)
{
  __shared__ float S[32][33];
  int n0 = blockIdx.x*32, k0 = blockIdx.y*32;
  int tx = threadIdx.x & 31, ty = threadIdx.x >> 5;   // ty 0..7
  #pragma unroll
  for (int i = 0; i < 4; ++i)
    S[ty + 8*i][tx] = W[(size_t)(k0 + ty + 8*i)*N + n0 + tx];
  __syncthreads();
  #pragma unroll
  for (int i = 0; i < 4; ++i)
    WT[(size_t)(n0 + ty + 8*i)*K + k0 + tx] = f2b(S[tx][ty + 8*i]);
}

// ---------------- Wx[512][48] -> WxT[48][512] bf16 (tiny)
__global__ __launch_bounds__(256) void tcastWx_k(const float* __restrict__ Wx,
    u16* __restrict__ WxT)
{
  int idx = blockIdx.x*256 + threadIdx.x;    // 48*512
  int n = idx >> 9, k = idx & 511;
  WxT[idx] = f2b(Wx[k*48 + n]);
}

// ---------------- Wdt[16][512] -> WdtTp[512][32] bf16, rows r>=16 zero (tiny)
__global__ __launch_bounds__(256) void tcastWdt_k(const float* __restrict__ Wdt,
    u16* __restrict__ WdtTp)
{
  int idx = blockIdx.x*256 + threadIdx.x;    // 512*32
  int c = idx >> 5, r = idx & 31;
  WdtTp[idx] = (r < 16) ? f2b(Wdt[r*512 + c]) : (u16)0;
}

// ---------------- bf16 MFMA GEMM: C = A(MxK,bf16) @ W via WT[N][K] [+bias][+resid]
// OUTB: 0 = fp32 out, 1 = bf16 out
template<int K, int OUTB>
__global__ __launch_bounds__(256) void gemm_mfma(
    const u16* __restrict__ Ab, const u16* __restrict__ WT,
    const float* __restrict__ bias, const float* __restrict__ resid,
    void* __restrict__ Cv, int N)
{
  const int tid = threadIdx.x;
  const int wave = tid >> 6, lane = tid & 63;
  const int quad = lane >> 4, l16 = lane & 15;
  const int bm = blockIdx.x*128 + (wave & 1)*64;
  const int bn = blockIdx.y*128 + (wave >> 1)*64;
  floatx4 acc[4][4];
  #pragma unroll
  for (int r = 0; r < 4; ++r)
    #pragma unroll
    for (int c = 0; c < 4; ++c) acc[r][c] = (floatx4){0.f,0.f,0.f,0.f};

  const u16* Ap = Ab + (size_t)(bm + l16)*K + quad*8;
  const u16* Bp = WT + (size_t)(bn + l16)*K + quad*8;
  #pragma unroll 2
  for (int k0 = 0; k0 < K; k0 += 32) {
    bf16x8 af[4], bf[4];
    #pragma unroll
    for (int r = 0; r < 4; ++r) af[r] = *(const bf16x8*)(Ap + (size_t)r*16*K + k0);
    #pragma unroll
    for (int c = 0; c < 4; ++c) bf[c] = *(const bf16x8*)(Bp + (size_t)c*16*K + k0);
    #pragma unroll
    for (int r = 0; r < 4; ++r)
      #pragma unroll
      for (int c = 0; c < 4; ++c)
        acc[r][c] = __builtin_amdgcn_mfma_f32_16x16x32_bf16(af[r], bf[c], acc[r][c], 0, 0, 0);
  }
  #pragma unroll
  for (int c = 0; c < 4; ++c) {
    int n = bn + c*16 + l16;
    float bv = bias ? bias[n] : 0.f;
    #pragma unroll
    for (int r = 0; r < 4; ++r) {
      #pragma unroll
      for (int reg = 0; reg < 4; ++reg) {
        int m = bm + r*16 + quad*4 + reg;
        float t = acc[r][c][reg] + bv;
        if (resid) t += resid[(size_t)m*N + n];
        if (OUTB) ((u16*)Cv)[(size_t)m*N + n] = f2b(t);
        else      ((float*)Cv)[(size_t)m*N + n] = t;
      }
    }
  }
}

// ---------------- RMSNorm: one wave per token, writes bf16
__global__ __launch_bounds__(256) void rmsnorm_k(const float* __restrict__ X,
    const float* __restrict__ w, u16* __restrict__ XNb)
{
  int n = blockIdx.x*4 + (threadIdx.x >> 6);
  int lane = threadIdx.x & 63;
  const float4 x = *(const float4*)&X[(size_t)n*DMODEL + lane*4];
  float ss = x.x*x.x + x.y*x.y + x.z*x.z + x.w*x.w;
  #pragma unroll
  for (int m = 1; m < 64; m <<= 1) ss += __shfl_xor(ss, m);
  float r = rsqrtf(ss * (1.f/DMODEL) + 1e-5f);
  ushort4 o;
  o.x = f2b(x.x * r * w[lane*4+0]);
  o.y = f2b(x.y * r * w[lane*4+1]);
  o.z = f2b(x.z * r * w[lane*4+2]);
  o.w = f2b(x.w * r * w[lane*4+3]);
  *(ushort4*)&XNb[(size_t)n*DMODEL + lane*4] = o;
}

// ---------------- causal depthwise conv (K=4) + SiLU, bf16 in/out
__global__ __launch_bounds__(256) void conv_silu_k(const u16* __restrict__ XZb,
    const float* __restrict__ cw, const float* __restrict__ cb,
    u16* __restrict__ XPb)
{
  int g = blockIdx.x*256 + threadIdx.x;   // NTOK * 128 c4-groups
  int c4 = (g & 127) << 2;
  int n = g >> 7;
  int l = n >> 3;
  float w[4][4];
  #pragma unroll
  for (int i = 0; i < 4; ++i)
    #pragma unroll
    for (int k = 0; k < 4; ++k) w[i][k] = cw[(c4+i)*4 + k];
  float acc[4];
  #pragma unroll
  for (int i = 0; i < 4; ++i) acc[i] = cb[c4+i];
  #pragma unroll
  for (int k = 0; k < 4; ++k) {
    int lp = l - 3 + k;
    if (lp >= 0) {
      const ushort4 xv = *(const ushort4*)&XZb[(size_t)(n - BB*(3-k))*1024 + c4];
      acc[0] = fmaf(w[0][k], b2f(xv.x), acc[0]);
      acc[1] = fmaf(w[1][k], b2f(xv.y), acc[1]);
      acc[2] = fmaf(w[2][k], b2f(xv.z), acc[2]);
      acc[3] = fmaf(w[3][k], b2f(xv.w), acc[3]);
    }
  }
  ushort4 ob;
  ob.x = f2b(siluf(acc[0])); ob.y = f2b(siluf(acc[1]));
  ob.z = f2b(siluf(acc[2])); ob.w = f2b(siluf(acc[3]));
  *(ushort4*)&XPb[(size_t)n*DINNER + c4] = ob;
}

// ---------------- GEMM1 of x_dbl: B/C/dtr = XPb @ WxT^T (N=48, K=512)
__global__ __launch_bounds__(128) void xdblBC_k(const u16* __restrict__ XPb,
    const u16* __restrict__ WxT,
    float* __restrict__ BM, float* __restrict__ CM, u16* __restrict__ DTRb)
{
  const int tid = threadIdx.x;
  const int wave = tid >> 6, lane = tid & 63;
  const int quad = lane >> 4, l16 = lane & 15;
  const int tok0 = blockIdx.x*32 + wave*16;

  floatx4 acc[3];
  #pragma unroll
  for (int j = 0; j < 3; ++j) acc[j] = (floatx4){0.f,0.f,0.f,0.f};
  const u16* Ap = XPb + (size_t)(tok0 + l16)*DINNER + quad*8;
  const u16* Bp = WxT + (size_t)l16*DINNER + quad*8;
  #pragma unroll
  for (int k0 = 0; k0 < DINNER; k0 += 32) {
    bf16x8 af = *(const bf16x8*)(Ap + k0);
    #pragma unroll
    for (int j = 0; j < 3; ++j) {
      bf16x8 bf = *(const bf16x8*)(Bp + (size_t)j*16*DINNER + k0);
      acc[j] = __builtin_amdgcn_mfma_f32_16x16x32_bf16(af, bf, acc[j], 0, 0, 0);
    }
  }
  #pragma unroll
  for (int reg = 0; reg < 4; ++reg) {
    size_t t = (size_t)(tok0 + quad*4 + reg);
    BM[t*16 + l16] = acc[1][reg];
    CM[t*16 + l16] = acc[2][reg];
    DTRb[t*32 + l16]      = f2b(acc[0][reg]);
    DTRb[t*32 + 16 + l16] = 0;
  }
}

// ---------------- dt GEMM: DT = softplus(DTRb @ WdtTp^T + b_dt)
__global__ __launch_bounds__(256) void dtg_k(const u16* __restrict__ DTRb,
    const u16* __restrict__ WdtTp, const float* __restrict__ bdt,
    float* __restrict__ DT)
{
  const int tid = threadIdx.x;
  const int wave = tid >> 6, lane = tid & 63;
  const int quad = lane >> 4, l16 = lane & 15;
  const int bm = blockIdx.x*128 + (wave & 1)*64;
  const int bn = blockIdx.y*128 + (wave >> 1)*64;
  bf16x8 af[4], bf[4];
  #pragma unroll
  for (int r = 0; r < 4; ++r)
    af[r] = *(const bf16x8*)(DTRb + (size_t)(bm + r*16 + l16)*32 + quad*8);
  #pragma unroll
  for (int c = 0; c < 4; ++c)
    bf[c] = *(const bf16x8*)(WdtTp + (size_t)(bn + c*16 + l16)*32 + quad*8);
  #pragma unroll
  for (int c = 0; c < 4; ++c) {
    int n = bn + c*16 + l16;
    float bd = bdt[n];
    #pragma unroll
    for (int r = 0; r < 4; ++r) {
      floatx4 d = __builtin_amdgcn_mfma_f32_16x16x32_bf16(af[r], bf[c],
                    (floatx4){0.f,0.f,0.f,0.f}, 0, 0, 0);
      #pragma unroll
      for (int reg = 0; reg < 4; ++reg) {
        int m = bm + r*16 + quad*4 + reg;
        float sum = d[reg] + bd;
        DT[(size_t)m*DINNER + n] = (sum > 20.f) ? sum : __logf(1.f + __expf(sum));
      }
    }
  }
}

// ---------------- scan phase A: per-segment h_end (h0=0) + sum(dt)
__global__ __launch_bounds__(256) void scanA_k(const float* __restrict__ DT,
    const u16* __restrict__ XPb, const float* __restrict__ BM,
    const float* __restrict__ Alog, float* __restrict__ HEND, float* __restrict__ DTS)
{
  __shared__ __align__(16) float Bs[SEGLEN*16];
  const int tid = threadIdx.x;
  const int seg = blockIdx.x, b = blockIdx.y, half = blockIdx.z;
  const int c = half*256 + tid;
  const int t0 = seg*SEGLEN;
  {
    int t = tid >> 4, s = tid & 15;
    Bs[tid] = BM[((size_t)(t0+t)*BB + b)*16 + s];
  }
  float As[16];
  #pragma unroll
  for (int s = 0; s < 16; ++s) As[s] = -__expf(Alog[c*16+s]);
  bool uni = true;
  #pragma unroll
  for (int s = 1; s < 16; ++s)
    uni = uni && (fabsf(As[s] - As[0]*(float)(s+1)) <= 1e-4f*(float)(s+1));
  float h[16];
  #pragma unroll
  for (int s = 0; s < 16; ++s) h[s] = 0.f;
  float dts = 0.f;
  __syncthreads();
  const size_t base = (size_t)t0*BB + b;
  const float* dtp = DT  + base*DINNER + c;
  const u16*   xpp = XPb + base*DINNER + c;
  float dt = dtp[0];
  float xp = b2f(xpp[0]);
  for (int t = 0; t < SEGLEN; ++t) {
    float dtn = 0.f, xpn = 0.f;
    if (t+1 < SEGLEN) {
      dtn = dtp[(size_t)(t+1)*BB*DINNER];
      xpn = b2f(xpp[(size_t)(t+1)*BB*DINNER]);
    }
    dts += dt;
    float dtx = dt * xp;
    const float4 b0 = *(const float4*)&Bs[t*16+0];
    const float4 b1 = *(const float4*)&Bs[t*16+4];
    const float4 b2 = *(const float4*)&Bs[t*16+8];
    const float4 b3 = *(const float4*)&Bs[t*16+12];
    const float bv[16] = {b0.x,b0.y,b0.z,b0.w, b1.x,b1.y,b1.z,b1.w,
                          b2.x,b2.y,b2.z,b2.w, b3.x,b3.y,b3.z,b3.w};
    float dA[16];
    if (uni) {
      float p = __expf(dt*As[0]);
      dA[0] = p;
      #pragma unroll
      for (int s = 1; s < 16; ++s) dA[s] = dA[s-1]*p;
    } else {
      #pragma unroll
      for (int s = 0; s < 16; ++s) dA[s] = __expf(dt*As[s]);
    }
    #pragma unroll
    for (int s = 0; s < 16; ++s)
      h[s] = fmaf(dA[s], h[s], dtx*bv[s]);
    dt = dtn; xp = xpn;
  }
  float* hp = &HEND[(((size_t)seg*BB + b)*DINNER + c)*16];
  #pragma unroll
  for (int q = 0; q < 4; ++q)
    *(float4*)&hp[q*4] = make_float4(h[q*4], h[q*4+1], h[q*4+2], h[q*4+3]);
  DTS[((size_t)seg*BB + b)*DINNER + c] = dts;
}

// ---------------- stitch: sequential over NSEG segments, in-place HEND -> h0
__global__ __launch_bounds__(256) void stitch_k(float* __restrict__ HEND,
    const float* __restrict__ DTS, const float* __restrict__ Alog)
{
  int g = blockIdx.x*256 + threadIdx.x;
  int b = g >> 13;
  int rem = g & 8191;          // c*16+s
  int cidx = rem >> 4;
  float A = -__expf(Alog[rem]);
  float h0 = 0.f;
  for (int k = 0; k < NSEG; ++k) {
    size_t idx = (((size_t)k*BB + b) << 13) + rem;
    float hend = HEND[idx];
    HEND[idx] = h0;
    float dts = DTS[((size_t)k*BB + b)*DINNER + cidx];
    h0 = fmaf(__expf(dts*A), h0, hend);
  }
}

// ---------------- scan phase C: full scan with h0, fused gate + bf16 output
__global__ __launch_bounds__(256) void scanC_k(const float* __restrict__ DT,
    const u16* __restrict__ XPb, const float* __restrict__ BM, const float* __restrict__ CM,
    const u16* __restrict__ XZb, const float* __restrict__ Alog, const float* __restrict__ Dp,
    const float* __restrict__ H0, u16* __restrict__ YGb)
{
  __shared__ __align__(16) float Bs[SEGLEN*16];
  __shared__ __align__(16) float Cs[SEGLEN*16];
  const int tid = threadIdx.x;
  const int seg = blockIdx.x, b = blockIdx.y, half = blockIdx.z;
  const int c = half*256 + tid;
  const int t0 = seg*SEGLEN;
  {
    int t = tid >> 4, s = tid & 15;
    size_t nb = ((size_t)(t0+t)*BB + b)*16 + s;
    Bs[tid] = BM[nb];
    Cs[tid] = CM[nb];
  }
  float As[16];
  #pragma unroll
  for (int s = 0; s < 16; ++s) As[s] = -__expf(Alog[c*16+s]);
  bool uni = true;
  #pragma unroll
  for (int s = 1; s < 16; ++s)
    uni = uni && (fabsf(As[s] - As[0]*(float)(s+1)) <= 1e-4f*(float)(s+1));
  float h[16];
  const float* hp = &H0[(((size_t)seg*BB + b)*DINNER + c)*16];
  #pragma unroll
  for (int q = 0; q < 4; ++q) {
    float4 hv = *(const float4*)&hp[q*4];
    h[q*4+0]=hv.x; h[q*4+1]=hv.y; h[q*4+2]=hv.z; h[q*4+3]=hv.w;
  }
  const float Dv = Dp[c];
  __syncthreads();
  const size_t base = (size_t)t0*BB + b;
  const float* dtp = DT  + base*DINNER + c;
  const u16*   xpp = XPb + base*DINNER + c;
  const u16*   zp  = XZb + base*1024 + DINNER + c;
  u16*         ygp = YGb + base*DINNER + c;
  float dt = dtp[0];
  float xp = b2f(xpp[0]);
  float zg = b2f(zp[0]);
  for (int t = 0; t < SEGLEN; ++t) {
    float dtn = 0.f, xpn = 0.f, zgn = 0.f;
    if (t+1 < SEGLEN) {
      dtn = dtp[(size_t)(t+1)*BB*DINNER];
      xpn = b2f(xpp[(size_t)(t+1)*BB*DINNER]);
      zgn = b2f(zp[(size_t)(t+1)*BB*1024]);
    }
    float dtx = dt * xp;
    const float4 b0 = *(const float4*)&Bs[t*16+0];
    const float4 b1 = *(const float4*)&Bs[t*16+4];
    const float4 b2 = *(const float4*)&Bs[t*16+8];
    const float4 b3 = *(const float4*)&Bs[t*16+12];
    const float4 c0 = *(const float4*)&Cs[t*16+0];
    const float4 c1 = *(const float4*)&Cs[t*16+4];
    const float4 c2 = *(const float4*)&Cs[t*16+8];
    const float4 c3 = *(const float4*)&Cs[t*16+12];
    const float bv[16] = {b0.x,b0.y,b0.z,b0.w, b1.x,b1.y,b1.z,b1.w,
                          b2.x,b2.y,b2.z,b2.w, b3.x,b3.y,b3.z,b3.w};
    const float cv[16] = {c0.x,c0.y,c0.z,c0.w, c1.x,c1.y,c1.z,c1.w,
                          c2.x,c2.y,c2.z,c2.w, c3.x,c3.y,c3.z,c3.w};
    float dA[16];
    if (uni) {
      float p = __expf(dt*As[0]);
      dA[0] = p;
      #pragma unroll
      for (int s = 1; s < 16; ++s) dA[s] = dA[s-1]*p;
    } else {
      #pragma unroll
      for (int s = 0; s < 16; ++s) dA[s] = __expf(dt*As[s]);
    }
    float y0 = 0.f, y1 = 0.f, y2 = 0.f, y3 = 0.f;
    #pragma unroll
    for (int q = 0; q < 4; ++q) {
      h[q*4+0] = fmaf(dA[q*4+0], h[q*4+0], dtx*bv[q*4+0]);
      h[q*4+1] = fmaf(dA[q*4+1], h[q*4+1], dtx*bv[q*4+1]);
      h[q*4+2] = fmaf(dA[q*4+2], h[q*4+2], dtx*bv[q*4+2]);
      h[q*4+3] = fmaf(dA[q*4+3], h[q*4+3], dtx*bv[q*4+3]);
      y0 = fmaf(h[q*4+0], cv[q*4+0], y0);
      y1 = fmaf(h[q*4+1], cv[q*4+1], y1);
      y2 = fmaf(h[q*4+2], cv[q*4+2], y2);
      y3 = fmaf(h[q*4+3], cv[q*4+3], y3);
    }
    float y = (y0+y1) + (y2+y3);
    ygp[(size_t)t*BB*DINNER] = f2b((y + xp*Dv) * siluf(zg));
    dt = dtn; xp = xpn; zg = zgn;
  }
}

// ---------------- action head + Normal log-prob, 8 tokens/block
__global__ __launch_bounds__(256) void head_logp_k(const float* __restrict__ X2,
    const float* __restrict__ Wh, const float* __restrict__ bh, const float* __restrict__ lstd,
    const float* __restrict__ a, float* __restrict__ out)
{
  int n = blockIdx.x*8 + (threadIdx.x >> 5);
  int j = threadIdx.x & 31;
  float accv = bh[j];
  const float* xr = &X2[(size_t)n*DMODEL];
  for (int k = 0; k < DMODEL; k += 4) {
    float4 xv = *(const float4*)&xr[k];
    accv = fmaf(xv.x, Wh[(k+0)*32 + j], accv);
    accv = fmaf(xv.y, Wh[(k+1)*32 + j], accv);
    accv = fmaf(xv.z, Wh[(k+2)*32 + j], accv);
    accv = fmaf(xv.w, Wh[(k+3)*32 + j], accv);
  }
  float ls = lstd[j];
  float z = (a[(size_t)n*32 + j] - accv) * __expf(-ls);
  float t = -0.5f*z*z - ls - 0.91893853320467274f;   // 0.5*log(2*pi)
  t += __shfl_xor(t, 1);
  t += __shfl_xor(t, 2);
  t += __shfl_xor(t, 4);
  t += __shfl_xor(t, 8);
  t += __shfl_xor(t, 16);
  if (j == 0) out[n] = t;
}

extern "C" void kernel_launch(void* const* d_in, const int* in_sizes, int n_in,
                              void* d_out, int out_size, void* d_ws, size_t ws_size,
                              hipStream_t stream)
{
  const float* s    = (const float*)d_in[0];
  const float* a    = (const float*)d_in[1];
  const float* Wemb = (const float*)d_in[2];
  const float* bemb = (const float*)d_in[3];
  const float* nw   = (const float*)d_in[4];
  const float* Win  = (const float*)d_in[5];
  const float* cw   = (const float*)d_in[6];
  const float* cb   = (const float*)d_in[7];
  const float* Wx   = (const float*)d_in[8];
  const float* Wdt  = (const float*)d_in[9];
  const float* bdt  = (const float*)d_in[10];
  const float* Alog = (const float*)d_in[11];
  const float* Dp   = (const float*)d_in[12];
  const float* Wout = (const float*)d_in[13];
  const float* Wh   = (const float*)d_in[14];
  const float* bh   = (const float*)d_in[15];
  const float* lstd = (const float*)d_in[16];

  // -------- workspace layout (~170 MB)
  float* X    = (float*)d_ws;                       // NTOK*256 fp32
  u16*   XZb  = (u16*)(X + (size_t)NTOK*DMODEL);    // NTOK*1024 bf16 [xp|z]
  u16*   XPb  = XZb + (size_t)NTOK*1024;            // NTOK*512 bf16
  float* DT   = (float*)(XPb + (size_t)NTOK*DINNER);// NTOK*512 fp32
  float* BM   = DT + (size_t)NTOK*DINNER;           // NTOK*16
  float* CM   = BM + (size_t)NTOK*16;               // NTOK*16
  float* HEND = CM + (size_t)NTOK*16;               // NSEG*8*512*16 fp32
  float* DTS  = HEND + (size_t)NSEG*BB*DINNER*16;   // NSEG*8*512 fp32
  u16*   YGb  = (u16*)(DTS + (size_t)NSEG*BB*DINNER);
  u16*   sb   = YGb + (size_t)NTOK*DINNER;          // NTOK*128
  u16*   XNb  = sb  + (size_t)NTOK*128;             // NTOK*256
  u16*   WTe  = XNb + (size_t)NTOK*DMODEL;          // 256*128
  u16*   WTi  = WTe + 256*128;                      // 1024*256
  u16*   WTo  = WTi + 1024*256;                     // 256*512
  u16*   WxT  = WTo + 256*512;                      // 48*512
  u16*   WdtTp= WxT + 48*512;                       // 512*32
  u16*   DTRb = WdtTp + 512*32;                     // NTOK*32
  float* out  = (float*)d_out;

  tcast_k   <<<dim3(DMODEL/32, 128/32),    256, 0, stream>>>(Wemb, WTe, 128, DMODEL);
  tcast_k   <<<dim3(1024/32,  DMODEL/32),  256, 0, stream>>>(Win,  WTi, DMODEL, 1024);
  tcast_k   <<<dim3(DMODEL/32, DINNER/32), 256, 0, stream>>>(Wout, WTo, DINNER, DMODEL);
  tcastWx_k <<<48*512/256,                 256, 0, stream>>>(Wx, WxT);
  tcastWdt_k<<<512*32/256,                 256, 0, stream>>>(Wdt, WdtTp);
  castb_k   <<<NTOK*128/1024,              256, 0, stream>>>(s, sb);

  gemm_mfma<128,0><<<dim3(128,2), 256, 0, stream>>>(sb,  WTe, bemb,   nullptr, X,   DMODEL);
  rmsnorm_k       <<<4096,        256, 0, stream>>>(X, nw, XNb);
  gemm_mfma<256,1><<<dim3(128,8), 256, 0, stream>>>(XNb, WTi, nullptr, nullptr, XZb, 1024);
  conv_silu_k     <<<8192,        256, 0, stream>>>(XZb, cw, cb, XPb);
  xdblBC_k        <<<512,         128, 0, stream>>>(XPb, WxT, BM, CM, DTRb);
  dtg_k           <<<dim3(128,4), 256, 0, stream>>>(DTRb, WdtTp, bdt, DT);
  scanA_k         <<<dim3(NSEG,BB,2), 256, 0, stream>>>(DT, XPb, BM, Alog, HEND, DTS);
  stitch_k        <<<256,         256, 0, stream>>>(HEND, DTS, Alog);
  scanC_k         <<<dim3(NSEG,BB,2), 256, 0, stream>>>(DT, XPb, BM, CM, XZb, Alog, Dp, HEND, YGb);
  gemm_mfma<512,0><<<dim3(128,2), 256, 0, stream>>>(YGb, WTo, nullptr, X,      X,   DMODEL);
  head_logp_k     <<<2048,        256, 0, stream>>>(X, Wh, bh, lstd, a, out);
}

// Round 10
// 280.797 us; speedup vs baseline: 3.0425x; 1.1976x over previous
//
#include <hip/hip_runtime.h>

typedef unsigned short u16;
typedef short bf16x8 __attribute__((ext_vector_type(8)));   // 8 bf16 = 4 VGPR
typedef float floatx4 __attribute__((ext_vector_type(4)));

#define LSEQ 2048
#define BB 8
#define NTOK (LSEQ*BB)        // 16384 tokens, n = l*B + b
#define DMODEL 256
#define DINNER 512
#define NSEG 128
#define SEGLEN 16             // LSEQ / NSEG

__device__ __forceinline__ float siluf(float x){ return x / (1.f + __expf(-x)); }
__device__ __forceinline__ float b2f(u16 x){ return __uint_as_float(((unsigned)x) << 16); }
__device__ __forceinline__ u16 f2b(float f){
  unsigned u = __float_as_uint(f);
  unsigned r = (u + 0x7fffu + ((u >> 16) & 1u)) >> 16;
  return (u16)r;
}

// ---------------- fused prep: s cast + 6 weight transpose/casts, range-switched
// blocks: [0,2048) sb | [2048,2176) WTe | [2176,3200) WTi | [3200,3712) WTo
//         [3712,3808) WxT | [3808,3872) WdtTp | [3872,3904) WhT
__global__ __launch_bounds__(256) void prep_k(
    const float* __restrict__ s, const float* __restrict__ Wemb,
    const float* __restrict__ Win, const float* __restrict__ Wout,
    const float* __restrict__ Wx, const float* __restrict__ Wdt,
    const float* __restrict__ Wh,
    u16* __restrict__ sb, u16* __restrict__ WTe, u16* __restrict__ WTi,
    u16* __restrict__ WTo, u16* __restrict__ WxT, u16* __restrict__ WdtTp,
    u16* __restrict__ WhT)
{
  int g = blockIdx.x, tid = threadIdx.x;
  if (g < 2048) {                       // s -> bf16, vectorized
    int i = (g*256 + tid)*4;
    float4 v = *(const float4*)&s[i];
    ushort4 o; o.x=f2b(v.x); o.y=f2b(v.y); o.z=f2b(v.z); o.w=f2b(v.w);
    *(ushort4*)&sb[i] = o;
  } else if (g < 2176) {                // WTe[n][k], n<256, k<128
    int idx = (g-2048)*256 + tid; int n = idx >> 7, k = idx & 127;
    WTe[idx] = f2b(Wemb[(size_t)k*256 + n]);
  } else if (g < 3200) {                // WTi[n][k], n<1024, k<256
    int idx = (g-2176)*256 + tid; int n = idx >> 8, k = idx & 255;
    WTi[idx] = f2b(Win[(size_t)k*1024 + n]);
  } else if (g < 3712) {                // WTo[n][k], n<256, k<512
    int idx = (g-3200)*256 + tid; int n = idx >> 9, k = idx & 511;
    WTo[idx] = f2b(Wout[(size_t)k*256 + n]);
  } else if (g < 3808) {                // WxT[48][512]
    int idx = (g-3712)*256 + tid; int n = idx >> 9, k = idx & 511;
    WxT[idx] = f2b(Wx[(size_t)k*48 + n]);
  } else if (g < 3872) {                // WdtTp[512][32], rows>=16 zero
    int idx = (g-3808)*256 + tid; int c = idx >> 5, r = idx & 31;
    WdtTp[idx] = (r < 16) ? f2b(Wdt[(size_t)r*512 + c]) : (u16)0;
  } else {                              // WhT[32][256]
    int idx = (g-3872)*256 + tid; int j = idx >> 8, k = idx & 255;
    WhT[idx] = f2b(Wh[(size_t)k*32 + j]);
  }
}

// ---------------- bf16 MFMA GEMM: C = A(MxK,bf16) @ W via WT[N][K] [+bias]
// OUTB: 0 = fp32 out, 1 = bf16 out
template<int K, int OUTB>
__global__ __launch_bounds__(256) void gemm_mfma(
    const u16* __restrict__ Ab, const u16* __restrict__ WT,
    const float* __restrict__ bias, void* __restrict__ Cv, int N)
{
  const int tid = threadIdx.x;
  const int wave = tid >> 6, lane = tid & 63;
  const int quad = lane >> 4, l16 = lane & 15;
  const int bm = blockIdx.x*128 + (wave & 1)*64;
  const int bn = blockIdx.y*128 + (wave >> 1)*64;
  floatx4 acc[4][4];
  #pragma unroll
  for (int r = 0; r < 4; ++r)
    #pragma unroll
    for (int c = 0; c < 4; ++c) acc[r][c] = (floatx4){0.f,0.f,0.f,0.f};

  const u16* Ap = Ab + (size_t)(bm + l16)*K + quad*8;
  const u16* Bp = WT + (size_t)(bn + l16)*K + quad*8;
  #pragma unroll 2
  for (int k0 = 0; k0 < K; k0 += 32) {
    bf16x8 af[4], bf[4];
    #pragma unroll
    for (int r = 0; r < 4; ++r) af[r] = *(const bf16x8*)(Ap + (size_t)r*16*K + k0);
    #pragma unroll
    for (int c = 0; c < 4; ++c) bf[c] = *(const bf16x8*)(Bp + (size_t)c*16*K + k0);
    #pragma unroll
    for (int r = 0; r < 4; ++r)
      #pragma unroll
      for (int c = 0; c < 4; ++c)
        acc[r][c] = __builtin_amdgcn_mfma_f32_16x16x32_bf16(af[r], bf[c], acc[r][c], 0, 0, 0);
  }
  #pragma unroll
  for (int c = 0; c < 4; ++c) {
    int n = bn + c*16 + l16;
    float bv = bias ? bias[n] : 0.f;
    #pragma unroll
    for (int r = 0; r < 4; ++r) {
      #pragma unroll
      for (int reg = 0; reg < 4; ++reg) {
        int m = bm + r*16 + quad*4 + reg;
        float t = acc[r][c][reg] + bv;
        if (OUTB) ((u16*)Cv)[(size_t)m*N + n] = f2b(t);
        else      ((float*)Cv)[(size_t)m*N + n] = t;
      }
    }
  }
}

// ---------------- RMSNorm: one wave per token, writes bf16
__global__ __launch_bounds__(256) void rmsnorm_k(const float* __restrict__ X,
    const float* __restrict__ w, u16* __restrict__ XNb)
{
  int n = blockIdx.x*4 + (threadIdx.x >> 6);
  int lane = threadIdx.x & 63;
  const float4 x = *(const float4*)&X[(size_t)n*DMODEL + lane*4];
  float ss = x.x*x.x + x.y*x.y + x.z*x.z + x.w*x.w;
  #pragma unroll
  for (int m = 1; m < 64; m <<= 1) ss += __shfl_xor(ss, m);
  float r = rsqrtf(ss * (1.f/DMODEL) + 1e-5f);
  ushort4 o;
  o.x = f2b(x.x * r * w[lane*4+0]);
  o.y = f2b(x.y * r * w[lane*4+1]);
  o.z = f2b(x.z * r * w[lane*4+2]);
  o.w = f2b(x.w * r * w[lane*4+3]);
  *(ushort4*)&XNb[(size_t)n*DMODEL + lane*4] = o;
}

// ---------------- causal depthwise conv (K=4) + SiLU, bf16 in/out
__global__ __launch_bounds__(256) void conv_silu_k(const u16* __restrict__ XZb,
    const float* __restrict__ cw, const float* __restrict__ cb,
    u16* __restrict__ XPb)
{
  int g = blockIdx.x*256 + threadIdx.x;   // NTOK * 128 c4-groups
  int c4 = (g & 127) << 2;
  int n = g >> 7;
  int l = n >> 3;
  float w[4][4];
  #pragma unroll
  for (int i = 0; i < 4; ++i)
    #pragma unroll
    for (int k = 0; k < 4; ++k) w[i][k] = cw[(c4+i)*4 + k];
  float acc[4];
  #pragma unroll
  for (int i = 0; i < 4; ++i) acc[i] = cb[c4+i];
  #pragma unroll
  for (int k = 0; k < 4; ++k) {
    int lp = l - 3 + k;
    if (lp >= 0) {
      const ushort4 xv = *(const ushort4*)&XZb[(size_t)(n - BB*(3-k))*1024 + c4];
      acc[0] = fmaf(w[0][k], b2f(xv.x), acc[0]);
      acc[1] = fmaf(w[1][k], b2f(xv.y), acc[1]);
      acc[2] = fmaf(w[2][k], b2f(xv.z), acc[2]);
      acc[3] = fmaf(w[3][k], b2f(xv.w), acc[3]);
    }
  }
  ushort4 ob;
  ob.x = f2b(siluf(acc[0])); ob.y = f2b(siluf(acc[1]));
  ob.z = f2b(siluf(acc[2])); ob.w = f2b(siluf(acc[3]));
  *(ushort4*)&XPb[(size_t)n*DINNER + c4] = ob;
}

// ---------------- GEMM1 of x_dbl: B/C/dtr = XPb @ WxT^T (N=48, K=512)
__global__ __launch_bounds__(128) void xdblBC_k(const u16* __restrict__ XPb,
    const u16* __restrict__ WxT,
    float* __restrict__ BM, float* __restrict__ CM, u16* __restrict__ DTRb)
{
  const int tid = threadIdx.x;
  const int wave = tid >> 6, lane = tid & 63;
  const int quad = lane >> 4, l16 = lane & 15;
  const int tok0 = blockIdx.x*32 + wave*16;

  floatx4 acc[3];
  #pragma unroll
  for (int j = 0; j < 3; ++j) acc[j] = (floatx4){0.f,0.f,0.f,0.f};
  const u16* Ap = XPb + (size_t)(tok0 + l16)*DINNER + quad*8;
  const u16* Bp = WxT + (size_t)l16*DINNER + quad*8;
  #pragma unroll
  for (int k0 = 0; k0 < DINNER; k0 += 32) {
    bf16x8 af = *(const bf16x8*)(Ap + k0);
    #pragma unroll
    for (int j = 0; j < 3; ++j) {
      bf16x8 bf = *(const bf16x8*)(Bp + (size_t)j*16*DINNER + k0);
      acc[j] = __builtin_amdgcn_mfma_f32_16x16x32_bf16(af, bf, acc[j], 0, 0, 0);
    }
  }
  #pragma unroll
  for (int reg = 0; reg < 4; ++reg) {
    size_t t = (size_t)(tok0 + quad*4 + reg);
    BM[t*16 + l16] = acc[1][reg];
    CM[t*16 + l16] = acc[2][reg];
    DTRb[t*32 + l16]      = f2b(acc[0][reg]);
    DTRb[t*32 + 16 + l16] = 0;
  }
}

// ---------------- dt GEMM: DTb = softplus(DTRb @ WdtTp^T + b_dt), bf16 out
__global__ __launch_bounds__(256) void dtg_k(const u16* __restrict__ DTRb,
    const u16* __restrict__ WdtTp, const float* __restrict__ bdt,
    u16* __restrict__ DTb)
{
  const int tid = threadIdx.x;
  const int wave = tid >> 6, lane = tid & 63;
  const int quad = lane >> 4, l16 = lane & 15;
  const int bm = blockIdx.x*128 + (wave & 1)*64;
  const int bn = blockIdx.y*128 + (wave >> 1)*64;
  bf16x8 af[4], bf[4];
  #pragma unroll
  for (int r = 0; r < 4; ++r)
    af[r] = *(const bf16x8*)(DTRb + (size_t)(bm + r*16 + l16)*32 + quad*8);
  #pragma unroll
  for (int c = 0; c < 4; ++c)
    bf[c] = *(const bf16x8*)(WdtTp + (size_t)(bn + c*16 + l16)*32 + quad*8);
  #pragma unroll
  for (int c = 0; c < 4; ++c) {
    int n = bn + c*16 + l16;
    float bd = bdt[n];
    #pragma unroll
    for (int r = 0; r < 4; ++r) {
      floatx4 d = __builtin_amdgcn_mfma_f32_16x16x32_bf16(af[r], bf[c],
                    (floatx4){0.f,0.f,0.f,0.f}, 0, 0, 0);
      #pragma unroll
      for (int reg = 0; reg < 4; ++reg) {
        int m = bm + r*16 + quad*4 + reg;
        float sum = d[reg] + bd;
        DTb[(size_t)m*DINNER + n] = f2b((sum > 20.f) ? sum : __logf(1.f + __expf(sum)));
      }
    }
  }
}

// ---------------- scan phase A: per-segment h_end (h0=0) + sum(dt)
__global__ __launch_bounds__(256) void scanA_k(const u16* __restrict__ DTb,
    const u16* __restrict__ XPb, const float* __restrict__ BM,
    const float* __restrict__ Alog, float* __restrict__ HEND, float* __restrict__ DTS)
{
  __shared__ __align__(16) float Bs[SEGLEN*16];
  const int tid = threadIdx.x;
  const int seg = blockIdx.x, b = blockIdx.y, half = blockIdx.z;
  const int c = half*256 + tid;
  const int t0 = seg*SEGLEN;
  {
    int t = tid >> 4, s = tid & 15;
    Bs[tid] = BM[((size_t)(t0+t)*BB + b)*16 + s];
  }
  float As[16];
  #pragma unroll
  for (int s = 0; s < 16; ++s) As[s] = -__expf(Alog[c*16+s]);
  bool uni = true;
  #pragma unroll
  for (int s = 1; s < 16; ++s)
    uni = uni && (fabsf(As[s] - As[0]*(float)(s+1)) <= 1e-4f*(float)(s+1));
  float h[16];
  #pragma unroll
  for (int s = 0; s < 16; ++s) h[s] = 0.f;
  float dts = 0.f;
  __syncthreads();
  const size_t base = (size_t)t0*BB + b;
  const u16* dtp = DTb + base*DINNER + c;
  const u16* xpp = XPb + base*DINNER + c;
  float dt = b2f(dtp[0]);
  float xp = b2f(xpp[0]);
  for (int t = 0; t < SEGLEN; ++t) {
    float dtn = 0.f, xpn = 0.f;
    if (t+1 < SEGLEN) {
      dtn = b2f(dtp[(size_t)(t+1)*BB*DINNER]);
      xpn = b2f(xpp[(size_t)(t+1)*BB*DINNER]);
    }
    dts += dt;
    float dtx = dt * xp;
    const float4 b0 = *(const float4*)&Bs[t*16+0];
    const float4 b1 = *(const float4*)&Bs[t*16+4];
    const float4 b2 = *(const float4*)&Bs[t*16+8];
    const float4 b3 = *(const float4*)&Bs[t*16+12];
    const float bv[16] = {b0.x,b0.y,b0.z,b0.w, b1.x,b1.y,b1.z,b1.w,
                          b2.x,b2.y,b2.z,b2.w, b3.x,b3.y,b3.z,b3.w};
    float dA[16];
    if (uni) {
      float p = __expf(dt*As[0]);
      dA[0] = p;
      #pragma unroll
      for (int s = 1; s < 16; ++s) dA[s] = dA[s-1]*p;
    } else {
      #pragma unroll
      for (int s = 0; s < 16; ++s) dA[s] = __expf(dt*As[s]);
    }
    #pragma unroll
    for (int s = 0; s < 16; ++s)
      h[s] = fmaf(dA[s], h[s], dtx*bv[s]);
    dt = dtn; xp = xpn;
  }
  float* hp = &HEND[(((size_t)seg*BB + b)*DINNER + c)*16];
  #pragma unroll
  for (int q = 0; q < 4; ++q)
    *(float4*)&hp[q*4] = make_float4(h[q*4], h[q*4+1], h[q*4+2], h[q*4+3]);
  DTS[((size_t)seg*BB + b)*DINNER + c] = dts;
}

// ---------------- stitch: sequential over NSEG segments, in-place HEND -> h0
__global__ __launch_bounds__(256) void stitch_k(float* __restrict__ HEND,
    const float* __restrict__ DTS, const float* __restrict__ Alog)
{
  int g = blockIdx.x*256 + threadIdx.x;
  int b = g >> 13;
  int rem = g & 8191;          // c*16+s
  int cidx = rem >> 4;
  float A = -__expf(Alog[rem]);
  float h0 = 0.f;
  for (int k = 0; k < NSEG; ++k) {
    size_t idx = (((size_t)k*BB + b) << 13) + rem;
    float hend = HEND[idx];
    HEND[idx] = h0;
    float dts = DTS[((size_t)k*BB + b)*DINNER + cidx];
    h0 = fmaf(__expf(dts*A), h0, hend);
  }
}

// ---------------- scan phase C: full scan with h0, fused gate + bf16 output
__global__ __launch_bounds__(256) void scanC_k(const u16* __restrict__ DTb,
    const u16* __restrict__ XPb, const float* __restrict__ BM, const float* __restrict__ CM,
    const u16* __restrict__ XZb, const float* __restrict__ Alog, const float* __restrict__ Dp,
    const float* __restrict__ H0, u16* __restrict__ YGb)
{
  __shared__ __align__(16) float Bs[SEGLEN*16];
  __shared__ __align__(16) float Cs[SEGLEN*16];
  const int tid = threadIdx.x;
  const int seg = blockIdx.x, b = blockIdx.y, half = blockIdx.z;
  const int c = half*256 + tid;
  const int t0 = seg*SEGLEN;
  {
    int t = tid >> 4, s = tid & 15;
    size_t nb = ((size_t)(t0+t)*BB + b)*16 + s;
    Bs[tid] = BM[nb];
    Cs[tid] = CM[nb];
  }
  float As[16];
  #pragma unroll
  for (int s = 0; s < 16; ++s) As[s] = -__expf(Alog[c*16+s]);
  bool uni = true;
  #pragma unroll
  for (int s = 1; s < 16; ++s)
    uni = uni && (fabsf(As[s] - As[0]*(float)(s+1)) <= 1e-4f*(float)(s+1));
  float h[16];
  const float* hp = &H0[(((size_t)seg*BB + b)*DINNER + c)*16];
  #pragma unroll
  for (int q = 0; q < 4; ++q) {
    float4 hv = *(const float4*)&hp[q*4];
    h[q*4+0]=hv.x; h[q*4+1]=hv.y; h[q*4+2]=hv.z; h[q*4+3]=hv.w;
  }
  const float Dv = Dp[c];
  __syncthreads();
  const size_t base = (size_t)t0*BB + b;
  const u16* dtp = DTb + base*DINNER + c;
  const u16* xpp = XPb + base*DINNER + c;
  const u16* zp  = XZb + base*1024 + DINNER + c;
  u16*       ygp = YGb + base*DINNER + c;
  float dt = b2f(dtp[0]);
  float xp = b2f(xpp[0]);
  float zg = b2f(zp[0]);
  for (int t = 0; t < SEGLEN; ++t) {
    float dtn = 0.f, xpn = 0.f, zgn = 0.f;
    if (t+1 < SEGLEN) {
      dtn = b2f(dtp[(size_t)(t+1)*BB*DINNER]);
      xpn = b2f(xpp[(size_t)(t+1)*BB*DINNER]);
      zgn = b2f(zp[(size_t)(t+1)*BB*1024]);
    }
    float dtx = dt * xp;
    const float4 b0 = *(const float4*)&Bs[t*16+0];
    const float4 b1 = *(const float4*)&Bs[t*16+4];
    const float4 b2 = *(const float4*)&Bs[t*16+8];
    const float4 b3 = *(const float4*)&Bs[t*16+12];
    const float4 c0 = *(const float4*)&Cs[t*16+0];
    const float4 c1 = *(const float4*)&Cs[t*16+4];
    const float4 c2 = *(const float4*)&Cs[t*16+8];
    const float4 c3 = *(const float4*)&Cs[t*16+12];
    const float bv[16] = {b0.x,b0.y,b0.z,b0.w, b1.x,b1.y,b1.z,b1.w,
                          b2.x,b2.y,b2.z,b2.w, b3.x,b3.y,b3.z,b3.w};
    const float cv[16] = {c0.x,c0.y,c0.z,c0.w, c1.x,c1.y,c1.z,c1.w,
                          c2.x,c2.y,c2.z,c2.w, c3.x,c3.y,c3.z,c3.w};
    float dA[16];
    if (uni) {
      float p = __expf(dt*As[0]);
      dA[0] = p;
      #pragma unroll
      for (int s = 1; s < 16; ++s) dA[s] = dA[s-1]*p;
    } else {
      #pragma unroll
      for (int s = 0; s < 16; ++s) dA[s] = __expf(dt*As[s]);
    }
    float y0 = 0.f, y1 = 0.f, y2 = 0.f, y3 = 0.f;
    #pragma unroll
    for (int q = 0; q < 4; ++q) {
      h[q*4+0] = fmaf(dA[q*4+0], h[q*4+0], dtx*bv[q*4+0]);
      h[q*4+1] = fmaf(dA[q*4+1], h[q*4+1], dtx*bv[q*4+1]);
      h[q*4+2] = fmaf(dA[q*4+2], h[q*4+2], dtx*bv[q*4+2]);
      h[q*4+3] = fmaf(dA[q*4+3], h[q*4+3], dtx*bv[q*4+3]);
      y0 = fmaf(h[q*4+0], cv[q*4+0], y0);
      y1 = fmaf(h[q*4+1], cv[q*4+1], y1);
      y2 = fmaf(h[q*4+2], cv[q*4+2], y2);
      y3 = fmaf(h[q*4+3], cv[q*4+3], y3);
    }
    float y = (y0+y1) + (y2+y3);
    ygp[(size_t)t*BB*DINNER] = f2b((y + xp*Dv) * siluf(zg));
    dt = dtn; xp = xpn; zg = zgn;
  }
}

// ---------------- fused out-proj + residual + action head + Normal log-prob.
// Block = 64 tokens x full N=256 (4 waves, each 64x64 over K=512).
// Epilogue stashes resid-added X tile as bf16 in LDS, then per-wave head MFMA
// (16 tokens x 32 outs, K=256) + in-wave reduce over j.
__global__ __launch_bounds__(256) void outhead_k(const u16* __restrict__ YGb,
    const u16* __restrict__ WTo, const float* __restrict__ Xres,
    const u16* __restrict__ WhT, const float* __restrict__ bh,
    const float* __restrict__ lstd, const float* __restrict__ a,
    float* __restrict__ out)
{
  __shared__ u16 Xs[64*264];
  const int tid = threadIdx.x;
  const int wave = tid >> 6, lane = tid & 63;
  const int quad = lane >> 4, l16 = lane & 15;
  const int m0 = blockIdx.x*64;
  const int n0 = wave*64;
  floatx4 acc[4][4];
  #pragma unroll
  for (int r = 0; r < 4; ++r)
    #pragma unroll
    for (int c = 0; c < 4; ++c) acc[r][c] = (floatx4){0.f,0.f,0.f,0.f};
  const u16* Ap = YGb + (size_t)(m0 + l16)*DINNER + quad*8;
  const u16* Bp = WTo + (size_t)(n0 + l16)*DINNER + quad*8;
  #pragma unroll 2
  for (int k0 = 0; k0 < DINNER; k0 += 32) {
    bf16x8 af[4], bf[4];
    #pragma unroll
    for (int r = 0; r < 4; ++r) af[r] = *(const bf16x8*)(Ap + (size_t)r*16*DINNER + k0);
    #pragma unroll
    for (int c = 0; c < 4; ++c) bf[c] = *(const bf16x8*)(Bp + (size_t)c*16*DINNER + k0);
    #pragma unroll
    for (int r = 0; r < 4; ++r)
      #pragma unroll
      for (int c = 0; c < 4; ++c)
        acc[r][c] = __builtin_amdgcn_mfma_f32_16x16x32_bf16(af[r], bf[c], acc[r][c], 0, 0, 0);
  }
  // resid add -> LDS bf16
  #pragma unroll
  for (int c = 0; c < 4; ++c) {
    int n = n0 + c*16 + l16;
    #pragma unroll
    for (int r = 0; r < 4; ++r) {
      #pragma unroll
      for (int reg = 0; reg < 4; ++reg) {
        int ml = r*16 + quad*4 + reg;
        float t = acc[r][c][reg] + Xres[(size_t)(m0 + ml)*DMODEL + n];
        Xs[ml*264 + n] = f2b(t);
      }
    }
  }
  __syncthreads();
  // head: wave handles tokens [wave*16, +16)
  floatx4 mu[2];
  mu[0] = (floatx4){0.f,0.f,0.f,0.f};
  mu[1] = (floatx4){0.f,0.f,0.f,0.f};
  #pragma unroll
  for (int k0 = 0; k0 < DMODEL; k0 += 32) {
    bf16x8 axf = *(const bf16x8*)&Xs[(wave*16 + l16)*264 + k0 + quad*8];
    #pragma unroll
    for (int nt = 0; nt < 2; ++nt) {
      bf16x8 bwf = *(const bf16x8*)(WhT + (size_t)(nt*16 + l16)*DMODEL + k0 + quad*8);
      mu[nt] = __builtin_amdgcn_mfma_f32_16x16x32_bf16(axf, bwf, mu[nt], 0, 0, 0);
    }
  }
  float ls0 = lstd[l16],      els0 = __expf(-ls0), bh0 = bh[l16];
  float ls1 = lstd[16 + l16], els1 = __expf(-ls1), bh1 = bh[16 + l16];
  #pragma unroll
  for (int reg = 0; reg < 4; ++reg) {
    int tok = m0 + wave*16 + quad*4 + reg;
    float m0v = mu[0][reg] + bh0;
    float m1v = mu[1][reg] + bh1;
    float z0 = (a[(size_t)tok*32 + l16]      - m0v) * els0;
    float z1 = (a[(size_t)tok*32 + 16 + l16] - m1v) * els1;
    float t = (-0.5f*z0*z0 - ls0) + (-0.5f*z1*z1 - ls1) - 2.f*0.91893853320467274f;
    t += __shfl_xor(t, 1);
    t += __shfl_xor(t, 2);
    t += __shfl_xor(t, 4);
    t += __shfl_xor(t, 8);
    if (l16 == 0) out[tok] = t;
  }
}

extern "C" void kernel_launch(void* const* d_in, const int* in_sizes, int n_in,
                              void* d_out, int out_size, void* d_ws, size_t ws_size,
                              hipStream_t stream)
{
  const float* s    = (const float*)d_in[0];
  const float* a    = (const float*)d_in[1];
  const float* Wemb = (const float*)d_in[2];
  const float* bemb = (const float*)d_in[3];
  const float* nw   = (const float*)d_in[4];
  const float* Win  = (const float*)d_in[5];
  const float* cw   = (const float*)d_in[6];
  const float* cb   = (const float*)d_in[7];
  const float* Wx   = (const float*)d_in[8];
  const float* Wdt  = (const float*)d_in[9];
  const float* bdt  = (const float*)d_in[10];
  const float* Alog = (const float*)d_in[11];
  const float* Dp   = (const float*)d_in[12];
  const float* Wout = (const float*)d_in[13];
  const float* Wh   = (const float*)d_in[14];
  const float* bh   = (const float*)d_in[15];
  const float* lstd = (const float*)d_in[16];

  // -------- workspace layout (~140 MB)
  float* X    = (float*)d_ws;                       // NTOK*256 fp32 (emb resid)
  u16*   XZb  = (u16*)(X + (size_t)NTOK*DMODEL);    // NTOK*1024 bf16 [xp|z]
  u16*   XPb  = XZb + (size_t)NTOK*1024;            // NTOK*512 bf16
  u16*   DTb  = XPb + (size_t)NTOK*DINNER;          // NTOK*512 bf16
  u16*   YGb  = DTb + (size_t)NTOK*DINNER;          // NTOK*512 bf16
  u16*   sb   = YGb + (size_t)NTOK*DINNER;          // NTOK*128 bf16
  u16*   XNb  = sb  + (size_t)NTOK*128;             // NTOK*256 bf16
  u16*   WTe  = XNb + (size_t)NTOK*DMODEL;          // 256*128
  u16*   WTi  = WTe + 256*128;                      // 1024*256
  u16*   WTo  = WTi + 1024*256;                     // 256*512
  u16*   WxT  = WTo + 256*512;                      // 48*512
  u16*   WdtTp= WxT + 48*512;                       // 512*32
  u16*   WhT  = WdtTp + 512*32;                     // 32*256
  u16*   DTRb = WhT + 32*256;                       // NTOK*32
  float* BM   = (float*)(DTRb + (size_t)NTOK*32);   // NTOK*16 fp32
  float* CM   = BM + (size_t)NTOK*16;               // NTOK*16 fp32
  float* HEND = CM + (size_t)NTOK*16;               // NSEG*8*512*16 fp32
  float* DTS  = HEND + (size_t)NSEG*BB*DINNER*16;   // NSEG*8*512 fp32
  float* out  = (float*)d_out;

  prep_k          <<<3904,        256, 0, stream>>>(s, Wemb, Win, Wout, Wx, Wdt, Wh,
                                                    sb, WTe, WTi, WTo, WxT, WdtTp, WhT);
  gemm_mfma<128,0><<<dim3(128,2), 256, 0, stream>>>(sb,  WTe, bemb,   X,   DMODEL);
  rmsnorm_k       <<<4096,        256, 0, stream>>>(X, nw, XNb);
  gemm_mfma<256,1><<<dim3(128,8), 256, 0, stream>>>(XNb, WTi, nullptr, XZb, 1024);
  conv_silu_k     <<<8192,        256, 0, stream>>>(XZb, cw, cb, XPb);
  xdblBC_k        <<<512,         128, 0, stream>>>(XPb, WxT, BM, CM, DTRb);
  dtg_k           <<<dim3(128,4), 256, 0, stream>>>(DTRb, WdtTp, bdt, DTb);
  scanA_k         <<<dim3(NSEG,BB,2), 256, 0, stream>>>(DTb, XPb, BM, Alog, HEND, DTS);
  stitch_k        <<<256,         256, 0, stream>>>(HEND, DTS, Alog);
  scanC_k         <<<dim3(NSEG,BB,2), 256, 0, stream>>>(DTb, XPb, BM, CM, XZb, Alog, Dp, HEND, YGb);
  outhead_k       <<<256,         256, 0, stream>>>(YGb, WTo, X, WhT, bh, lstd, a, out);
}

// Round 11
// 277.400 us; speedup vs baseline: 3.0797x; 1.0122x over previous
//
#include <hip/hip_runtime.h>

typedef unsigned short u16;
typedef short bf16x8 __attribute__((ext_vector_type(8)));   // 8 bf16 = 4 VGPR
typedef float floatx4 __attribute__((ext_vector_type(4)));

#define LSEQ 2048
#define BB 8
#define NTOK (LSEQ*BB)        // 16384 tokens, n = l*B + b
#define DMODEL 256
#define DINNER 512
#define NSEG 128
#define SEGLEN 16             // LSEQ / NSEG

__device__ __forceinline__ float siluf(float x){ return x / (1.f + __expf(-x)); }
__device__ __forceinline__ float b2f(u16 x){ return __uint_as_float(((unsigned)x) << 16); }
__device__ __forceinline__ u16 f2b(float f){
  unsigned u = __float_as_uint(f);
  unsigned r = (u + 0x7fffu + ((u >> 16) & 1u)) >> 16;
  return (u16)r;
}

// ---------------- fused prep: s cast + 6 weight transpose/casts, range-switched
__global__ __launch_bounds__(256) void prep_k(
    const float* __restrict__ s, const float* __restrict__ Wemb,
    const float* __restrict__ Win, const float* __restrict__ Wout,
    const float* __restrict__ Wx, const float* __restrict__ Wdt,
    const float* __restrict__ Wh,
    u16* __restrict__ sb, u16* __restrict__ WTe, u16* __restrict__ WTi,
    u16* __restrict__ WTo, u16* __restrict__ WxT, u16* __restrict__ WdtTp,
    u16* __restrict__ WhT)
{
  int g = blockIdx.x, tid = threadIdx.x;
  if (g < 2048) {                       // s -> bf16, vectorized
    int i = (g*256 + tid)*4;
    float4 v = *(const float4*)&s[i];
    ushort4 o; o.x=f2b(v.x); o.y=f2b(v.y); o.z=f2b(v.z); o.w=f2b(v.w);
    *(ushort4*)&sb[i] = o;
  } else if (g < 2176) {                // WTe[n][k], n<256, k<128
    int idx = (g-2048)*256 + tid; int n = idx >> 7, k = idx & 127;
    WTe[idx] = f2b(Wemb[(size_t)k*256 + n]);
  } else if (g < 3200) {                // WTi[n][k], n<1024, k<256
    int idx = (g-2176)*256 + tid; int n = idx >> 8, k = idx & 255;
    WTi[idx] = f2b(Win[(size_t)k*1024 + n]);
  } else if (g < 3712) {                // WTo[n][k], n<256, k<512
    int idx = (g-3200)*256 + tid; int n = idx >> 9, k = idx & 511;
    WTo[idx] = f2b(Wout[(size_t)k*256 + n]);
  } else if (g < 3808) {                // WxT[48][512]
    int idx = (g-3712)*256 + tid; int n = idx >> 9, k = idx & 511;
    WxT[idx] = f2b(Wx[(size_t)k*48 + n]);
  } else if (g < 3872) {                // WdtTp[512][32], rows>=16 zero
    int idx = (g-3808)*256 + tid; int c = idx >> 5, r = idx & 31;
    WdtTp[idx] = (r < 16) ? f2b(Wdt[(size_t)r*512 + c]) : (u16)0;
  } else {                              // WhT[32][256]
    int idx = (g-3872)*256 + tid; int j = idx >> 8, k = idx & 255;
    WhT[idx] = f2b(Wh[(size_t)k*32 + j]);
  }
}

// ---------------- bf16 MFMA GEMM: C = A(MxK,bf16) @ W via WT[N][K] [+bias]
// OUTB: 0 = fp32 out, 1 = bf16 out. Epilogue: LDS-staged, coalesced 16B stores.
template<int K, int OUTB>
__global__ __launch_bounds__(256) void gemm_mfma(
    const u16* __restrict__ Ab, const u16* __restrict__ WT,
    const float* __restrict__ bias, void* __restrict__ Cv, int N)
{
  __shared__ u16 Cs[128*136];           // 34816 B; also reused as float[64][132]
  const int tid = threadIdx.x;
  const int wave = tid >> 6, lane = tid & 63;
  const int quad = lane >> 4, l16 = lane & 15;
  const int bm0 = blockIdx.x*128, bn0 = blockIdx.y*128;
  const int bm = bm0 + (wave & 1)*64;
  const int bn = bn0 + (wave >> 1)*64;
  floatx4 acc[4][4];
  #pragma unroll
  for (int r = 0; r < 4; ++r)
    #pragma unroll
    for (int c = 0; c < 4; ++c) acc[r][c] = (floatx4){0.f,0.f,0.f,0.f};

  const u16* Ap = Ab + (size_t)(bm + l16)*K + quad*8;
  const u16* Bp = WT + (size_t)(bn + l16)*K + quad*8;
  #pragma unroll 2
  for (int k0 = 0; k0 < K; k0 += 32) {
    bf16x8 af[4], bf[4];
    #pragma unroll
    for (int r = 0; r < 4; ++r) af[r] = *(const bf16x8*)(Ap + (size_t)r*16*K + k0);
    #pragma unroll
    for (int c = 0; c < 4; ++c) bf[c] = *(const bf16x8*)(Bp + (size_t)c*16*K + k0);
    #pragma unroll
    for (int r = 0; r < 4; ++r)
      #pragma unroll
      for (int c = 0; c < 4; ++c)
        acc[r][c] = __builtin_amdgcn_mfma_f32_16x16x32_bf16(af[r], bf[c], acc[r][c], 0, 0, 0);
  }

  if (OUTB) {
    // bf16 tile in LDS, then 8 coalesced passes of 16B stores
    #pragma unroll
    for (int c = 0; c < 4; ++c) {
      int nl = (wave >> 1)*64 + c*16 + l16;
      float bv = bias ? bias[bn0 + nl] : 0.f;
      #pragma unroll
      for (int r = 0; r < 4; ++r)
        #pragma unroll
        for (int reg = 0; reg < 4; ++reg) {
          int ml = (wave & 1)*64 + r*16 + quad*4 + reg;
          Cs[ml*136 + nl] = f2b(acc[r][c][reg] + bv);
        }
    }
    __syncthreads();
    #pragma unroll
    for (int p = 0; p < 8; ++p) {
      int row = p*16 + (tid >> 4);
      int col = (tid & 15)*8;
      uint4 v = *(const uint4*)&Cs[row*136 + col];
      *(uint4*)&((u16*)Cv)[(size_t)(bm0+row)*N + bn0 + col] = v;
    }
  } else {
    // fp32: two half-tiles through LDS (float[64][132])
    float* Cf = (float*)Cs;
    #pragma unroll
    for (int half = 0; half < 2; ++half) {
      if ((wave & 1) == half) {
        #pragma unroll
        for (int c = 0; c < 4; ++c) {
          int nl = (wave >> 1)*64 + c*16 + l16;
          float bv = bias ? bias[bn0 + nl] : 0.f;
          #pragma unroll
          for (int r = 0; r < 4; ++r)
            #pragma unroll
            for (int reg = 0; reg < 4; ++reg) {
              int ml = r*16 + quad*4 + reg;
              Cf[ml*132 + nl] = acc[r][c][reg] + bv;
            }
        }
      }
      __syncthreads();
      #pragma unroll
      for (int p = 0; p < 8; ++p) {
        int row = p*8 + (tid >> 5);
        int col = (tid & 31)*4;
        float4 v = *(const float4*)&Cf[row*132 + col];
        *(float4*)&((float*)Cv)[(size_t)(bm0 + half*64 + row)*N + bn0 + col] = v;
      }
      __syncthreads();
    }
  }
}

// ---------------- RMSNorm: one wave per token, writes bf16
__global__ __launch_bounds__(256) void rmsnorm_k(const float* __restrict__ X,
    const float* __restrict__ w, u16* __restrict__ XNb)
{
  int n = blockIdx.x*4 + (threadIdx.x >> 6);
  int lane = threadIdx.x & 63;
  const float4 x = *(const float4*)&X[(size_t)n*DMODEL + lane*4];
  float ss = x.x*x.x + x.y*x.y + x.z*x.z + x.w*x.w;
  #pragma unroll
  for (int m = 1; m < 64; m <<= 1) ss += __shfl_xor(ss, m);
  float r = rsqrtf(ss * (1.f/DMODEL) + 1e-5f);
  ushort4 o;
  o.x = f2b(x.x * r * w[lane*4+0]);
  o.y = f2b(x.y * r * w[lane*4+1]);
  o.z = f2b(x.z * r * w[lane*4+2]);
  o.w = f2b(x.w * r * w[lane*4+3]);
  *(ushort4*)&XNb[(size_t)n*DMODEL + lane*4] = o;
}

// ---------------- causal depthwise conv (K=4) + SiLU, bf16 in/out
__global__ __launch_bounds__(256) void conv_silu_k(const u16* __restrict__ XZb,
    const float* __restrict__ cw, const float* __restrict__ cb,
    u16* __restrict__ XPb)
{
  int g = blockIdx.x*256 + threadIdx.x;   // NTOK * 128 c4-groups
  int c4 = (g & 127) << 2;
  int n = g >> 7;
  int l = n >> 3;
  float w[4][4];
  #pragma unroll
  for (int i = 0; i < 4; ++i)
    #pragma unroll
    for (int k = 0; k < 4; ++k) w[i][k] = cw[(c4+i)*4 + k];
  float acc[4];
  #pragma unroll
  for (int i = 0; i < 4; ++i) acc[i] = cb[c4+i];
  #pragma unroll
  for (int k = 0; k < 4; ++k) {
    int lp = l - 3 + k;
    if (lp >= 0) {
      const ushort4 xv = *(const ushort4*)&XZb[(size_t)(n - BB*(3-k))*1024 + c4];
      acc[0] = fmaf(w[0][k], b2f(xv.x), acc[0]);
      acc[1] = fmaf(w[1][k], b2f(xv.y), acc[1]);
      acc[2] = fmaf(w[2][k], b2f(xv.z), acc[2]);
      acc[3] = fmaf(w[3][k], b2f(xv.w), acc[3]);
    }
  }
  ushort4 ob;
  ob.x = f2b(siluf(acc[0])); ob.y = f2b(siluf(acc[1]));
  ob.z = f2b(siluf(acc[2])); ob.w = f2b(siluf(acc[3]));
  *(ushort4*)&XPb[(size_t)n*DINNER + c4] = ob;
}

// ---------------- GEMM1 of x_dbl: B/C/dtr = XPb @ WxT^T (N=48, K=512)
__global__ __launch_bounds__(128) void xdblBC_k(const u16* __restrict__ XPb,
    const u16* __restrict__ WxT,
    float* __restrict__ BM, float* __restrict__ CM, u16* __restrict__ DTRb)
{
  const int tid = threadIdx.x;
  const int wave = tid >> 6, lane = tid & 63;
  const int quad = lane >> 4, l16 = lane & 15;
  const int tok0 = blockIdx.x*32 + wave*16;

  floatx4 acc[3];
  #pragma unroll
  for (int j = 0; j < 3; ++j) acc[j] = (floatx4){0.f,0.f,0.f,0.f};
  const u16* Ap = XPb + (size_t)(tok0 + l16)*DINNER + quad*8;
  const u16* Bp = WxT + (size_t)l16*DINNER + quad*8;
  #pragma unroll
  for (int k0 = 0; k0 < DINNER; k0 += 32) {
    bf16x8 af = *(const bf16x8*)(Ap + k0);
    #pragma unroll
    for (int j = 0; j < 3; ++j) {
      bf16x8 bf = *(const bf16x8*)(Bp + (size_t)j*16*DINNER + k0);
      acc[j] = __builtin_amdgcn_mfma_f32_16x16x32_bf16(af, bf, acc[j], 0, 0, 0);
    }
  }
  #pragma unroll
  for (int reg = 0; reg < 4; ++reg) {
    size_t t = (size_t)(tok0 + quad*4 + reg);
    BM[t*16 + l16] = acc[1][reg];
    CM[t*16 + l16] = acc[2][reg];
    DTRb[t*32 + l16]      = f2b(acc[0][reg]);
    DTRb[t*32 + 16 + l16] = 0;
  }
}

// ---------------- dt GEMM: DTb = softplus(DTRb @ WdtTp^T + b_dt), bf16 out
__global__ __launch_bounds__(256) void dtg_k(const u16* __restrict__ DTRb,
    const u16* __restrict__ WdtTp, const float* __restrict__ bdt,
    u16* __restrict__ DTb)
{
  __shared__ u16 Cs[128*136];
  const int tid = threadIdx.x;
  const int wave = tid >> 6, lane = tid & 63;
  const int quad = lane >> 4, l16 = lane & 15;
  const int bm0 = blockIdx.x*128, bn0 = blockIdx.y*128;
  const int bm = bm0 + (wave & 1)*64;
  const int bn = bn0 + (wave >> 1)*64;
  bf16x8 af[4], bf[4];
  #pragma unroll
  for (int r = 0; r < 4; ++r)
    af[r] = *(const bf16x8*)(DTRb + (size_t)(bm + r*16 + l16)*32 + quad*8);
  #pragma unroll
  for (int c = 0; c < 4; ++c)
    bf[c] = *(const bf16x8*)(WdtTp + (size_t)(bn + c*16 + l16)*32 + quad*8);
  #pragma unroll
  for (int c = 0; c < 4; ++c) {
    int nl = (wave >> 1)*64 + c*16 + l16;
    float bd = bdt[bn0 + nl];
    #pragma unroll
    for (int r = 0; r < 4; ++r) {
      floatx4 d = __builtin_amdgcn_mfma_f32_16x16x32_bf16(af[r], bf[c],
                    (floatx4){0.f,0.f,0.f,0.f}, 0, 0, 0);
      #pragma unroll
      for (int reg = 0; reg < 4; ++reg) {
        int ml = (wave & 1)*64 + r*16 + quad*4 + reg;
        float sum = d[reg] + bd;
        Cs[ml*136 + nl] = f2b((sum > 20.f) ? sum : __logf(1.f + __expf(sum)));
      }
    }
  }
  __syncthreads();
  #pragma unroll
  for (int p = 0; p < 8; ++p) {
    int row = p*16 + (tid >> 4);
    int col = (tid & 15)*8;
    uint4 v = *(const uint4*)&Cs[row*136 + col];
    *(uint4*)&DTb[(size_t)(bm0+row)*DINNER + bn0 + col] = v;
  }
}

// ---------------- scan phase A: per-segment h_end (h0=0, bf16 out) + sum(dt)
__global__ __launch_bounds__(256) void scanA_k(const u16* __restrict__ DTb,
    const u16* __restrict__ XPb, const float* __restrict__ BM,
    const float* __restrict__ Alog, u16* __restrict__ HENDb, float* __restrict__ DTS)
{
  __shared__ __align__(16) float Bs[SEGLEN*16];
  const int tid = threadIdx.x;
  const int seg = blockIdx.x, b = blockIdx.y, half = blockIdx.z;
  const int c = half*256 + tid;
  const int t0 = seg*SEGLEN;
  {
    int t = tid >> 4, s = tid & 15;
    Bs[tid] = BM[((size_t)(t0+t)*BB + b)*16 + s];
  }
  float As[16];
  #pragma unroll
  for (int s = 0; s < 16; ++s) As[s] = -__expf(Alog[c*16+s]);
  bool uni = true;
  #pragma unroll
  for (int s = 1; s < 16; ++s)
    uni = uni && (fabsf(As[s] - As[0]*(float)(s+1)) <= 1e-4f*(float)(s+1));
  float h[16];
  #pragma unroll
  for (int s = 0; s < 16; ++s) h[s] = 0.f;
  float dts = 0.f;
  __syncthreads();
  const size_t base = (size_t)t0*BB + b;
  const u16* dtp = DTb + base*DINNER + c;
  const u16* xpp = XPb + base*DINNER + c;
  float dt = b2f(dtp[0]);
  float xp = b2f(xpp[0]);
  for (int t = 0; t < SEGLEN; ++t) {
    float dtn = 0.f, xpn = 0.f;
    if (t+1 < SEGLEN) {
      dtn = b2f(dtp[(size_t)(t+1)*BB*DINNER]);
      xpn = b2f(xpp[(size_t)(t+1)*BB*DINNER]);
    }
    dts += dt;
    float dtx = dt * xp;
    const float4 b0 = *(const float4*)&Bs[t*16+0];
    const float4 b1 = *(const float4*)&Bs[t*16+4];
    const float4 b2 = *(const float4*)&Bs[t*16+8];
    const float4 b3 = *(const float4*)&Bs[t*16+12];
    const float bv[16] = {b0.x,b0.y,b0.z,b0.w, b1.x,b1.y,b1.z,b1.w,
                          b2.x,b2.y,b2.z,b2.w, b3.x,b3.y,b3.z,b3.w};
    float dA[16];
    if (uni) {
      float p = __expf(dt*As[0]);
      dA[0] = p;
      #pragma unroll
      for (int s = 1; s < 16; ++s) dA[s] = dA[s-1]*p;
    } else {
      #pragma unroll
      for (int s = 0; s < 16; ++s) dA[s] = __expf(dt*As[s]);
    }
    #pragma unroll
    for (int s = 0; s < 16; ++s)
      h[s] = fmaf(dA[s], h[s], dtx*bv[s]);
    dt = dtn; xp = xpn;
  }
  u16* hp = &HENDb[(((size_t)seg*BB + b)*DINNER + c)*16];
  #pragma unroll
  for (int q = 0; q < 2; ++q) {
    ushort8plug:;
    ushort4 v0, v1;
    v0.x = f2b(h[q*8+0]); v0.y = f2b(h[q*8+1]); v0.z = f2b(h[q*8+2]); v0.w = f2b(h[q*8+3]);
    v1.x = f2b(h[q*8+4]); v1.y = f2b(h[q*8+5]); v1.z = f2b(h[q*8+6]); v1.w = f2b(h[q*8+7]);
    *(ushort4*)&hp[q*8]     = v0;
    *(ushort4*)&hp[q*8 + 4] = v1;
  }
  DTS[((size_t)seg*BB + b)*DINNER + c] = dts;
}

// ---------------- stitch: sequential over NSEG segments, in-place HENDb -> h0
__global__ __launch_bounds__(256) void stitch_k(u16* __restrict__ HENDb,
    const float* __restrict__ DTS, const float* __restrict__ Alog)
{
  int g = blockIdx.x*256 + threadIdx.x;
  int b = g >> 13;
  int rem = g & 8191;          // c*16+s
  int cidx = rem >> 4;
  float A = -__expf(Alog[rem]);
  float h0 = 0.f;
  for (int k = 0; k < NSEG; ++k) {
    size_t idx = (((size_t)k*BB + b) << 13) + rem;
    float hend = b2f(HENDb[idx]);
    HENDb[idx] = f2b(h0);
    float dts = DTS[((size_t)k*BB + b)*DINNER + cidx];
    h0 = fmaf(__expf(dts*A), h0, hend);
  }
}

// ---------------- scan phase C: full scan with h0 (bf16), fused gate + bf16 out
__global__ __launch_bounds__(256) void scanC_k(const u16* __restrict__ DTb,
    const u16* __restrict__ XPb, const float* __restrict__ BM, const float* __restrict__ CM,
    const u16* __restrict__ XZb, const float* __restrict__ Alog, const float* __restrict__ Dp,
    const u16* __restrict__ H0b, u16* __restrict__ YGb)
{
  __shared__ __align__(16) float Bs[SEGLEN*16];
  __shared__ __align__(16) float Cs[SEGLEN*16];
  const int tid = threadIdx.x;
  const int seg = blockIdx.x, b = blockIdx.y, half = blockIdx.z;
  const int c = half*256 + tid;
  const int t0 = seg*SEGLEN;
  {
    int t = tid >> 4, s = tid & 15;
    size_t nb = ((size_t)(t0+t)*BB + b)*16 + s;
    Bs[tid] = BM[nb];
    Cs[tid] = CM[nb];
  }
  float As[16];
  #pragma unroll
  for (int s = 0; s < 16; ++s) As[s] = -__expf(Alog[c*16+s]);
  bool uni = true;
  #pragma unroll
  for (int s = 1; s < 16; ++s)
    uni = uni && (fabsf(As[s] - As[0]*(float)(s+1)) <= 1e-4f*(float)(s+1));
  float h[16];
  const u16* hp = &H0b[(((size_t)seg*BB + b)*DINNER + c)*16];
  #pragma unroll
  for (int q = 0; q < 4; ++q) {
    ushort4 hv = *(const ushort4*)&hp[q*4];
    h[q*4+0]=b2f(hv.x); h[q*4+1]=b2f(hv.y); h[q*4+2]=b2f(hv.z); h[q*4+3]=b2f(hv.w);
  }
  const float Dv = Dp[c];
  __syncthreads();
  const size_t base = (size_t)t0*BB + b;
  const u16* dtp = DTb + base*DINNER + c;
  const u16* xpp = XPb + base*DINNER + c;
  const u16* zp  = XZb + base*1024 + DINNER + c;
  u16*       ygp = YGb + base*DINNER + c;
  float dt = b2f(dtp[0]);
  float xp = b2f(xpp[0]);
  float zg = b2f(zp[0]);
  for (int t = 0; t < SEGLEN; ++t) {
    float dtn = 0.f, xpn = 0.f, zgn = 0.f;
    if (t+1 < SEGLEN) {
      dtn = b2f(dtp[(size_t)(t+1)*BB*DINNER]);
      xpn = b2f(xpp[(size_t)(t+1)*BB*DINNER]);
      zgn = b2f(zp[(size_t)(t+1)*BB*1024]);
    }
    float dtx = dt * xp;
    const float4 b0 = *(const float4*)&Bs[t*16+0];
    const float4 b1 = *(const float4*)&Bs[t*16+4];
    const float4 b2 = *(const float4*)&Bs[t*16+8];
    const float4 b3 = *(const float4*)&Bs[t*16+12];
    const float4 c0 = *(const float4*)&Cs[t*16+0];
    const float4 c1 = *(const float4*)&Cs[t*16+4];
    const float4 c2 = *(const float4*)&Cs[t*16+8];
    const float4 c3 = *(const float4*)&Cs[t*16+12];
    const float bv[16] = {b0.x,b0.y,b0.z,b0.w, b1.x,b1.y,b1.z,b1.w,
                          b2.x,b2.y,b2.z,b2.w, b3.x,b3.y,b3.z,b3.w};
    const float cv[16] = {c0.x,c0.y,c0.z,c0.w, c1.x,c1.y,c1.z,c1.w,
                          c2.x,c2.y,c2.z,c2.w, c3.x,c3.y,c3.z,c3.w};
    float dA[16];
    if (uni) {
      float p = __expf(dt*As[0]);
      dA[0] = p;
      #pragma unroll
      for (int s = 1; s < 16; ++s) dA[s] = dA[s-1]*p;
    } else {
      #pragma unroll
      for (int s = 0; s < 16; ++s) dA[s] = __expf(dt*As[s]);
    }
    float y0 = 0.f, y1 = 0.f, y2 = 0.f, y3 = 0.f;
    #pragma unroll
    for (int q = 0; q < 4; ++q) {
      h[q*4+0] = fmaf(dA[q*4+0], h[q*4+0], dtx*bv[q*4+0]);
      h[q*4+1] = fmaf(dA[q*4+1], h[q*4+1], dtx*bv[q*4+1]);
      h[q*4+2] = fmaf(dA[q*4+2], h[q*4+2], dtx*bv[q*4+2]);
      h[q*4+3] = fmaf(dA[q*4+3], h[q*4+3], dtx*bv[q*4+3]);
      y0 = fmaf(h[q*4+0], cv[q*4+0], y0);
      y1 = fmaf(h[q*4+1], cv[q*4+1], y1);
      y2 = fmaf(h[q*4+2], cv[q*4+2], y2);
      y3 = fmaf(h[q*4+3], cv[q*4+3], y3);
    }
    float y = (y0+y1) + (y2+y3);
    ygp[(size_t)t*BB*DINNER] = f2b((y + xp*Dv) * siluf(zg));
    dt = dtn; xp = xpn; zg = zgn;
  }
}

// ---------------- fused out-proj + residual + action head + Normal log-prob
__global__ __launch_bounds__(256) void outhead_k(const u16* __restrict__ YGb,
    const u16* __restrict__ WTo, const float* __restrict__ Xres,
    const u16* __restrict__ WhT, const float* __restrict__ bh,
    const float* __restrict__ lstd, const float* __restrict__ a,
    float* __restrict__ out)
{
  __shared__ u16 Xs[64*264];
  const int tid = threadIdx.x;
  const int wave = tid >> 6, lane = tid & 63;
  const int quad = lane >> 4, l16 = lane & 15;
  const int m0 = blockIdx.x*64;
  const int n0 = wave*64;
  floatx4 acc[4][4];
  #pragma unroll
  for (int r = 0; r < 4; ++r)
    #pragma unroll
    for (int c = 0; c < 4; ++c) acc[r][c] = (floatx4){0.f,0.f,0.f,0.f};
  const u16* Ap = YGb + (size_t)(m0 + l16)*DINNER + quad*8;
  const u16* Bp = WTo + (size_t)(n0 + l16)*DINNER + quad*8;
  #pragma unroll 2
  for (int k0 = 0; k0 < DINNER; k0 += 32) {
    bf16x8 af[4], bf[4];
    #pragma unroll
    for (int r = 0; r < 4; ++r) af[r] = *(const bf16x8*)(Ap + (size_t)r*16*DINNER + k0);
    #pragma unroll
    for (int c = 0; c < 4; ++c) bf[c] = *(const bf16x8*)(Bp + (size_t)c*16*DINNER + k0);
    #pragma unroll
    for (int r = 0; r < 4; ++r)
      #pragma unroll
      for (int c = 0; c < 4; ++c)
        acc[r][c] = __builtin_amdgcn_mfma_f32_16x16x32_bf16(af[r], bf[c], acc[r][c], 0, 0, 0);
  }
  #pragma unroll
  for (int c = 0; c < 4; ++c) {
    int n = n0 + c*16 + l16;
    #pragma unroll
    for (int r = 0; r < 4; ++r) {
      #pragma unroll
      for (int reg = 0; reg < 4; ++reg) {
        int ml = r*16 + quad*4 + reg;
        float t = acc[r][c][reg] + Xres[(size_t)(m0 + ml)*DMODEL + n];
        Xs[ml*264 + n] = f2b(t);
      }
    }
  }
  __syncthreads();
  floatx4 mu[2];
  mu[0] = (floatx4){0.f,0.f,0.f,0.f};
  mu[1] = (floatx4){0.f,0.f,0.f,0.f};
  #pragma unroll
  for (int k0 = 0; k0 < DMODEL; k0 += 32) {
    bf16x8 axf = *(const bf16x8*)&Xs[(wave*16 + l16)*264 + k0 + quad*8];
    #pragma unroll
    for (int nt = 0; nt < 2; ++nt) {
      bf16x8 bwf = *(const bf16x8*)(WhT + (size_t)(nt*16 + l16)*DMODEL + k0 + quad*8);
      mu[nt] = __builtin_amdgcn_mfma_f32_16x16x32_bf16(axf, bwf, mu[nt], 0, 0, 0);
    }
  }
  float ls0 = lstd[l16],      els0 = __expf(-ls0), bh0 = bh[l16];
  float ls1 = lstd[16 + l16], els1 = __expf(-ls1), bh1 = bh[16 + l16];
  #pragma unroll
  for (int reg = 0; reg < 4; ++reg) {
    int tok = m0 + wave*16 + quad*4 + reg;
    float m0v = mu[0][reg] + bh0;
    float m1v = mu[1][reg] + bh1;
    float z0 = (a[(size_t)tok*32 + l16]      - m0v) * els0;
    float z1 = (a[(size_t)tok*32 + 16 + l16] - m1v) * els1;
    float t = (-0.5f*z0*z0 - ls0) + (-0.5f*z1*z1 - ls1) - 2.f*0.91893853320467274f;
    t += __shfl_xor(t, 1);
    t += __shfl_xor(t, 2);
    t += __shfl_xor(t, 4);
    t += __shfl_xor(t, 8);
    if (l16 == 0) out[tok] = t;
  }
}

extern "C" void kernel_launch(void* const* d_in, const int* in_sizes, int n_in,
                              void* d_out, int out_size, void* d_ws, size_t ws_size,
                              hipStream_t stream)
{
  const float* s    = (const float*)d_in[0];
  const float* a    = (const float*)d_in[1];
  const float* Wemb = (const float*)d_in[2];
  const float* bemb = (const float*)d_in[3];
  const float* nw   = (const float*)d_in[4];
  const float* Win  = (const float*)d_in[5];
  const float* cw   = (const float*)d_in[6];
  const float* cb   = (const float*)d_in[7];
  const float* Wx   = (const float*)d_in[8];
  const float* Wdt  = (const float*)d_in[9];
  const float* bdt  = (const float*)d_in[10];
  const float* Alog = (const float*)d_in[11];
  const float* Dp   = (const float*)d_in[12];
  const float* Wout = (const float*)d_in[13];
  const float* Wh   = (const float*)d_in[14];
  const float* bh   = (const float*)d_in[15];
  const float* lstd = (const float*)d_in[16];

  // -------- workspace layout
  float* X    = (float*)d_ws;                       // NTOK*256 fp32 (emb resid)
  u16*   XZb  = (u16*)(X + (size_t)NTOK*DMODEL);    // NTOK*1024 bf16 [xp|z]
  u16*   XPb  = XZb + (size_t)NTOK*1024;            // NTOK*512 bf16
  u16*   DTb  = XPb + (size_t)NTOK*DINNER;          // NTOK*512 bf16
  u16*   YGb  = DTb + (size_t)NTOK*DINNER;          // NTOK*512 bf16
  u16*   sb   = YGb + (size_t)NTOK*DINNER;          // NTOK*128 bf16
  u16*   XNb  = sb  + (size_t)NTOK*128;             // NTOK*256 bf16
  u16*   WTe  = XNb + (size_t)NTOK*DMODEL;          // 256*128
  u16*   WTi  = WTe + 256*128;                      // 1024*256
  u16*   WTo  = WTi + 1024*256;                     // 256*512
  u16*   WxT  = WTo + 256*512;                      // 48*512
  u16*   WdtTp= WxT + 48*512;                       // 512*32
  u16*   WhT  = WdtTp + 512*32;                     // 32*256
  u16*   DTRb = WhT + 32*256;                       // NTOK*32
  u16*   HENDb= DTRb + (size_t)NTOK*32;             // NSEG*8*512*16 bf16
  float* BM   = (float*)(HENDb + (size_t)NSEG*BB*DINNER*16); // NTOK*16 fp32
  float* CM   = BM + (size_t)NTOK*16;               // NTOK*16 fp32
  float* DTS  = CM + (size_t)NTOK*16;               // NSEG*8*512 fp32
  float* out  = (float*)d_out;

  prep_k          <<<3904,        256, 0, stream>>>(s, Wemb, Win, Wout, Wx, Wdt, Wh,
                                                    sb, WTe, WTi, WTo, WxT, WdtTp, WhT);
  gemm_mfma<128,0><<<dim3(128,2), 256, 0, stream>>>(sb,  WTe, bemb,   X,   DMODEL);
  rmsnorm_k       <<<4096,        256, 0, stream>>>(X, nw, XNb);
  gemm_mfma<256,1><<<dim3(128,8), 256, 0, stream>>>(XNb, WTi, nullptr, XZb, 1024);
  conv_silu_k     <<<8192,        256, 0, stream>>>(XZb, cw, cb, XPb);
  xdblBC_k        <<<512,         128, 0, stream>>>(XPb, WxT, BM, CM, DTRb);
  dtg_k           <<<dim3(128,4), 256, 0, stream>>>(DTRb, WdtTp, bdt, DTb);
  scanA_k         <<<dim3(NSEG,BB,2), 256, 0, stream>>>(DTb, XPb, BM, Alog, HENDb, DTS);
  stitch_k        <<<256,         256, 0, stream>>>(HENDb, DTS, Alog);
  scanC_k         <<<dim3(NSEG,BB,2), 256, 0, stream>>>(DTb, XPb, BM, CM, XZb, Alog, Dp, HENDb, YGb);
  outhead_k       <<<256,         256, 0, stream>>>(YGb, WTo, X, WhT, bh, lstd, a, out);
}

// Round 12
// 252.357 us; speedup vs baseline: 3.3854x; 1.0992x over previous
//
#include <hip/hip_runtime.h>

typedef unsigned short u16;
typedef short bf16x8 __attribute__((ext_vector_type(8)));   // 8 bf16 = 4 VGPR
typedef float floatx4 __attribute__((ext_vector_type(4)));

#define LSEQ 2048
#define BB 8
#define NTOK (LSEQ*BB)        // 16384 tokens, n = l*B + b
#define DMODEL 256
#define DINNER 512
#define NSEG 128
#define SEGLEN 16             // LSEQ / NSEG

__device__ __forceinline__ float siluf(float x){ return x / (1.f + __expf(-x)); }
__device__ __forceinline__ float b2f(u16 x){ return __uint_as_float(((unsigned)x) << 16); }
__device__ __forceinline__ u16 f2b(float f){
  unsigned u = __float_as_uint(f);
  unsigned r = (u + 0x7fffu + ((u >> 16) & 1u)) >> 16;
  return (u16)r;
}

// ---------------- fused prep: s cast + 6 weight transpose/casts, range-switched
__global__ __launch_bounds__(256) void prep_k(
    const float* __restrict__ s, const float* __restrict__ Wemb,
    const float* __restrict__ Win, const float* __restrict__ Wout,
    const float* __restrict__ Wx, const float* __restrict__ Wdt,
    const float* __restrict__ Wh,
    u16* __restrict__ sb, u16* __restrict__ WTe, u16* __restrict__ WTi,
    u16* __restrict__ WTo, u16* __restrict__ WxT, u16* __restrict__ WdtTp,
    u16* __restrict__ WhT)
{
  int g = blockIdx.x, tid = threadIdx.x;
  if (g < 2048) {                       // s -> bf16, vectorized
    int i = (g*256 + tid)*4;
    float4 v = *(const float4*)&s[i];
    ushort4 o; o.x=f2b(v.x); o.y=f2b(v.y); o.z=f2b(v.z); o.w=f2b(v.w);
    *(ushort4*)&sb[i] = o;
  } else if (g < 2176) {                // WTe[n][k], n<256, k<128
    int idx = (g-2048)*256 + tid; int n = idx >> 7, k = idx & 127;
    WTe[idx] = f2b(Wemb[(size_t)k*256 + n]);
  } else if (g < 3200) {                // WTi[n][k], n<1024, k<256
    int idx = (g-2176)*256 + tid; int n = idx >> 8, k = idx & 255;
    WTi[idx] = f2b(Win[(size_t)k*1024 + n]);
  } else if (g < 3712) {                // WTo[n][k], n<256, k<512
    int idx = (g-3200)*256 + tid; int n = idx >> 9, k = idx & 511;
    WTo[idx] = f2b(Wout[(size_t)k*256 + n]);
  } else if (g < 3808) {                // WxT[48][512]
    int idx = (g-3712)*256 + tid; int n = idx >> 9, k = idx & 511;
    WxT[idx] = f2b(Wx[(size_t)k*48 + n]);
  } else if (g < 3872) {                // WdtTp[512][32], rows>=16 zero
    int idx = (g-3808)*256 + tid; int c = idx >> 5, r = idx & 31;
    WdtTp[idx] = (r < 16) ? f2b(Wdt[(size_t)r*512 + c]) : (u16)0;
  } else {                              // WhT[32][256]
    int idx = (g-3872)*256 + tid; int j = idx >> 8, k = idx & 255;
    WhT[idx] = f2b(Wh[(size_t)k*32 + j]);
  }
}

// ---------------- LDS-staged bf16 MFMA GEMM: C = A @ W (WT[N][K]) [+bias]
// Per 32-K step: coalesced 16B/lane staging of A/B tiles, ds_read_b128 frags.
// Row stride 40 u16 (80B, 16B-aligned). Epilogue LDS-staged coalesced stores.
template<int K, int OUTB>
__global__ __launch_bounds__(256) void gemm_mfma(
    const u16* __restrict__ Ab, const u16* __restrict__ WT,
    const float* __restrict__ bias, void* __restrict__ Cv, int N)
{
  __shared__ u16 SH[128*136];           // 34816 B; staging + epilogue reuse
  u16* As = SH;                         // [128][40]
  u16* Bs = SH + 128*40;                // [128][40]
  const int tid = threadIdx.x;
  const int wave = tid >> 6, lane = tid & 63;
  const int quad = lane >> 4, l16 = lane & 15;
  const int bm0 = blockIdx.x*128, bn0 = blockIdx.y*128;
  const int wm = (wave & 1)*64, wn = (wave >> 1)*64;
  const int srow = tid >> 2, sch = (tid & 3)*8;
  floatx4 acc[4][4];
  #pragma unroll
  for (int r = 0; r < 4; ++r)
    #pragma unroll
    for (int c = 0; c < 4; ++c) acc[r][c] = (floatx4){0.f,0.f,0.f,0.f};

  for (int k0 = 0; k0 < K; k0 += 32) {
    #pragma unroll
    for (int p = 0; p < 2; ++p) {
      int row = srow + p*64;
      *(uint4*)&As[row*40 + sch] = *(const uint4*)&Ab[(size_t)(bm0+row)*K + k0 + sch];
      *(uint4*)&Bs[row*40 + sch] = *(const uint4*)&WT[(size_t)(bn0+row)*K + k0 + sch];
    }
    __syncthreads();
    bf16x8 af[4], bf[4];
    #pragma unroll
    for (int r = 0; r < 4; ++r) af[r] = *(const bf16x8*)&As[(wm + r*16 + l16)*40 + quad*8];
    #pragma unroll
    for (int c = 0; c < 4; ++c) bf[c] = *(const bf16x8*)&Bs[(wn + c*16 + l16)*40 + quad*8];
    #pragma unroll
    for (int r = 0; r < 4; ++r)
      #pragma unroll
      for (int c = 0; c < 4; ++c)
        acc[r][c] = __builtin_amdgcn_mfma_f32_16x16x32_bf16(af[r], bf[c], acc[r][c], 0, 0, 0);
    __syncthreads();
  }

  if (OUTB) {
    u16* Cs = SH;                       // [128][136]
    #pragma unroll
    for (int c = 0; c < 4; ++c) {
      int nl = wn + c*16 + l16;
      float bv = bias ? bias[bn0 + nl] : 0.f;
      #pragma unroll
      for (int r = 0; r < 4; ++r)
        #pragma unroll
        for (int reg = 0; reg < 4; ++reg) {
          int ml = wm + r*16 + quad*4 + reg;
          Cs[ml*136 + nl] = f2b(acc[r][c][reg] + bv);
        }
    }
    __syncthreads();
    #pragma unroll
    for (int p = 0; p < 8; ++p) {
      int row = p*16 + (tid >> 4);
      int col = (tid & 15)*8;
      uint4 v = *(const uint4*)&Cs[row*136 + col];
      *(uint4*)&((u16*)Cv)[(size_t)(bm0+row)*N + bn0 + col] = v;
    }
  } else {
    float* Cf = (float*)SH;             // [64][132]
    #pragma unroll
    for (int half = 0; half < 2; ++half) {
      if ((wave & 1) == half) {
        #pragma unroll
        for (int c = 0; c < 4; ++c) {
          int nl = wn + c*16 + l16;
          float bv = bias ? bias[bn0 + nl] : 0.f;
          #pragma unroll
          for (int r = 0; r < 4; ++r)
            #pragma unroll
            for (int reg = 0; reg < 4; ++reg) {
              int ml = r*16 + quad*4 + reg;
              Cf[ml*132 + nl] = acc[r][c][reg] + bv;
            }
        }
      }
      __syncthreads();
      #pragma unroll
      for (int p = 0; p < 8; ++p) {
        int row = p*8 + (tid >> 5);
        int col = (tid & 31)*4;
        float4 v = *(const float4*)&Cf[row*132 + col];
        *(float4*)&((float*)Cv)[(size_t)(bm0 + half*64 + row)*N + bn0 + col] = v;
      }
      __syncthreads();
    }
  }
}

// ---------------- RMSNorm: one wave per token, writes bf16
__global__ __launch_bounds__(256) void rmsnorm_k(const float* __restrict__ X,
    const float* __restrict__ w, u16* __restrict__ XNb)
{
  int n = blockIdx.x*4 + (threadIdx.x >> 6);
  int lane = threadIdx.x & 63;
  const float4 x = *(const float4*)&X[(size_t)n*DMODEL + lane*4];
  float ss = x.x*x.x + x.y*x.y + x.z*x.z + x.w*x.w;
  #pragma unroll
  for (int m = 1; m < 64; m <<= 1) ss += __shfl_xor(ss, m);
  float r = rsqrtf(ss * (1.f/DMODEL) + 1e-5f);
  ushort4 o;
  o.x = f2b(x.x * r * w[lane*4+0]);
  o.y = f2b(x.y * r * w[lane*4+1]);
  o.z = f2b(x.z * r * w[lane*4+2]);
  o.w = f2b(x.w * r * w[lane*4+3]);
  *(ushort4*)&XNb[(size_t)n*DMODEL + lane*4] = o;
}

// ---------------- causal depthwise conv (K=4) + SiLU, bf16 in/out
__global__ __launch_bounds__(256) void conv_silu_k(const u16* __restrict__ XZb,
    const float* __restrict__ cw, const float* __restrict__ cb,
    u16* __restrict__ XPb)
{
  int g = blockIdx.x*256 + threadIdx.x;   // NTOK * 128 c4-groups
  int c4 = (g & 127) << 2;
  int n = g >> 7;
  int l = n >> 3;
  float w[4][4];
  #pragma unroll
  for (int i = 0; i < 4; ++i)
    #pragma unroll
    for (int k = 0; k < 4; ++k) w[i][k] = cw[(c4+i)*4 + k];
  float acc[4];
  #pragma unroll
  for (int i = 0; i < 4; ++i) acc[i] = cb[c4+i];
  #pragma unroll
  for (int k = 0; k < 4; ++k) {
    int lp = l - 3 + k;
    if (lp >= 0) {
      const ushort4 xv = *(const ushort4*)&XZb[(size_t)(n - BB*(3-k))*1024 + c4];
      acc[0] = fmaf(w[0][k], b2f(xv.x), acc[0]);
      acc[1] = fmaf(w[1][k], b2f(xv.y), acc[1]);
      acc[2] = fmaf(w[2][k], b2f(xv.z), acc[2]);
      acc[3] = fmaf(w[3][k], b2f(xv.w), acc[3]);
    }
  }
  ushort4 ob;
  ob.x = f2b(siluf(acc[0])); ob.y = f2b(siluf(acc[1]));
  ob.z = f2b(siluf(acc[2])); ob.w = f2b(siluf(acc[3]));
  *(ushort4*)&XPb[(size_t)n*DINNER + c4] = ob;
}

// ---------------- GEMM1 of x_dbl: B/C/dtr = XPb @ WxT^T (N=48, K=512)
__global__ __launch_bounds__(128) void xdblBC_k(const u16* __restrict__ XPb,
    const u16* __restrict__ WxT,
    float* __restrict__ BM, float* __restrict__ CM, u16* __restrict__ DTRb)
{
  const int tid = threadIdx.x;
  const int wave = tid >> 6, lane = tid & 63;
  const int quad = lane >> 4, l16 = lane & 15;
  const int tok0 = blockIdx.x*32 + wave*16;

  floatx4 acc[3];
  #pragma unroll
  for (int j = 0; j < 3; ++j) acc[j] = (floatx4){0.f,0.f,0.f,0.f};
  const u16* Ap = XPb + (size_t)(tok0 + l16)*DINNER + quad*8;
  const u16* Bp = WxT + (size_t)l16*DINNER + quad*8;
  #pragma unroll
  for (int k0 = 0; k0 < DINNER; k0 += 32) {
    bf16x8 af = *(const bf16x8*)(Ap + k0);
    #pragma unroll
    for (int j = 0; j < 3; ++j) {
      bf16x8 bf = *(const bf16x8*)(Bp + (size_t)j*16*DINNER + k0);
      acc[j] = __builtin_amdgcn_mfma_f32_16x16x32_bf16(af, bf, acc[j], 0, 0, 0);
    }
  }
  #pragma unroll
  for (int reg = 0; reg < 4; ++reg) {
    size_t t = (size_t)(tok0 + quad*4 + reg);
    BM[t*16 + l16] = acc[1][reg];
    CM[t*16 + l16] = acc[2][reg];
    DTRb[t*32 + l16]      = f2b(acc[0][reg]);
    DTRb[t*32 + 16 + l16] = 0;
  }
}

// ---------------- dt GEMM: DTb = softplus(DTRb @ WdtTp^T + b_dt), bf16 out
__global__ __launch_bounds__(256) void dtg_k(const u16* __restrict__ DTRb,
    const u16* __restrict__ WdtTp, const float* __restrict__ bdt,
    u16* __restrict__ DTb)
{
  __shared__ u16 Cs[128*136];
  const int tid = threadIdx.x;
  const int wave = tid >> 6, lane = tid & 63;
  const int quad = lane >> 4, l16 = lane & 15;
  const int bm0 = blockIdx.x*128, bn0 = blockIdx.y*128;
  const int bm = bm0 + (wave & 1)*64;
  const int bn = bn0 + (wave >> 1)*64;
  bf16x8 af[4], bf[4];
  #pragma unroll
  for (int r = 0; r < 4; ++r)
    af[r] = *(const bf16x8*)(DTRb + (size_t)(bm + r*16 + l16)*32 + quad*8);
  #pragma unroll
  for (int c = 0; c < 4; ++c)
    bf[c] = *(const bf16x8*)(WdtTp + (size_t)(bn + c*16 + l16)*32 + quad*8);
  #pragma unroll
  for (int c = 0; c < 4; ++c) {
    int nl = (wave >> 1)*64 + c*16 + l16;
    float bd = bdt[bn0 + nl];
    #pragma unroll
    for (int r = 0; r < 4; ++r) {
      floatx4 d = __builtin_amdgcn_mfma_f32_16x16x32_bf16(af[r], bf[c],
                    (floatx4){0.f,0.f,0.f,0.f}, 0, 0, 0);
      #pragma unroll
      for (int reg = 0; reg < 4; ++reg) {
        int ml = (wave & 1)*64 + r*16 + quad*4 + reg;
        float sum = d[reg] + bd;
        Cs[ml*136 + nl] = f2b((sum > 20.f) ? sum : __logf(1.f + __expf(sum)));
      }
    }
  }
  __syncthreads();
  #pragma unroll
  for (int p = 0; p < 8; ++p) {
    int row = p*16 + (tid >> 4);
    int col = (tid & 15)*8;
    uint4 v = *(const uint4*)&Cs[row*136 + col];
    *(uint4*)&DTb[(size_t)(bm0+row)*DINNER + bn0 + col] = v;
  }
}

// ---------------- scan phase A: per-segment h_end (h0=0, bf16 out) + sum(dt)
__global__ __launch_bounds__(256) void scanA_k(const u16* __restrict__ DTb,
    const u16* __restrict__ XPb, const float* __restrict__ BM,
    const float* __restrict__ Alog, u16* __restrict__ HENDb, float* __restrict__ DTS)
{
  __shared__ __align__(16) float Bs[SEGLEN*16];
  const int tid = threadIdx.x;
  const int seg = blockIdx.x, b = blockIdx.y, half = blockIdx.z;
  const int c = half*256 + tid;
  const int t0 = seg*SEGLEN;
  {
    int t = tid >> 4, s = tid & 15;
    Bs[tid] = BM[((size_t)(t0+t)*BB + b)*16 + s];
  }
  float As[16];
  #pragma unroll
  for (int s = 0; s < 16; ++s) As[s] = -__expf(Alog[c*16+s]);
  bool uni = true;
  #pragma unroll
  for (int s = 1; s < 16; ++s)
    uni = uni && (fabsf(As[s] - As[0]*(float)(s+1)) <= 1e-4f*(float)(s+1));
  float h[16];
  #pragma unroll
  for (int s = 0; s < 16; ++s) h[s] = 0.f;
  float dts = 0.f;
  __syncthreads();
  const size_t base = (size_t)t0*BB + b;
  const u16* dtp = DTb + base*DINNER + c;
  const u16* xpp = XPb + base*DINNER + c;
  float dt = b2f(dtp[0]);
  float xp = b2f(xpp[0]);
  for (int t = 0; t < SEGLEN; ++t) {
    float dtn = 0.f, xpn = 0.f;
    if (t+1 < SEGLEN) {
      dtn = b2f(dtp[(size_t)(t+1)*BB*DINNER]);
      xpn = b2f(xpp[(size_t)(t+1)*BB*DINNER]);
    }
    dts += dt;
    float dtx = dt * xp;
    const float4 b0 = *(const float4*)&Bs[t*16+0];
    const float4 b1 = *(const float4*)&Bs[t*16+4];
    const float4 b2 = *(const float4*)&Bs[t*16+8];
    const float4 b3 = *(const float4*)&Bs[t*16+12];
    const float bv[16] = {b0.x,b0.y,b0.z,b0.w, b1.x,b1.y,b1.z,b1.w,
                          b2.x,b2.y,b2.z,b2.w, b3.x,b3.y,b3.z,b3.w};
    float dA[16];
    if (uni) {
      float p = __expf(dt*As[0]);
      dA[0] = p;
      #pragma unroll
      for (int s = 1; s < 16; ++s) dA[s] = dA[s-1]*p;
    } else {
      #pragma unroll
      for (int s = 0; s < 16; ++s) dA[s] = __expf(dt*As[s]);
    }
    #pragma unroll
    for (int s = 0; s < 16; ++s)
      h[s] = fmaf(dA[s], h[s], dtx*bv[s]);
    dt = dtn; xp = xpn;
  }
  u16* hp = &HENDb[(((size_t)seg*BB + b)*DINNER + c)*16];
  #pragma unroll
  for (int q = 0; q < 2; ++q) {
    ushort4 v0, v1;
    v0.x = f2b(h[q*8+0]); v0.y = f2b(h[q*8+1]); v0.z = f2b(h[q*8+2]); v0.w = f2b(h[q*8+3]);
    v1.x = f2b(h[q*8+4]); v1.y = f2b(h[q*8+5]); v1.z = f2b(h[q*8+6]); v1.w = f2b(h[q*8+7]);
    *(ushort4*)&hp[q*8]     = v0;
    *(ushort4*)&hp[q*8 + 4] = v1;
  }
  DTS[((size_t)seg*BB + b)*DINNER + c] = dts;
}

// ---------------- stitch: sequential over NSEG segments, in-place HENDb -> h0
__global__ __launch_bounds__(256) void stitch_k(u16* __restrict__ HENDb,
    const float* __restrict__ DTS, const float* __restrict__ Alog)
{
  int g = blockIdx.x*256 + threadIdx.x;
  int b = g >> 13;
  int rem = g & 8191;          // c*16+s
  int cidx = rem >> 4;
  float A = -__expf(Alog[rem]);
  float h0 = 0.f;
  for (int k = 0; k < NSEG; ++k) {
    size_t idx = (((size_t)k*BB + b) << 13) + rem;
    float hend = b2f(HENDb[idx]);
    HENDb[idx] = f2b(h0);
    float dts = DTS[((size_t)k*BB + b)*DINNER + cidx];
    h0 = fmaf(__expf(dts*A), h0, hend);
  }
}

// ---------------- scan phase C: full scan with h0 (bf16), fused gate + bf16 out
__global__ __launch_bounds__(256) void scanC_k(const u16* __restrict__ DTb,
    const u16* __restrict__ XPb, const float* __restrict__ BM, const float* __restrict__ CM,
    const u16* __restrict__ XZb, const float* __restrict__ Alog, const float* __restrict__ Dp,
    const u16* __restrict__ H0b, u16* __restrict__ YGb)
{
  __shared__ __align__(16) float Bs[SEGLEN*16];
  __shared__ __align__(16) float Cs[SEGLEN*16];
  const int tid = threadIdx.x;
  const int seg = blockIdx.x, b = blockIdx.y, half = blockIdx.z;
  const int c = half*256 + tid;
  const int t0 = seg*SEGLEN;
  {
    int t = tid >> 4, s = tid & 15;
    size_t nb = ((size_t)(t0+t)*BB + b)*16 + s;
    Bs[tid] = BM[nb];
    Cs[tid] = CM[nb];
  }
  float As[16];
  #pragma unroll
  for (int s = 0; s < 16; ++s) As[s] = -__expf(Alog[c*16+s]);
  bool uni = true;
  #pragma unroll
  for (int s = 1; s < 16; ++s)
    uni = uni && (fabsf(As[s] - As[0]*(float)(s+1)) <= 1e-4f*(float)(s+1));
  float h[16];
  const u16* hp = &H0b[(((size_t)seg*BB + b)*DINNER + c)*16];
  #pragma unroll
  for (int q = 0; q < 4; ++q) {
    ushort4 hv = *(const ushort4*)&hp[q*4];
    h[q*4+0]=b2f(hv.x); h[q*4+1]=b2f(hv.y); h[q*4+2]=b2f(hv.z); h[q*4+3]=b2f(hv.w);
  }
  const float Dv = Dp[c];
  __syncthreads();
  const size_t base = (size_t)t0*BB + b;
  const u16* dtp = DTb + base*DINNER + c;
  const u16* xpp = XPb + base*DINNER + c;
  const u16* zp  = XZb + base*1024 + DINNER + c;
  u16*       ygp = YGb + base*DINNER + c;
  float dt = b2f(dtp[0]);
  float xp = b2f(xpp[0]);
  float zg = b2f(zp[0]);
  for (int t = 0; t < SEGLEN; ++t) {
    float dtn = 0.f, xpn = 0.f, zgn = 0.f;
    if (t+1 < SEGLEN) {
      dtn = b2f(dtp[(size_t)(t+1)*BB*DINNER]);
      xpn = b2f(xpp[(size_t)(t+1)*BB*DINNER]);
      zgn = b2f(zp[(size_t)(t+1)*BB*1024]);
    }
    float dtx = dt * xp;
    const float4 b0 = *(const float4*)&Bs[t*16+0];
    const float4 b1 = *(const float4*)&Bs[t*16+4];
    const float4 b2 = *(const float4*)&Bs[t*16+8];
    const float4 b3 = *(const float4*)&Bs[t*16+12];
    const float4 c0 = *(const float4*)&Cs[t*16+0];
    const float4 c1 = *(const float4*)&Cs[t*16+4];
    const float4 c2 = *(const float4*)&Cs[t*16+8];
    const float4 c3 = *(const float4*)&Cs[t*16+12];
    const float bv[16] = {b0.x,b0.y,b0.z,b0.w, b1.x,b1.y,b1.z,b1.w,
                          b2.x,b2.y,b2.z,b2.w, b3.x,b3.y,b3.z,b3.w};
    const float cv[16] = {c0.x,c0.y,c0.z,c0.w, c1.x,c1.y,c1.z,c1.w,
                          c2.x,c2.y,c2.z,c2.w, c3.x,c3.y,c3.z,c3.w};
    float dA[16];
    if (uni) {
      float p = __expf(dt*As[0]);
      dA[0] = p;
      #pragma unroll
      for (int s = 1; s < 16; ++s) dA[s] = dA[s-1]*p;
    } else {
      #pragma unroll
      for (int s = 0; s < 16; ++s) dA[s] = __expf(dt*As[s]);
    }
    float y0 = 0.f, y1 = 0.f, y2 = 0.f, y3 = 0.f;
    #pragma unroll
    for (int q = 0; q < 4; ++q) {
      h[q*4+0] = fmaf(dA[q*4+0], h[q*4+0], dtx*bv[q*4+0]);
      h[q*4+1] = fmaf(dA[q*4+1], h[q*4+1], dtx*bv[q*4+1]);
      h[q*4+2] = fmaf(dA[q*4+2], h[q*4+2], dtx*bv[q*4+2]);
      h[q*4+3] = fmaf(dA[q*4+3], h[q*4+3], dtx*bv[q*4+3]);
      y0 = fmaf(h[q*4+0], cv[q*4+0], y0);
      y1 = fmaf(h[q*4+1], cv[q*4+1], y1);
      y2 = fmaf(h[q*4+2], cv[q*4+2], y2);
      y3 = fmaf(h[q*4+3], cv[q*4+3], y3);
    }
    float y = (y0+y1) + (y2+y3);
    ygp[(size_t)t*BB*DINNER] = f2b((y + xp*Dv) * siluf(zg));
    dt = dtn; xp = xpn; zg = zgn;
  }
}

// ---------------- fused out-proj + residual + action head + Normal log-prob.
// LDS-staged: A tile (64 tok x 32k) + full WTo B tile (256 x 32k) per K-step.
__global__ __launch_bounds__(256) void outhead_k(const u16* __restrict__ YGb,
    const u16* __restrict__ WTo, const float* __restrict__ Xres,
    const u16* __restrict__ WhT, const float* __restrict__ bh,
    const float* __restrict__ lstd, const float* __restrict__ a,
    float* __restrict__ out)
{
  __shared__ u16 Xs[64*264];            // 33792 B; staging + epilogue reuse
  u16* As = Xs;                         // [64][40]
  u16* Bs = Xs + 64*40;                 // [256][40]
  const int tid = threadIdx.x;
  const int wave = tid >> 6, lane = tid & 63;
  const int quad = lane >> 4, l16 = lane & 15;
  const int m0 = blockIdx.x*64;
  const int n0 = wave*64;
  const int srow = tid >> 2, sch = (tid & 3)*8;
  floatx4 acc[4][4];
  #pragma unroll
  for (int r = 0; r < 4; ++r)
    #pragma unroll
    for (int c = 0; c < 4; ++c) acc[r][c] = (floatx4){0.f,0.f,0.f,0.f};

  for (int k0 = 0; k0 < DINNER; k0 += 32) {
    if (srow < 64)
      *(uint4*)&As[srow*40 + sch] = *(const uint4*)&YGb[(size_t)(m0+srow)*DINNER + k0 + sch];
    #pragma unroll
    for (int p = 0; p < 4; ++p) {
      int row = srow + p*64;
      *(uint4*)&Bs[row*40 + sch] = *(const uint4*)&WTo[(size_t)row*DINNER + k0 + sch];
    }
    __syncthreads();
    bf16x8 af[4], bf[4];
    #pragma unroll
    for (int r = 0; r < 4; ++r) af[r] = *(const bf16x8*)&As[(r*16 + l16)*40 + quad*8];
    #pragma unroll
    for (int c = 0; c < 4; ++c) bf[c] = *(const bf16x8*)&Bs[(n0 + c*16 + l16)*40 + quad*8];
    #pragma unroll
    for (int r = 0; r < 4; ++r)
      #pragma unroll
      for (int c = 0; c < 4; ++c)
        acc[r][c] = __builtin_amdgcn_mfma_f32_16x16x32_bf16(af[r], bf[c], acc[r][c], 0, 0, 0);
    __syncthreads();
  }
  // resid add -> Xs bf16 [64][264]
  #pragma unroll
  for (int c = 0; c < 4; ++c) {
    int n = n0 + c*16 + l16;
    #pragma unroll
    for (int r = 0; r < 4; ++r) {
      #pragma unroll
      for (int reg = 0; reg < 4; ++reg) {
        int ml = r*16 + quad*4 + reg;
        float t = acc[r][c][reg] + Xres[(size_t)(m0 + ml)*DMODEL + n];
        Xs[ml*264 + n] = f2b(t);
      }
    }
  }
  __syncthreads();
  floatx4 mu[2];
  mu[0] = (floatx4){0.f,0.f,0.f,0.f};
  mu[1] = (floatx4){0.f,0.f,0.f,0.f};
  #pragma unroll
  for (int k0 = 0; k0 < DMODEL; k0 += 32) {
    bf16x8 axf = *(const bf16x8*)&Xs[(wave*16 + l16)*264 + k0 + quad*8];
    #pragma unroll
    for (int nt = 0; nt < 2; ++nt) {
      bf16x8 bwf = *(const bf16x8*)(WhT + (size_t)(nt*16 + l16)*DMODEL + k0 + quad*8);
      mu[nt] = __builtin_amdgcn_mfma_f32_16x16x32_bf16(axf, bwf, mu[nt], 0, 0, 0);
    }
  }
  float ls0 = lstd[l16],      els0 = __expf(-ls0), bh0 = bh[l16];
  float ls1 = lstd[16 + l16], els1 = __expf(-ls1), bh1 = bh[16 + l16];
  #pragma unroll
  for (int reg = 0; reg < 4; ++reg) {
    int tok = m0 + wave*16 + quad*4 + reg;
    float m0v = mu[0][reg] + bh0;
    float m1v = mu[1][reg] + bh1;
    float z0 = (a[(size_t)tok*32 + l16]      - m0v) * els0;
    float z1 = (a[(size_t)tok*32 + 16 + l16] - m1v) * els1;
    float t = (-0.5f*z0*z0 - ls0) + (-0.5f*z1*z1 - ls1) - 2.f*0.91893853320467274f;
    t += __shfl_xor(t, 1);
    t += __shfl_xor(t, 2);
    t += __shfl_xor(t, 4);
    t += __shfl_xor(t, 8);
    if (l16 == 0) out[tok] = t;
  }
}

extern "C" void kernel_launch(void* const* d_in, const int* in_sizes, int n_in,
                              void* d_out, int out_size, void* d_ws, size_t ws_size,
                              hipStream_t stream)
{
  const float* s    = (const float*)d_in[0];
  const float* a    = (const float*)d_in[1];
  const float* Wemb = (const float*)d_in[2];
  const float* bemb = (const float*)d_in[3];
  const float* nw   = (const float*)d_in[4];
  const float* Win  = (const float*)d_in[5];
  const float* cw   = (const float*)d_in[6];
  const float* cb   = (const float*)d_in[7];
  const float* Wx   = (const float*)d_in[8];
  const float* Wdt  = (const float*)d_in[9];
  const float* bdt  = (const float*)d_in[10];
  const float* Alog = (const float*)d_in[11];
  const float* Dp   = (const float*)d_in[12];
  const float* Wout = (const float*)d_in[13];
  const float* Wh   = (const float*)d_in[14];
  const float* bh   = (const float*)d_in[15];
  const float* lstd = (const float*)d_in[16];

  // -------- workspace layout
  float* X    = (float*)d_ws;                       // NTOK*256 fp32 (emb resid)
  u16*   XZb  = (u16*)(X + (size_t)NTOK*DMODEL);    // NTOK*1024 bf16 [xp|z]
  u16*   XPb  = XZb + (size_t)NTOK*1024;            // NTOK*512 bf16
  u16*   DTb  = XPb + (size_t)NTOK*DINNER;          // NTOK*512 bf16
  u16*   YGb  = DTb + (size_t)NTOK*DINNER;          // NTOK*512 bf16
  u16*   sb   = YGb + (size_t)NTOK*DINNER;          // NTOK*128 bf16
  u16*   XNb  = sb  + (size_t)NTOK*128;             // NTOK*256 bf16
  u16*   WTe  = XNb + (size_t)NTOK*DMODEL;          // 256*128
  u16*   WTi  = WTe + 256*128;                      // 1024*256
  u16*   WTo  = WTi + 1024*256;                     // 256*512
  u16*   WxT  = WTo + 256*512;                      // 48*512
  u16*   WdtTp= WxT + 48*512;                       // 512*32
  u16*   WhT  = WdtTp + 512*32;                     // 32*256
  u16*   DTRb = WhT + 32*256;                       // NTOK*32
  u16*   HENDb= DTRb + (size_t)NTOK*32;             // NSEG*8*512*16 bf16
  float* BM   = (float*)(HENDb + (size_t)NSEG*BB*DINNER*16); // NTOK*16 fp32
  float* CM   = BM + (size_t)NTOK*16;               // NTOK*16 fp32
  float* DTS  = CM + (size_t)NTOK*16;               // NSEG*8*512 fp32
  float* out  = (float*)d_out;

  prep_k          <<<3904,        256, 0, stream>>>(s, Wemb, Win, Wout, Wx, Wdt, Wh,
                                                    sb, WTe, WTi, WTo, WxT, WdtTp, WhT);
  gemm_mfma<128,0><<<dim3(128,2), 256, 0, stream>>>(sb,  WTe, bemb,   X,   DMODEL);
  rmsnorm_k       <<<4096,        256, 0, stream>>>(X, nw, XNb);
  gemm_mfma<256,1><<<dim3(128,8), 256, 0, stream>>>(XNb, WTi, nullptr, XZb, 1024);
  conv_silu_k     <<<8192,        256, 0, stream>>>(XZb, cw, cb, XPb);
  xdblBC_k        <<<512,         128, 0, stream>>>(XPb, WxT, BM, CM, DTRb);
  dtg_k           <<<dim3(128,4), 256, 0, stream>>>(DTRb, WdtTp, bdt, DTb);
  scanA_k         <<<dim3(NSEG,BB,2), 256, 0, stream>>>(DTb, XPb, BM, Alog, HENDb, DTS);
  stitch_k        <<<256,         256, 0, stream>>>(HENDb, DTS, Alog);
  scanC_k         <<<dim3(NSEG,BB,2), 256, 0, stream>>>(DTb, XPb, BM, CM, XZb, Alog, Dp, HENDb, YGb);
  outhead_k       <<<256,         256, 0, stream>>>(YGb, WTo, X, WhT, bh, lstd, a, out);
}

// Round 13
// 247.784 us; speedup vs baseline: 3.4479x; 1.0185x over previous
//
#include <hip/hip_runtime.h>

typedef unsigned short u16;
typedef short bf16x8 __attribute__((ext_vector_type(8)));   // 8 bf16 = 4 VGPR
typedef float floatx4 __attribute__((ext_vector_type(4)));

#define LSEQ 2048
#define BB 8
#define NTOK (LSEQ*BB)        // 16384 tokens, n = l*B + b
#define DMODEL 256
#define DINNER 512
#define NSEG 128
#define SEGLEN 16             // LSEQ / NSEG

__device__ __forceinline__ float siluf(float x){ return x / (1.f + __expf(-x)); }
__device__ __forceinline__ float b2f(u16 x){ return __uint_as_float(((unsigned)x) << 16); }
__device__ __forceinline__ u16 f2b(float f){
  unsigned u = __float_as_uint(f);
  unsigned r = (u + 0x7fffu + ((u >> 16) & 1u)) >> 16;
  return (u16)r;
}

// ---------------- prep: 6 weight transpose/casts, range-switched
// blocks: [0,128) WTe | [128,1152) WTi | [1152,1664) WTo | [1664,1760) WxT
//         [1760,1824) WdtTp | [1824,1856) WhT
__global__ __launch_bounds__(256) void prep_k(
    const float* __restrict__ Wemb, const float* __restrict__ Win,
    const float* __restrict__ Wout, const float* __restrict__ Wx,
    const float* __restrict__ Wdt, const float* __restrict__ Wh,
    u16* __restrict__ WTe, u16* __restrict__ WTi, u16* __restrict__ WTo,
    u16* __restrict__ WxT, u16* __restrict__ WdtTp, u16* __restrict__ WhT)
{
  int g = blockIdx.x, tid = threadIdx.x;
  if (g < 128) {                        // WTe[n][k], n<256, k<128
    int idx = g*256 + tid; int n = idx >> 7, k = idx & 127;
    WTe[idx] = f2b(Wemb[(size_t)k*256 + n]);
  } else if (g < 1152) {                // WTi[n][k], n<1024, k<256
    int idx = (g-128)*256 + tid; int n = idx >> 8, k = idx & 255;
    WTi[idx] = f2b(Win[(size_t)k*1024 + n]);
  } else if (g < 1664) {                // WTo[n][k], n<256, k<512
    int idx = (g-1152)*256 + tid; int n = idx >> 9, k = idx & 511;
    WTo[idx] = f2b(Wout[(size_t)k*256 + n]);
  } else if (g < 1760) {                // WxT[48][512]
    int idx = (g-1664)*256 + tid; int n = idx >> 9, k = idx & 511;
    WxT[idx] = f2b(Wx[(size_t)k*48 + n]);
  } else if (g < 1824) {                // WdtTp[512][32], rows>=16 zero
    int idx = (g-1760)*256 + tid; int c = idx >> 5, r = idx & 31;
    WdtTp[idx] = (r < 16) ? f2b(Wdt[(size_t)r*512 + c]) : (u16)0;
  } else {                              // WhT[32][256]
    int idx = (g-1824)*256 + tid; int j = idx >> 8, k = idx & 255;
    WhT[idx] = f2b(Wh[(size_t)k*32 + j]);
  }
}

// ---------------- fused emb GEMM + RMSNorm: block = 64 tokens x full N=256.
// Emits bf16 resid Xb and normalized XNb. A staged from fp32 s with cast.
__global__ __launch_bounds__(256) void embnorm_k(
    const float* __restrict__ s, const u16* __restrict__ WTe,
    const float* __restrict__ bemb, const float* __restrict__ nw,
    u16* __restrict__ Xb, u16* __restrict__ XNb)
{
  __shared__ u16 SH[64*264];            // staging As[64][40]+Bs[256][40]; epilogue Xs[64][264]
  __shared__ float ssq[64*4];
  __shared__ float rr[64];
  u16* As = SH;
  u16* Bs = SH + 64*40;
  const int tid = threadIdx.x;
  const int wave = tid >> 6, lane = tid & 63;
  const int quad = lane >> 4, l16 = lane & 15;
  const int m0 = blockIdx.x*64;
  const int wn = wave*64;
  const int srow = tid >> 2, sch = (tid & 3)*8;
  floatx4 acc[4][4];
  #pragma unroll
  for (int r = 0; r < 4; ++r)
    #pragma unroll
    for (int c = 0; c < 4; ++c) acc[r][c] = (floatx4){0.f,0.f,0.f,0.f};

  for (int k0 = 0; k0 < 128; k0 += 32) {
    {
      float4 v0 = *(const float4*)&s[(size_t)(m0+srow)*128 + k0 + sch];
      float4 v1 = *(const float4*)&s[(size_t)(m0+srow)*128 + k0 + sch + 4];
      __align__(16) u16 o[8];
      o[0]=f2b(v0.x); o[1]=f2b(v0.y); o[2]=f2b(v0.z); o[3]=f2b(v0.w);
      o[4]=f2b(v1.x); o[5]=f2b(v1.y); o[6]=f2b(v1.z); o[7]=f2b(v1.w);
      *(uint4*)&As[srow*40 + sch] = *(const uint4*)o;
    }
    #pragma unroll
    for (int p = 0; p < 4; ++p) {
      int row = srow + p*64;
      *(uint4*)&Bs[row*40 + sch] = *(const uint4*)&WTe[(size_t)row*128 + k0 + sch];
    }
    __syncthreads();
    bf16x8 af[4], bf[4];
    #pragma unroll
    for (int r = 0; r < 4; ++r) af[r] = *(const bf16x8*)&As[(r*16 + l16)*40 + quad*8];
    #pragma unroll
    for (int c = 0; c < 4; ++c) bf[c] = *(const bf16x8*)&Bs[(wn + c*16 + l16)*40 + quad*8];
    #pragma unroll
    for (int r = 0; r < 4; ++r)
      #pragma unroll
      for (int c = 0; c < 4; ++c)
        acc[r][c] = __builtin_amdgcn_mfma_f32_16x16x32_bf16(af[r], bf[c], acc[r][c], 0, 0, 0);
    __syncthreads();
  }
  u16* Xs = SH;                         // [64][264]
  #pragma unroll
  for (int c = 0; c < 4; ++c) {
    int n = wn + c*16 + l16;
    float bv = bemb[n];
    #pragma unroll
    for (int r = 0; r < 4; ++r)
      #pragma unroll
      for (int reg = 0; reg < 4; ++reg) {
        int ml = r*16 + quad*4 + reg;
        Xs[ml*264 + n] = f2b(acc[r][c][reg] + bv);
      }
  }
  __syncthreads();
  // coalesced Xb write
  #pragma unroll
  for (int p = 0; p < 8; ++p) {
    int row = p*8 + (tid >> 5);
    int col = (tid & 31)*8;
    *(uint4*)&Xb[(size_t)(m0+row)*256 + col] = *(const uint4*)&Xs[row*264 + col];
  }
  // rmsnorm: 4 threads per token
  const int tk = tid >> 2, q = tid & 3;
  float ss = 0.f;
  #pragma unroll
  for (int j = 0; j < 8; ++j) {
    uint4 v = *(const uint4*)&Xs[tk*264 + q*64 + j*8];
    const u16* u = (const u16*)&v;
    #pragma unroll
    for (int i = 0; i < 8; ++i) { float x = b2f(u[i]); ss += x*x; }
  }
  ssq[tk*4 + q] = ss;
  __syncthreads();
  if (q == 0)
    rr[tk] = rsqrtf((ssq[tk*4]+ssq[tk*4+1]+ssq[tk*4+2]+ssq[tk*4+3])*(1.f/DMODEL) + 1e-5f);
  __syncthreads();
  float r = rr[tk];
  #pragma unroll
  for (int j = 0; j < 8; ++j) {
    int idx = q*64 + j*8;
    uint4 v = *(const uint4*)&Xs[tk*264 + idx];
    const u16* u = (const u16*)&v;
    float4 w0 = *(const float4*)&nw[idx];
    float4 w1 = *(const float4*)&nw[idx+4];
    __align__(16) u16 o[8];
    o[0]=f2b(b2f(u[0])*r*w0.x); o[1]=f2b(b2f(u[1])*r*w0.y);
    o[2]=f2b(b2f(u[2])*r*w0.z); o[3]=f2b(b2f(u[3])*r*w0.w);
    o[4]=f2b(b2f(u[4])*r*w1.x); o[5]=f2b(b2f(u[5])*r*w1.y);
    o[6]=f2b(b2f(u[6])*r*w1.z); o[7]=f2b(b2f(u[7])*r*w1.w);
    *(uint4*)&XNb[(size_t)(m0+tk)*256 + idx] = *(const uint4*)o;
  }
}

// ---------------- LDS-staged bf16 MFMA GEMM (in-proj): C = A @ W, bf16 out
template<int K>
__global__ __launch_bounds__(256) void gemm_mfma(
    const u16* __restrict__ Ab, const u16* __restrict__ WT,
    u16* __restrict__ Cv, int N)
{
  __shared__ u16 SH[128*136];
  u16* As = SH;
  u16* Bs = SH + 128*40;
  const int tid = threadIdx.x;
  const int wave = tid >> 6, lane = tid & 63;
  const int quad = lane >> 4, l16 = lane & 15;
  const int bm0 = blockIdx.x*128, bn0 = blockIdx.y*128;
  const int wm = (wave & 1)*64, wn = (wave >> 1)*64;
  const int srow = tid >> 2, sch = (tid & 3)*8;
  floatx4 acc[4][4];
  #pragma unroll
  for (int r = 0; r < 4; ++r)
    #pragma unroll
    for (int c = 0; c < 4; ++c) acc[r][c] = (floatx4){0.f,0.f,0.f,0.f};

  for (int k0 = 0; k0 < K; k0 += 32) {
    #pragma unroll
    for (int p = 0; p < 2; ++p) {
      int row = srow + p*64;
      *(uint4*)&As[row*40 + sch] = *(const uint4*)&Ab[(size_t)(bm0+row)*K + k0 + sch];
      *(uint4*)&Bs[row*40 + sch] = *(const uint4*)&WT[(size_t)(bn0+row)*K + k0 + sch];
    }
    __syncthreads();
    bf16x8 af[4], bf[4];
    #pragma unroll
    for (int r = 0; r < 4; ++r) af[r] = *(const bf16x8*)&As[(wm + r*16 + l16)*40 + quad*8];
    #pragma unroll
    for (int c = 0; c < 4; ++c) bf[c] = *(const bf16x8*)&Bs[(wn + c*16 + l16)*40 + quad*8];
    #pragma unroll
    for (int r = 0; r < 4; ++r)
      #pragma unroll
      for (int c = 0; c < 4; ++c)
        acc[r][c] = __builtin_amdgcn_mfma_f32_16x16x32_bf16(af[r], bf[c], acc[r][c], 0, 0, 0);
    __syncthreads();
  }
  u16* Cs = SH;                         // [128][136]
  #pragma unroll
  for (int c = 0; c < 4; ++c) {
    int nl = wn + c*16 + l16;
    #pragma unroll
    for (int r = 0; r < 4; ++r)
      #pragma unroll
      for (int reg = 0; reg < 4; ++reg) {
        int ml = wm + r*16 + quad*4 + reg;
        Cs[ml*136 + nl] = f2b(acc[r][c][reg]);
      }
  }
  __syncthreads();
  #pragma unroll
  for (int p = 0; p < 8; ++p) {
    int row = p*16 + (tid >> 4);
    int col = (tid & 15)*8;
    uint4 v = *(const uint4*)&Cs[row*136 + col];
    *(uint4*)&Cv[(size_t)(bm0+row)*N + bn0 + col] = v;
  }
}

// ---------------- x_dbl GEMM1 with fused causal conv+SiLU in the staging phase.
// Block = 64 tokens; conv taps read from XZb (xp half), weights preloaded in LDS.
__global__ __launch_bounds__(256) void xdblBC_k(const u16* __restrict__ XZb,
    const float* __restrict__ cw, const float* __restrict__ cb,
    const u16* __restrict__ WxT,
    float* __restrict__ BM, float* __restrict__ CM, u16* __restrict__ DTRb)
{
  __shared__ u16 As[64*40];
  __shared__ u16 Ws[48*40];
  __shared__ float CWs[512*4];
  __shared__ float CBs[512];
  const int tid = threadIdx.x;
  const int wave = tid >> 6, lane = tid & 63;
  const int quad = lane >> 4, l16 = lane & 15;
  const int m0 = blockIdx.x*64;
  const int srow = tid >> 2, sch = (tid & 3)*8;
  const int n = m0 + srow;
  for (int e = tid; e < 2048; e += 256) CWs[e] = cw[e];
  for (int e = tid; e < 512;  e += 256) CBs[e] = cb[e];
  floatx4 acc[3];
  #pragma unroll
  for (int j = 0; j < 3; ++j) acc[j] = (floatx4){0.f,0.f,0.f,0.f};
  __syncthreads();
  const bf16x8 z8 = {0,0,0,0,0,0,0,0};
  for (int k0 = 0; k0 < DINNER; k0 += 32) {
    bf16x8 t3 = *(const bf16x8*)&XZb[(size_t)n*1024 + k0 + sch];
    bf16x8 t2 = z8, t1 = z8, t0v = z8;
    if (n >= 8)  t2  = *(const bf16x8*)&XZb[(size_t)(n-8)*1024  + k0 + sch];
    if (n >= 16) t1  = *(const bf16x8*)&XZb[(size_t)(n-16)*1024 + k0 + sch];
    if (n >= 24) t0v = *(const bf16x8*)&XZb[(size_t)(n-24)*1024 + k0 + sch];
    __align__(16) u16 outa[8];
    #pragma unroll
    for (int j = 0; j < 8; ++j) {
      int c = k0 + sch + j;
      float4 wv = *(const float4*)&CWs[c*4];
      float xc = CBs[c] + wv.x*b2f((u16)t0v[j]) + wv.y*b2f((u16)t1[j])
               + wv.z*b2f((u16)t2[j]) + wv.w*b2f((u16)t3[j]);
      outa[j] = f2b(siluf(xc));
    }
    *(uint4*)&As[srow*40 + sch] = *(const uint4*)outa;
    if (tid < 192) {
      int wr = tid >> 2;
      *(uint4*)&Ws[wr*40 + sch] = *(const uint4*)&WxT[(size_t)wr*512 + k0 + sch];
    }
    __syncthreads();
    bf16x8 af = *(const bf16x8*)&As[(wave*16 + l16)*40 + quad*8];
    #pragma unroll
    for (int j = 0; j < 3; ++j) {
      bf16x8 bf = *(const bf16x8*)&Ws[(j*16 + l16)*40 + quad*8];
      acc[j] = __builtin_amdgcn_mfma_f32_16x16x32_bf16(af, bf, acc[j], 0, 0, 0);
    }
    __syncthreads();
  }
  const int tok0 = m0 + wave*16;
  #pragma unroll
  for (int reg = 0; reg < 4; ++reg) {
    size_t t = (size_t)(tok0 + quad*4 + reg);
    BM[t*16 + l16] = acc[1][reg];
    CM[t*16 + l16] = acc[2][reg];
    DTRb[t*32 + l16]      = f2b(acc[0][reg]);
    DTRb[t*32 + 16 + l16] = 0;
  }
}

// ---------------- dt GEMM: DTb = softplus(DTRb @ WdtTp^T + b_dt), bf16 out
__global__ __launch_bounds__(256) void dtg_k(const u16* __restrict__ DTRb,
    const u16* __restrict__ WdtTp, const float* __restrict__ bdt,
    u16* __restrict__ DTb)
{
  __shared__ u16 Cs[128*136];
  const int tid = threadIdx.x;
  const int wave = tid >> 6, lane = tid & 63;
  const int quad = lane >> 4, l16 = lane & 15;
  const int bm0 = blockIdx.x*128, bn0 = blockIdx.y*128;
  const int bm = bm0 + (wave & 1)*64;
  const int bn = bn0 + (wave >> 1)*64;
  bf16x8 af[4], bf[4];
  #pragma unroll
  for (int r = 0; r < 4; ++r)
    af[r] = *(const bf16x8*)(DTRb + (size_t)(bm + r*16 + l16)*32 + quad*8);
  #pragma unroll
  for (int c = 0; c < 4; ++c)
    bf[c] = *(const bf16x8*)(WdtTp + (size_t)(bn + c*16 + l16)*32 + quad*8);
  #pragma unroll
  for (int c = 0; c < 4; ++c) {
    int nl = (wave >> 1)*64 + c*16 + l16;
    float bd = bdt[bn0 + nl];
    #pragma unroll
    for (int r = 0; r < 4; ++r) {
      floatx4 d = __builtin_amdgcn_mfma_f32_16x16x32_bf16(af[r], bf[c],
                    (floatx4){0.f,0.f,0.f,0.f}, 0, 0, 0);
      #pragma unroll
      for (int reg = 0; reg < 4; ++reg) {
        int ml = (wave & 1)*64 + r*16 + quad*4 + reg;
        float sum = d[reg] + bd;
        Cs[ml*136 + nl] = f2b((sum > 20.f) ? sum : __logf(1.f + __expf(sum)));
      }
    }
  }
  __syncthreads();
  #pragma unroll
  for (int p = 0; p < 8; ++p) {
    int row = p*16 + (tid >> 4);
    int col = (tid & 15)*8;
    uint4 v = *(const uint4*)&Cs[row*136 + col];
    *(uint4*)&DTb[(size_t)(bm0+row)*DINNER + bn0 + col] = v;
  }
}

// ---------------- scan phase A: rolling-window conv + per-segment h_end + sum(dt)
__global__ __launch_bounds__(256) void scanA_k(const u16* __restrict__ DTb,
    const u16* __restrict__ XZb, const float* __restrict__ BM,
    const float* __restrict__ cw, const float* __restrict__ cb,
    const float* __restrict__ Alog, u16* __restrict__ HENDb, float* __restrict__ DTS)
{
  __shared__ __align__(16) float Bs[SEGLEN*16];
  const int tid = threadIdx.x;
  const int seg = blockIdx.x, b = blockIdx.y, half = blockIdx.z;
  const int c = half*256 + tid;
  const int t0 = seg*SEGLEN;
  {
    int t = tid >> 4, s = tid & 15;
    Bs[tid] = BM[((size_t)(t0+t)*BB + b)*16 + s];
  }
  float As[16];
  #pragma unroll
  for (int s = 0; s < 16; ++s) As[s] = -__expf(Alog[c*16+s]);
  bool uni = true;
  #pragma unroll
  for (int s = 1; s < 16; ++s)
    uni = uni && (fabsf(As[s] - As[0]*(float)(s+1)) <= 1e-4f*(float)(s+1));
  const float4 cwv = *(const float4*)&cw[c*4];
  const float cbv = cb[c];
  float h[16];
  #pragma unroll
  for (int s = 0; s < 16; ++s) h[s] = 0.f;
  float dts = 0.f;
  __syncthreads();
  const size_t base = (size_t)t0*BB + b;
  const u16* dtp = DTb + base*DINNER + c;
  const u16* xzp = XZb + base*1024 + c;
  float w0 = (t0 >= 3) ? b2f(xzp[-(size_t)3*BB*1024]) : 0.f;
  float w1 = (t0 >= 2) ? b2f(xzp[-(size_t)2*BB*1024]) : 0.f;
  float w2 = (t0 >= 1) ? b2f(xzp[-(size_t)1*BB*1024]) : 0.f;
  float dt = b2f(dtp[0]);
  float xz = b2f(xzp[0]);
  for (int t = 0; t < SEGLEN; ++t) {
    float dtn = 0.f, xzn = 0.f;
    if (t+1 < SEGLEN) {
      dtn = b2f(dtp[(size_t)(t+1)*BB*DINNER]);
      xzn = b2f(xzp[(size_t)(t+1)*BB*1024]);
    }
    float xp = siluf(cbv + cwv.x*w0 + cwv.y*w1 + cwv.z*w2 + cwv.w*xz);
    w0 = w1; w1 = w2; w2 = xz;
    dts += dt;
    float dtx = dt * xp;
    const float4 b0 = *(const float4*)&Bs[t*16+0];
    const float4 b1 = *(const float4*)&Bs[t*16+4];
    const float4 b2 = *(const float4*)&Bs[t*16+8];
    const float4 b3 = *(const float4*)&Bs[t*16+12];
    const float bv[16] = {b0.x,b0.y,b0.z,b0.w, b1.x,b1.y,b1.z,b1.w,
                          b2.x,b2.y,b2.z,b2.w, b3.x,b3.y,b3.z,b3.w};
    float dA[16];
    if (uni) {
      float p = __expf(dt*As[0]);
      dA[0] = p;
      #pragma unroll
      for (int s = 1; s < 16; ++s) dA[s] = dA[s-1]*p;
    } else {
      #pragma unroll
      for (int s = 0; s < 16; ++s) dA[s] = __expf(dt*As[s]);
    }
    #pragma unroll
    for (int s = 0; s < 16; ++s)
      h[s] = fmaf(dA[s], h[s], dtx*bv[s]);
    dt = dtn; xz = xzn;
  }
  u16* hp = &HENDb[(((size_t)seg*BB + b)*DINNER + c)*16];
  #pragma unroll
  for (int q = 0; q < 2; ++q) {
    ushort4 v0, v1;
    v0.x = f2b(h[q*8+0]); v0.y = f2b(h[q*8+1]); v0.z = f2b(h[q*8+2]); v0.w = f2b(h[q*8+3]);
    v1.x = f2b(h[q*8+4]); v1.y = f2b(h[q*8+5]); v1.z = f2b(h[q*8+6]); v1.w = f2b(h[q*8+7]);
    *(ushort4*)&hp[q*8]     = v0;
    *(ushort4*)&hp[q*8 + 4] = v1;
  }
  DTS[((size_t)seg*BB + b)*DINNER + c] = dts;
}

// ---------------- stitch: sequential over NSEG segments, in-place HENDb -> h0
__global__ __launch_bounds__(256) void stitch_k(u16* __restrict__ HENDb,
    const float* __restrict__ DTS, const float* __restrict__ Alog)
{
  int g = blockIdx.x*256 + threadIdx.x;
  int b = g >> 13;
  int rem = g & 8191;          // c*16+s
  int cidx = rem >> 4;
  float A = -__expf(Alog[rem]);
  float h0 = 0.f;
  for (int k = 0; k < NSEG; ++k) {
    size_t idx = (((size_t)k*BB + b) << 13) + rem;
    float hend = b2f(HENDb[idx]);
    HENDb[idx] = f2b(h0);
    float dts = DTS[((size_t)k*BB + b)*DINNER + cidx];
    h0 = fmaf(__expf(dts*A), h0, hend);
  }
}

// ---------------- scan phase C: rolling conv + full scan with h0, gate, bf16 out
__global__ __launch_bounds__(256) void scanC_k(const u16* __restrict__ DTb,
    const u16* __restrict__ XZb, const float* __restrict__ BM, const float* __restrict__ CM,
    const float* __restrict__ cw, const float* __restrict__ cb,
    const float* __restrict__ Alog, const float* __restrict__ Dp,
    const u16* __restrict__ H0b, u16* __restrict__ YGb)
{
  __shared__ __align__(16) float Bs[SEGLEN*16];
  __shared__ __align__(16) float Cs[SEGLEN*16];
  const int tid = threadIdx.x;
  const int seg = blockIdx.x, b = blockIdx.y, half = blockIdx.z;
  const int c = half*256 + tid;
  const int t0 = seg*SEGLEN;
  {
    int t = tid >> 4, s = tid & 15;
    size_t nb = ((size_t)(t0+t)*BB + b)*16 + s;
    Bs[tid] = BM[nb];
    Cs[tid] = CM[nb];
  }
  float As[16];
  #pragma unroll
  for (int s = 0; s < 16; ++s) As[s] = -__expf(Alog[c*16+s]);
  bool uni = true;
  #pragma unroll
  for (int s = 1; s < 16; ++s)
    uni = uni && (fabsf(As[s] - As[0]*(float)(s+1)) <= 1e-4f*(float)(s+1));
  const float4 cwv = *(const float4*)&cw[c*4];
  const float cbv = cb[c];
  float h[16];
  const u16* hp = &H0b[(((size_t)seg*BB + b)*DINNER + c)*16];
  #pragma unroll
  for (int q = 0; q < 4; ++q) {
    ushort4 hv = *(const ushort4*)&hp[q*4];
    h[q*4+0]=b2f(hv.x); h[q*4+1]=b2f(hv.y); h[q*4+2]=b2f(hv.z); h[q*4+3]=b2f(hv.w);
  }
  const float Dv = Dp[c];
  __syncthreads();
  const size_t base = (size_t)t0*BB + b;
  const u16* dtp = DTb + base*DINNER + c;
  const u16* xzp = XZb + base*1024 + c;
  const u16* zp  = XZb + base*1024 + DINNER + c;
  u16*       ygp = YGb + base*DINNER + c;
  float w0 = (t0 >= 3) ? b2f(xzp[-(size_t)3*BB*1024]) : 0.f;
  float w1 = (t0 >= 2) ? b2f(xzp[-(size_t)2*BB*1024]) : 0.f;
  float w2 = (t0 >= 1) ? b2f(xzp[-(size_t)1*BB*1024]) : 0.f;
  float dt = b2f(dtp[0]);
  float xz = b2f(xzp[0]);
  float zg = b2f(zp[0]);
  for (int t = 0; t < SEGLEN; ++t) {
    float dtn = 0.f, xzn = 0.f, zgn = 0.f;
    if (t+1 < SEGLEN) {
      dtn = b2f(dtp[(size_t)(t+1)*BB*DINNER]);
      xzn = b2f(xzp[(size_t)(t+1)*BB*1024]);
      zgn = b2f(zp[(size_t)(t+1)*BB*1024]);
    }
    float xp = siluf(cbv + cwv.x*w0 + cwv.y*w1 + cwv.z*w2 + cwv.w*xz);
    w0 = w1; w1 = w2; w2 = xz;
    float dtx = dt * xp;
    const float4 b0 = *(const float4*)&Bs[t*16+0];
    const float4 b1 = *(const float4*)&Bs[t*16+4];
    const float4 b2 = *(const float4*)&Bs[t*16+8];
    const float4 b3 = *(const float4*)&Bs[t*16+12];
    const float4 c0 = *(const float4*)&Cs[t*16+0];
    const float4 c1 = *(const float4*)&Cs[t*16+4];
    const float4 c2 = *(const float4*)&Cs[t*16+8];
    const float4 c3 = *(const float4*)&Cs[t*16+12];
    const float bvv[16] = {b0.x,b0.y,b0.z,b0.w, b1.x,b1.y,b1.z,b1.w,
                           b2.x,b2.y,b2.z,b2.w, b3.x,b3.y,b3.z,b3.w};
    const float cvv[16] = {c0.x,c0.y,c0.z,c0.w, c1.x,c1.y,c1.z,c1.w,
                           c2.x,c2.y,c2.z,c2.w, c3.x,c3.y,c3.z,c3.w};
    float dA[16];
    if (uni) {
      float p = __expf(dt*As[0]);
      dA[0] = p;
      #pragma unroll
      for (int s = 1; s < 16; ++s) dA[s] = dA[s-1]*p;
    } else {
      #pragma unroll
      for (int s = 0; s < 16; ++s) dA[s] = __expf(dt*As[s]);
    }
    float y0 = 0.f, y1 = 0.f, y2 = 0.f, y3 = 0.f;
    #pragma unroll
    for (int q = 0; q < 4; ++q) {
      h[q*4+0] = fmaf(dA[q*4+0], h[q*4+0], dtx*bvv[q*4+0]);
      h[q*4+1] = fmaf(dA[q*4+1], h[q*4+1], dtx*bvv[q*4+1]);
      h[q*4+2] = fmaf(dA[q*4+2], h[q*4+2], dtx*bvv[q*4+2]);
      h[q*4+3] = fmaf(dA[q*4+3], h[q*4+3], dtx*bvv[q*4+3]);
      y0 = fmaf(h[q*4+0], cvv[q*4+0], y0);
      y1 = fmaf(h[q*4+1], cvv[q*4+1], y1);
      y2 = fmaf(h[q*4+2], cvv[q*4+2], y2);
      y3 = fmaf(h[q*4+3], cvv[q*4+3], y3);
    }
    float y = (y0+y1) + (y2+y3);
    ygp[(size_t)t*BB*DINNER] = f2b((y + xp*Dv) * siluf(zg));
    dt = dtn; xz = xzn; zg = zgn;
  }
}

// ---------------- fused out-proj + residual (bf16 Xb) + action head + log-prob
__global__ __launch_bounds__(256) void outhead_k(const u16* __restrict__ YGb,
    const u16* __restrict__ WTo, const u16* __restrict__ Xb,
    const u16* __restrict__ WhT, const float* __restrict__ bh,
    const float* __restrict__ lstd, const float* __restrict__ a,
    float* __restrict__ out)
{
  __shared__ u16 Xs[64*264];            // staging As[64][40]+Bs[256][40]; epilogue [64][264]
  u16* As = Xs;
  u16* Bs = Xs + 64*40;
  const int tid = threadIdx.x;
  const int wave = tid >> 6, lane = tid & 63;
  const int quad = lane >> 4, l16 = lane & 15;
  const int m0 = blockIdx.x*64;
  const int n0 = wave*64;
  const int srow = tid >> 2, sch = (tid & 3)*8;
  floatx4 acc[4][4];
  #pragma unroll
  for (int r = 0; r < 4; ++r)
    #pragma unroll
    for (int c = 0; c < 4; ++c) acc[r][c] = (floatx4){0.f,0.f,0.f,0.f};

  for (int k0 = 0; k0 < DINNER; k0 += 32) {
    if (srow < 64)
      *(uint4*)&As[srow*40 + sch] = *(const uint4*)&YGb[(size_t)(m0+srow)*DINNER + k0 + sch];
    #pragma unroll
    for (int p = 0; p < 4; ++p) {
      int row = srow + p*64;
      *(uint4*)&Bs[row*40 + sch] = *(const uint4*)&WTo[(size_t)row*DINNER + k0 + sch];
    }
    __syncthreads();
    bf16x8 af[4], bf[4];
    #pragma unroll
    for (int r = 0; r < 4; ++r) af[r] = *(const bf16x8*)&As[(r*16 + l16)*40 + quad*8];
    #pragma unroll
    for (int c = 0; c < 4; ++c) bf[c] = *(const bf16x8*)&Bs[(n0 + c*16 + l16)*40 + quad*8];
    #pragma unroll
    for (int r = 0; r < 4; ++r)
      #pragma unroll
      for (int c = 0; c < 4; ++c)
        acc[r][c] = __builtin_amdgcn_mfma_f32_16x16x32_bf16(af[r], bf[c], acc[r][c], 0, 0, 0);
    __syncthreads();
  }
  // stage Xb resid tile coalesced, then add acc in LDS
  #pragma unroll
  for (int p = 0; p < 8; ++p) {
    int row = p*8 + (tid >> 5);
    int col = (tid & 31)*8;
    *(uint4*)&Xs[row*264 + col] = *(const uint4*)&Xb[(size_t)(m0+row)*256 + col];
  }
  __syncthreads();
  #pragma unroll
  for (int c = 0; c < 4; ++c) {
    int n = n0 + c*16 + l16;
    #pragma unroll
    for (int r = 0; r < 4; ++r) {
      #pragma unroll
      for (int reg = 0; reg < 4; ++reg) {
        int ml = r*16 + quad*4 + reg;
        Xs[ml*264 + n] = f2b(acc[r][c][reg] + b2f(Xs[ml*264 + n]));
      }
    }
  }
  __syncthreads();
  floatx4 mu[2];
  mu[0] = (floatx4){0.f,0.f,0.f,0.f};
  mu[1] = (floatx4){0.f,0.f,0.f,0.f};
  #pragma unroll
  for (int k0 = 0; k0 < DMODEL; k0 += 32) {
    bf16x8 axf = *(const bf16x8*)&Xs[(wave*16 + l16)*264 + k0 + quad*8];
    #pragma unroll
    for (int nt = 0; nt < 2; ++nt) {
      bf16x8 bwf = *(const bf16x8*)(WhT + (size_t)(nt*16 + l16)*DMODEL + k0 + quad*8);
      mu[nt] = __builtin_amdgcn_mfma_f32_16x16x32_bf16(axf, bwf, mu[nt], 0, 0, 0);
    }
  }
  float ls0 = lstd[l16],      els0 = __expf(-ls0), bh0 = bh[l16];
  float ls1 = lstd[16 + l16], els1 = __expf(-ls1), bh1 = bh[16 + l16];
  #pragma unroll
  for (int reg = 0; reg < 4; ++reg) {
    int tok = m0 + wave*16 + quad*4 + reg;
    float m0v = mu[0][reg] + bh0;
    float m1v = mu[1][reg] + bh1;
    float z0 = (a[(size_t)tok*32 + l16]      - m0v) * els0;
    float z1 = (a[(size_t)tok*32 + 16 + l16] - m1v) * els1;
    float t = (-0.5f*z0*z0 - ls0) + (-0.5f*z1*z1 - ls1) - 2.f*0.91893853320467274f;
    t += __shfl_xor(t, 1);
    t += __shfl_xor(t, 2);
    t += __shfl_xor(t, 4);
    t += __shfl_xor(t, 8);
    if (l16 == 0) out[tok] = t;
  }
}

extern "C" void kernel_launch(void* const* d_in, const int* in_sizes, int n_in,
                              void* d_out, int out_size, void* d_ws, size_t ws_size,
                              hipStream_t stream)
{
  const float* s    = (const float*)d_in[0];
  const float* a    = (const float*)d_in[1];
  const float* Wemb = (const float*)d_in[2];
  const float* bemb = (const float*)d_in[3];
  const float* nw   = (const float*)d_in[4];
  const float* Win  = (const float*)d_in[5];
  const float* cw   = (const float*)d_in[6];
  const float* cb   = (const float*)d_in[7];
  const float* Wx   = (const float*)d_in[8];
  const float* Wdt  = (const float*)d_in[9];
  const float* bdt  = (const float*)d_in[10];
  const float* Alog = (const float*)d_in[11];
  const float* Dp   = (const float*)d_in[12];
  const float* Wout = (const float*)d_in[13];
  const float* Wh   = (const float*)d_in[14];
  const float* bh   = (const float*)d_in[15];
  const float* lstd = (const float*)d_in[16];

  // -------- workspace layout (~111 MB)
  u16*   Xb   = (u16*)d_ws;                         // NTOK*256 bf16 (emb resid)
  u16*   XZb  = Xb  + (size_t)NTOK*DMODEL;          // NTOK*1024 bf16 [xp|z]
  u16*   XNb  = XZb + (size_t)NTOK*1024;            // NTOK*256 bf16
  u16*   DTb  = XNb + (size_t)NTOK*DMODEL;          // NTOK*512 bf16
  u16*   YGb  = DTb + (size_t)NTOK*DINNER;          // NTOK*512 bf16
  u16*   WTe  = YGb + (size_t)NTOK*DINNER;          // 256*128
  u16*   WTi  = WTe + 256*128;                      // 1024*256
  u16*   WTo  = WTi + 1024*256;                     // 256*512
  u16*   WxT  = WTo + 256*512;                      // 48*512
  u16*   WdtTp= WxT + 48*512;                       // 512*32
  u16*   WhT  = WdtTp + 512*32;                     // 32*256
  u16*   DTRb = WhT + 32*256;                       // NTOK*32
  u16*   HENDb= DTRb + (size_t)NTOK*32;             // NSEG*8*512*16 bf16
  float* BM   = (float*)(HENDb + (size_t)NSEG*BB*DINNER*16); // NTOK*16 fp32
  float* CM   = BM + (size_t)NTOK*16;               // NTOK*16 fp32
  float* DTS  = CM + (size_t)NTOK*16;               // NSEG*8*512 fp32
  float* out  = (float*)d_out;

  prep_k       <<<1856,        256, 0, stream>>>(Wemb, Win, Wout, Wx, Wdt, Wh,
                                                 WTe, WTi, WTo, WxT, WdtTp, WhT);
  embnorm_k    <<<256,         256, 0, stream>>>(s, WTe, bemb, nw, Xb, XNb);
  gemm_mfma<256><<<dim3(128,8), 256, 0, stream>>>(XNb, WTi, XZb, 1024);
  xdblBC_k     <<<256,         256, 0, stream>>>(XZb, cw, cb, WxT, BM, CM, DTRb);
  dtg_k        <<<dim3(128,4), 256, 0, stream>>>(DTRb, WdtTp, bdt, DTb);
  scanA_k      <<<dim3(NSEG,BB,2), 256, 0, stream>>>(DTb, XZb, BM, cw, cb, Alog, HENDb, DTS);
  stitch_k     <<<256,         256, 0, stream>>>(HENDb, DTS, Alog);
  scanC_k      <<<dim3(NSEG,BB,2), 256, 0, stream>>>(DTb, XZb, BM, CM, cw, cb, Alog, Dp, HENDb, YGb);
  outhead_k    <<<256,         256, 0, stream>>>(YGb, WTo, Xb, WhT, bh, lstd, a, out);
}